// Round 12
// baseline (318.860 us; speedup 1.0000x reference)
//
#include <hip/hip_runtime.h>
#include <math.h>

typedef __bf16 bf16x8 __attribute__((ext_vector_type(8)));
typedef __bf16 bf16x4 __attribute__((ext_vector_type(4)));
typedef float f32x4 __attribute__((ext_vector_type(4)));

__device__ __forceinline__ void gload_lds16(const __bf16* g, __bf16* l) {
  __builtin_amdgcn_global_load_lds((const __attribute__((address_space(1))) void*)g,
                                   (__attribute__((address_space(3))) void*)l, 16, 0, 0);
}

__device__ __forceinline__ float gelu_exact(float v) {
  return 0.5f * v * (1.f + erff(v * 0.70710678118654752f));
}

// ---------------- fused prep: perm-src | 4x cvt | 4x transpose-cvt ----------------
__global__ __launch_bounds__(256) void prep_all(
    const float* __restrict__ src, __bf16* __restrict__ srcB2,
    const float* __restrict__ pos, __bf16* __restrict__ posB,
    const float* __restrict__ ow, __bf16* __restrict__ owB,
    const float* __restrict__ w1, __bf16* __restrict__ w1B,
    const float* __restrict__ w2, __bf16* __restrict__ w2B,
    const float* __restrict__ qw, const float* __restrict__ kw,
    const float* __restrict__ vw, const float* __restrict__ rw,
    __bf16* __restrict__ qkvT, __bf16* __restrict__ rwT) {
  __shared__ float t[32][33];
  int bid = blockIdx.x;
  const int tid = threadIdx.x;
  if (bid < 4096) {                       // src (i,b)-rows -> bf16 (b,i)-rows
    const int i = bid & 1023, b = bid >> 10;
    const float4 v = *(const float4*)(src + ((size_t)(i * 4 + b)) * 1024 + tid * 4);
    bf16x4 o = {(__bf16)v.x, (__bf16)v.y, (__bf16)v.z, (__bf16)v.w};
    *(bf16x4*)(srcB2 + (size_t)bid * 1024 + tid * 4) = o;
    return;
  }
  bid -= 4096;
  if (bid < 3329) {                       // straight converts
    const float* in; __bf16* out;
    if (bid < 1025) { in = pos; out = posB; }
    else if (bid < 1281) { bid -= 1025; in = ow; out = owB; }
    else if (bid < 2305) { bid -= 1281; in = w1; out = w1B; }
    else { bid -= 2305; in = w2; out = w2B; }
    const int base = bid * 4096 + tid * 4;
#pragma unroll
    for (int k2 = 0; k2 < 4; ++k2) {
      const int off = base + k2 * 1024;
      float4 v = *(const float4*)(in + off);
      bf16x4 o = {(__bf16)v.x, (__bf16)v.y, (__bf16)v.z, (__bf16)v.w};
      *(bf16x4*)(out + off) = o;
    }
    return;
  }
  bid -= 3329;                            // transpose-converts (4x 1024x1024)
  const int z = bid >> 10, rem = bid & 1023;
  const float* in; __bf16* out;
  switch (z) {
    case 0: in = qw; out = qkvT; break;
    case 1: in = kw; out = qkvT + 1024 * 1024; break;
    case 2: in = vw; out = qkvT + 2048 * 1024; break;
    default: in = rw; out = rwT; break;
  }
  const int c0 = (rem & 31) * 32, r0 = (rem >> 5) * 32;
  const int tx = tid & 31, ty = tid >> 5;
  for (int yy = ty; yy < 32; yy += 8)
    t[yy][tx] = in[(size_t)(r0 + yy) * 1024 + c0 + tx];
  __syncthreads();
  for (int yy = ty; yy < 32; yy += 8)
    out[(size_t)(c0 + yy) * 1024 + r0 + tx] = (__bf16)t[tx][yy];
}

// ---------------- bf16 MFMA GEMM body (2-phase, 128x64) ----------------
template<int BM, int BN, int MODE>
__device__ __forceinline__ void gemm_body(
    const __bf16* __restrict__ A, const __bf16* __restrict__ BT,
    float* __restrict__ Cf, __bf16* __restrict__ Cb,
    const float* __restrict__ bias, int M, int N, int K,
    int kStart, int kChunk, int mBase, int nBase, char* smemRaw) {
  constexpr int BK = 32;
  constexpr int ALOAD = (BM * BK) / 2048;
  constexpr int BLOAD = (BN * BK) / 2048;
  __bf16* lA = (__bf16*)smemRaw;                       // [2][BM*BK]
  __bf16* lB = (__bf16*)(smemRaw + 4 * BM * BK);       // [2][BN*BK]
  const int tid = threadIdx.x;
  const int w = tid >> 6, l = tid & 63;
  const int lr = l & 15, lk = l >> 4;
  const int srow = tid >> 2;
  const int scol = (tid & 3) * 8;
  const int wbase = w * 512;

  const __bf16* aSrc[ALOAD];
  const __bf16* bSrc[BLOAD];
#pragma unroll
  for (int i = 0; i < ALOAD; ++i) {
    int grow = mBase + srow + i * 64;
    grow = grow < M ? grow : M - 1;
    aSrc[i] = A + (size_t)grow * K + kStart + scol;
  }
#pragma unroll
  for (int i = 0; i < BLOAD; ++i) {
    const int grow = nBase + srow + i * 64;
    bSrc[i] = BT + (size_t)grow * K + kStart + scol;
  }
  auto stage = [&](int buf) {
#pragma unroll
    for (int i = 0; i < ALOAD; ++i) {
      gload_lds16(aSrc[i], &lA[buf * BM * BK + i * 2048 + wbase]);
      aSrc[i] += BK;
    }
#pragma unroll
    for (int i = 0; i < BLOAD; ++i) {
      gload_lds16(bSrc[i], &lB[buf * BN * BK + i * 2048 + wbase]);
      bSrc[i] += BK;
    }
  };

  constexpr int WM = BM / 2, WN = BN / 2;
  constexpr int MF = WM / 16, NF = WN / 16;
  const int wr = w >> 1, wc = w & 1;
  f32x4 acc[MF][NF] = {};

  const int nIter = kChunk / BK;
  stage(0);
  int cur = 0;
#pragma unroll 1
  for (int t = 0; t < nIter; ++t) {
    __syncthreads();
    if (t + 1 < nIter) stage(cur ^ 1);
    bf16x8 af[MF], bfr[NF];
#pragma unroll
    for (int mi = 0; mi < MF; ++mi)
      af[mi] = *(const bf16x8*)&lA[cur * BM * BK + (wr * WM + mi * 16 + lr) * BK + lk * 8];
#pragma unroll
    for (int nj = 0; nj < NF; ++nj)
      bfr[nj] = *(const bf16x8*)&lB[cur * BN * BK + (wc * WN + nj * 16 + lr) * BK + lk * 8];
#pragma unroll
    for (int mi = 0; mi < MF; ++mi)
#pragma unroll
      for (int nj = 0; nj < NF; ++nj)
        acc[mi][nj] = __builtin_amdgcn_mfma_f32_16x16x32_bf16(af[mi], bfr[nj], acc[mi][nj], 0, 0, 0);
    cur ^= 1;
  }
#pragma unroll
  for (int mi = 0; mi < MF; ++mi) {
#pragma unroll
    for (int nj = 0; nj < NF; ++nj) {
      const int col = nBase + wc * WN + nj * 16 + lr;
      const int row0 = mBase + wr * WM + mi * 16 + lk * 4;
#pragma unroll
      for (int j = 0; j < 4; ++j) {
        const int row = row0 + j;
        if (row < M) {
          float v = acc[mi][nj][j];
          if constexpr (MODE == 1) {
            v = gelu_exact(v + bias[col]);
            Cb[(size_t)row * N + col] = (__bf16)v;
          } else if constexpr (MODE == 2) {
            Cb[(size_t)row * N + col] = (__bf16)v;
          } else {
            Cf[(size_t)row * N + col] = v;
          }
        }
      }
    }
  }
}

template<int BM, int BN, int MODE>
__global__ __launch_bounds__(256)
void gemm_bt(const __bf16* __restrict__ A, const __bf16* __restrict__ BT,
             float* __restrict__ Cf, __bf16* __restrict__ Cb,
             __bf16* __restrict__ Cb2, const float* __restrict__ bias,
             int M, int N, int K, int kChunk) {
  __shared__ __align__(16) char smem[4 * (BM + BN) * 32];
  __bf16* cb = (blockIdx.z == 1) ? Cb2 : Cb;
  const int gx = gridDim.x;
  const int G = gx * gridDim.y;
  const int flat = blockIdx.y * gx + blockIdx.x;
  const int band = G >> 3;
  const int x8 = flat & 7, loc = flat >> 3;
  const int rpb = band / gx;
  const int ny = x8 * rpb + loc % rpb;
  const int nx = loc / rpb;
  gemm_body<BM, BN, MODE>(A, BT, Cf, cb, bias, M, N, K, blockIdx.z * kChunk,
                          kChunk, ny * BM, nx * BN, smem);
}

// ---- vT + kpos projections in one launch (1040 blocks, XCD-chunked) ----
__global__ __launch_bounds__(256)
void proj2_kernel(const __bf16* __restrict__ vwT, const __bf16* __restrict__ srcB2,
                  const __bf16* __restrict__ posB, const __bf16* __restrict__ rwT,
                  __bf16* __restrict__ vTB, __bf16* __restrict__ kposB) {
  __shared__ __align__(16) char smem[4 * (128 + 64) * 32];
  const int raw = blockIdx.x;
  int bid = (raw & 7) * 130 + (raw >> 3);   // 1040/8 = 130 per XCD
  if (bid < 512) {
    gemm_body<128, 64, 2>(vwT, srcB2, nullptr, vTB, nullptr, 1024, 4096, 1024,
                          0, 1024, (bid >> 6) * 128, (bid & 63) * 64, smem);
  } else {
    const int t = bid - 512;
    gemm_body<128, 64, 2>(posB, rwT, nullptr, kposB, nullptr, 4100, 1024, 1024,
                          0, 1024, (t >> 4) * 128, (t & 15) * 64, smem);
  }
}

// ---------------- 256x128-tile deep-pipeline GEMM (3-side counted-vmcnt) ----------------
template<int MODE>
__global__ __launch_bounds__(512)
void gemm256(const __bf16* __restrict__ A, const __bf16* __restrict__ BT,
             __bf16* __restrict__ Cb, const float* __restrict__ bias,
             int M, int N, int K) {
  __shared__ __align__(16) __bf16 sm[3 * 24576];
  const int tid = threadIdx.x;
  const int wid = tid >> 6, l = tid & 63;
  const int lcol = l & 15, lk = l >> 4;
  const int wm = wid >> 1, wn = wid & 1;
  const int gx = gridDim.x;
  const int G = gx * gridDim.y;
  const int flat = blockIdx.y * gx + blockIdx.x;
  const int band = G >> 3;
  const int x8 = flat & 7, loc = flat >> 3;
  const int rpb = band / gx;
  const int ny = x8 * rpb + loc % rpb;
  const int nx = loc / rpb;
  const int mBase = ny * 256, nBase = nx * 128;

  int rowj[2], gslotj[2];
#pragma unroll
  for (int j = 0; j < 2; ++j) {
    const int u = (wid * 2 + j) * 64 + l;
    rowj[j] = u >> 3;
    gslotj[j] = (u & 7) ^ (rowj[j] & 7);
  }
  auto issueHT = [&](int kt, int ht, int side) {
    __bf16* base = sm + side * 24576 + (ht == 2 ? 16384 : ht * 8192);
#pragma unroll
    for (int j = 0; j < 2; ++j) {
      const __bf16* src = (ht < 2)
        ? A + (size_t)(mBase + ht * 128 + rowj[j]) * K + kt * 64 + gslotj[j] * 8
        : BT + (size_t)(nBase + rowj[j]) * K + kt * 64 + gslotj[j] * 8;
      gload_lds16(src, base + (wid * 2 + j) * 512);
    }
  };

  const int nkt = K >> 6;
  issueHT(0, 0, 0); issueHT(0, 1, 0); issueHT(0, 2, 0);
  issueHT(1, 0, 1); issueHT(1, 1, 1); issueHT(1, 2, 1);

  f32x4 acc[4][4] = {};
#pragma unroll 1
  for (int j = 0; j < nkt; ++j) {
    asm volatile("s_waitcnt vmcnt(6)" ::: "memory");
    __builtin_amdgcn_s_barrier();
    __builtin_amdgcn_sched_barrier(0);
    const int side = j % 3;
    const int sn = (j + 2) % 3;
    const int ktn = (j + 2 < nkt) ? j + 2 : nkt - 1;
    const __bf16* Ab = sm + side * 24576;
    const __bf16* Bb = Ab + 16384;
    issueHT(ktn, 0, sn);
    bf16x8 af[4][2];
#pragma unroll
    for (int mi = 0; mi < 4; ++mi)
#pragma unroll
      for (int kk = 0; kk < 2; ++kk) {
        const int row = wm * 64 + mi * 16 + lcol;
        af[mi][kk] = *(const bf16x8*)&Ab[row * 64 + (((kk * 4 + lk) ^ (row & 7)) * 8)];
      }
    issueHT(ktn, 1, sn);
    bf16x8 bfv[4][2];
#pragma unroll
    for (int nj = 0; nj < 4; ++nj)
#pragma unroll
      for (int kk = 0; kk < 2; ++kk) {
        const int row = wn * 64 + nj * 16 + lcol;
        bfv[nj][kk] = *(const bf16x8*)&Bb[row * 64 + (((kk * 4 + lk) ^ (row & 7)) * 8)];
      }
    issueHT(ktn, 2, sn);
    __builtin_amdgcn_s_setprio(1);
#pragma unroll
    for (int mi = 0; mi < 4; ++mi)
#pragma unroll
      for (int nj = 0; nj < 4; ++nj) {
        acc[mi][nj] = __builtin_amdgcn_mfma_f32_16x16x32_bf16(af[mi][0], bfv[nj][0], acc[mi][nj], 0, 0, 0);
        acc[mi][nj] = __builtin_amdgcn_mfma_f32_16x16x32_bf16(af[mi][1], bfv[nj][1], acc[mi][nj], 0, 0, 0);
      }
    __builtin_amdgcn_s_setprio(0);
  }
#pragma unroll
  for (int mi = 0; mi < 4; ++mi)
#pragma unroll
    for (int nj = 0; nj < 4; ++nj) {
      const int col = nBase + wn * 64 + nj * 16 + lcol;
      const int row0 = mBase + wm * 64 + mi * 16 + lk * 4;
#pragma unroll
      for (int jj = 0; jj < 4; ++jj) {
        float v = acc[mi][nj][jj];
        if constexpr (MODE == 1) v = gelu_exact(v + bias[col]);
        Cb[(size_t)(row0 + jj) * N + col] = (__bf16)v;
      }
    }
}

// ---------------- MFMA rel-pos attention v9: KVBLK=32, 3 blocks/CU ----------------
// Same math as v8 (swapped MFMAs, band-ring sbd, Z via ones-MFMA), tile halved:
// K/KP tiles [32][64], VT [64][32], P [64][32]; LDS 44.5 KB -> 3 blocks/CU.
__global__ __launch_bounds__(256)
void attn9(const __bf16* __restrict__ qk, const __bf16* __restrict__ vT,
           const __bf16* __restrict__ kpos, const float* __restrict__ rwbias,
           const float* __restrict__ rrbias, __bf16* __restrict__ av) {
  constexpr float ALPHA = 0.125f * 1.44269504088896f;
  constexpr int PB = 132;
  // K dbuf 0:8192 | KP dbuf 8192:16384 | VT dbuf 16384:24576 | P 24576:28672 | sbd 28672:45568
  __shared__ __align__(16) char smem[45568];
  __bf16* sP  = (__bf16*)(smem + 24576);
  __bf16* sbd = (__bf16*)(smem + 28672);

  const int flat = blockIdx.x;
  const int xcd = flat & 7, rr_ = flat >> 3;
  const int bn = xcd * 8 + (rr_ >> 4);
  const int it = rr_ & 15;
  const int b = bn >> 4, n = bn & 15;
  const int i0 = it * 64;
  const int tid = threadIdx.x;
  const int l = tid & 63;
  const int lcol = l & 15, lk = l >> 4;
  const int strip = (tid >> 6) * 16;
  const int nh64 = n * 64;
  const int q = strip + lcol;

  // staging geometry: K/KP tiles [32 rows][8 slots]; VT tile [64 rows][4 slots]
  const int rK = tid >> 3;                       // 0..31
  const int csK = ((tid & 7) ^ (rK & 7)) * 8;
  const int rV = tid >> 2;                       // 0..63
  const int csV = ((tid & 3) ^ (rV & 3)) * 8;
  const int wdst = (tid & 192) * 8;              // wave-uniform LDS elem offset

  bf16x8 onesf;
#pragma unroll
  for (int u = 0; u < 8; ++u) onesf[u] = (__bf16)1.0f;

  // ---- q fragments: qac (rwb), qlo (rrb, rows i0+q), qhi (rrb, rows i0+q+1) ----
  bf16x8 qac[2], qlo[2], qhi[2];
  {
    const __bf16* qrow = qk + ((size_t)(b * 1024 + i0 + q)) * 2048 + nh64;
    int gH = i0 + q + 1; gH = gH < 1024 ? gH : 1023;
    const __bf16* qrowH = qk + ((size_t)(b * 1024 + gH)) * 2048 + nh64;
#pragma unroll
    for (int kk = 0; kk < 2; ++kk) {
      bf16x8 qv = *(const bf16x8*)(qrow + kk * 32 + lk * 8);
      bf16x8 qh = *(const bf16x8*)(qrowH + kk * 32 + lk * 8);
      const int dbase = nh64 + kk * 32 + lk * 8;
#pragma unroll
      for (int u = 0; u < 8; ++u) {
        const float rb = rrbias[dbase + u];
        qac[kk][u] = (__bf16)(((float)qv[u] + rwbias[dbase + u]) * ALPHA);
        qlo[kk][u] = (__bf16)(((float)qv[u] + rb) * ALPHA);
        qhi[kk][u] = (__bf16)(((float)qh[u] + rb) * ALPHA);
      }
    }
  }

  // ---- prologue stage: lowA->VTs1, lowB->KPs1, K0->Ks0, KP0->KPs0, VT0->VTs0 ----
  {
    // lowA: rrel in [-i0-64,-i0-32) -> idx = 960-i0+rK ; lowB: idx = 992-i0+rK
    gload_lds16(kpos + ((size_t)((960 - i0 + rK) * 4 + b)) * 1024 + nh64 + csK,
                (__bf16*)(smem + 20480) + wdst);          // VT side1 (temp, [32][64])
    gload_lds16(kpos + ((size_t)((992 - i0 + rK) * 4 + b)) * 1024 + nh64 + csK,
                (__bf16*)(smem + 12288) + wdst);          // KP side1 (temp)
    gload_lds16(qk + ((size_t)(b * 1024 + rK)) * 2048 + 1024 + nh64 + csK,
                (__bf16*)(smem) + wdst);                  // K jt0 -> side0
    const int rrel = rK - i0;
    const int idx = (rrel <= 0) ? (1024 + rrel) : (rrel - 1);
    gload_lds16(kpos + ((size_t)(idx * 4 + b)) * 1024 + nh64 + csK,
                (__bf16*)(smem + 8192) + wdst);           // KP jt0 -> side0
    gload_lds16(vT + ((size_t)(nh64 + rV)) * 4096 + b * 1024 + csV,
                (__bf16*)(smem + 16384) + wdst);          // VT jt0 -> side0
  }
  __syncthreads();
  // ---- prologue G on low band (qlo, rows q) ----
  {
    const __bf16* bands[2] = {(const __bf16*)(smem + 20480), (const __bf16*)(smem + 12288)};
#pragma unroll
    for (int ba = 0; ba < 2; ++ba) {
      const int rrel0 = -i0 - 64 + ba * 32;
#pragma unroll
      for (int fb = 0; fb < 2; ++fb) {
        const int row = fb * 16 + lcol;
        f32x4 g = {};
        g = __builtin_amdgcn_mfma_f32_16x16x32_bf16(
            *(const bf16x8*)&bands[ba][row * 64 + ((lk ^ (row & 7)) * 8)], qlo[0], g, 0, 0, 0);
        g = __builtin_amdgcn_mfma_f32_16x16x32_bf16(
            *(const bf16x8*)&bands[ba][row * 64 + (((4 + lk) ^ (row & 7)) * 8)], qlo[1], g, 0, 0, 0);
        bf16x4 gw = {(__bf16)g[0], (__bf16)g[1], (__bf16)g[2], (__bf16)g[3]};
        *(bf16x4*)&sbd[q * PB + ((rrel0 + fb * 16 + lk * 4) & 127)] = gw;
      }
    }
  }
  __syncthreads();   // prologue-temp reads done before jt0 stages into side1

  f32x4 oacc[4] = {};
  f32x4 zq = {};

#pragma unroll 1
  for (int jt = 0; jt < 32; ++jt) {
    const int cur = jt & 1, nxt = cur ^ 1;
    const int d0 = jt * 32 - i0;
    __bf16* sK   = (__bf16*)(smem + cur * 4096);
    __bf16* sKn  = (__bf16*)(smem + nxt * 4096);
    __bf16* sKP  = (__bf16*)(smem + 8192 + cur * 4096);
    __bf16* sKPn = (__bf16*)(smem + 8192 + nxt * 4096);
    __bf16* sVT  = (__bf16*)(smem + 16384 + cur * 4096);
    __bf16* sVTn = (__bf16*)(smem + 16384 + nxt * 4096);
    // ---- stage jt+1 (K, KP, VT); OOB prefetch at jt=31 never read ----
    {
      const int j0n = (jt + 1) * 32;
      int krow = j0n + rK; krow = krow < 1024 ? krow : 1023;
      gload_lds16(qk + ((size_t)(b * 1024 + krow)) * 2048 + 1024 + nh64 + csK, sKn + wdst);
      const int rreln = d0 + 32 + rK;
      const int idx = (rreln <= 0) ? (1024 + rreln) : (rreln - 1);
      gload_lds16(kpos + ((size_t)(idx * 4 + b)) * 1024 + nh64 + csK, sKPn + wdst);
      gload_lds16(vT + ((size_t)(nh64 + rV)) * 4096 + b * 1024 + j0n + csV, sVTn + wdst);
    }
    // ---- G MFMA on current band batch (32 cols): hi for d0>=0, lo for d0<0; row q ----
    {
      const bf16x8 qg0 = (d0 >= 0) ? qhi[0] : qlo[0];
      const bf16x8 qg1 = (d0 >= 0) ? qhi[1] : qlo[1];
#pragma unroll
      for (int fb = 0; fb < 2; ++fb) {
        const int row = fb * 16 + lcol;
        f32x4 g = {};
        g = __builtin_amdgcn_mfma_f32_16x16x32_bf16(
            *(const bf16x8*)&sKP[row * 64 + ((lk ^ (row & 7)) * 8)], qg0, g, 0, 0, 0);
        g = __builtin_amdgcn_mfma_f32_16x16x32_bf16(
            *(const bf16x8*)&sKP[row * 64 + (((4 + lk) ^ (row & 7)) * 8)], qg1, g, 0, 0, 0);
        bf16x4 gw = {(__bf16)g[0], (__bf16)g[1], (__bf16)g[2], (__bf16)g[3]};
        *(bf16x4*)&sbd[q * PB + ((d0 + fb * 16 + lk * 4) & 127)] = gw;
      }
      if (d0 == 0) {   // fix col rrel=0 (needs lo q-rows): once per block
        const int cl = tid >> 2, part = tid & 3;
        const __bf16* qs = qk + ((size_t)(b * 1024 + i0 + cl)) * 2048 + nh64 + part * 16;
        bf16x8 a0 = *(const bf16x8*)qs;
        bf16x8 a1 = *(const bf16x8*)(qs + 8);
        bf16x8 k0 = *(const bf16x8*)&sKP[(2 * part) * 8];       // row 0, swizzle 0
        bf16x8 k1 = *(const bf16x8*)&sKP[(2 * part + 1) * 8];
        float s64 = 0.f;
#pragma unroll
        for (int u = 0; u < 8; ++u)
          s64 += ((float)a0[u] + rrbias[nh64 + part * 16 + u]) * (float)k0[u]
               + ((float)a1[u] + rrbias[nh64 + part * 16 + 8 + u]) * (float)k1[u];
        s64 += __shfl_xor(s64, 1, 64);
        s64 += __shfl_xor(s64, 2, 64);
        if (part == 0) sbd[cl * PB] = (__bf16)(s64 * ALPHA);
      }
    }
    // ---- ac MFMA (swapped): sc[fk][jj] = S[jl=fk*16+lk*4+jj][q], jl in [0,32) ----
    f32x4 sc[2];
#pragma unroll
    for (int fk = 0; fk < 2; ++fk) {
      const int row = fk * 16 + lcol;
      f32x4 a = {};
      a = __builtin_amdgcn_mfma_f32_16x16x32_bf16(
          *(const bf16x8*)&sK[row * 64 + ((lk ^ (row & 7)) * 8)], qac[0], a, 0, 0, 0);
      a = __builtin_amdgcn_mfma_f32_16x16x32_bf16(
          *(const bf16x8*)&sK[row * 64 + (((4 + lk) ^ (row & 7)) * 8)], qac[1], a, 0, 0, 0);
      sc[fk] = a;
    }
    // ---- gather + exp2 + P store (wave-private rows; no barrier) ----
    {
      const int rowb = q * PB;
      const int sb = d0 - q;
#pragma unroll
      for (int fk = 0; fk < 2; ++fk) {
        const int cb = sb + fk * 16 + lk * 4;
        float e0 = exp2f(sc[fk][0] + (float)sbd[rowb + ((cb) & 127)]);
        float e1 = exp2f(sc[fk][1] + (float)sbd[rowb + ((cb + 1) & 127)]);
        float e2 = exp2f(sc[fk][2] + (float)sbd[rowb + ((cb + 2) & 127)]);
        float e3 = exp2f(sc[fk][3] + (float)sbd[rowb + ((cb + 3) & 127)]);
        bf16x4 pw = {(__bf16)e0, (__bf16)e1, (__bf16)e2, (__bf16)e3};
        *(bf16x4*)&sP[q * 32 + (((fk * 2 + (lk >> 1)) ^ (q & 3)) * 8) + (lk & 1) * 4] = pw;
      }
    }
    // ---- PV MFMA (K=32: single frag) + Z-ones MFMA ----
    {
      bf16x8 pa = *(const bf16x8*)&sP[q * 32 + ((lk ^ (q & 3)) * 8)];
      zq = __builtin_amdgcn_mfma_f32_16x16x32_bf16(pa, onesf, zq, 0, 0, 0);
#pragma unroll
      for (int fd = 0; fd < 4; ++fd) {
        const int vrow = fd * 16 + lcol;
        bf16x8 bv = *(const bf16x8*)&sVT[vrow * 32 + ((lk ^ (vrow & 3)) * 8)];
        oacc[fd] = __builtin_amdgcn_mfma_f32_16x16x32_bf16(pa, bv, oacc[fd], 0, 0, 0);
      }
    }
    __syncthreads();   // rotation: cur reads done; next-jt staging drained
  }
  // ---- epilogue: zq[jj] is Z for exactly the row this thread stores ----
#pragma unroll
  for (int jj = 0; jj < 4; ++jj) {
    const float rz = 1.f / zq[jj];
    const int ig = i0 + strip + lk * 4 + jj;
    __bf16* dst = av + ((size_t)(ig * 4 + b)) * 1024 + nh64;
#pragma unroll
    for (int fd = 0; fd < 4; ++fd)
      dst[fd * 16 + lcol] = (__bf16)(oacc[fd][jj] * rz);
  }
}

// ---------------- fused residual + LayerNorm (two bf16 partial addends) ----------------
__global__ __launch_bounds__(256)
void ln_fuse(const float* __restrict__ A, const __bf16* __restrict__ P0,
             const __bf16* __restrict__ P1, const float* __restrict__ cb,
             const float* __restrict__ g, const float* __restrict__ be,
             float* __restrict__ oF, __bf16* __restrict__ oB) {
  const int row = blockIdx.x, t = threadIdx.x;
  const size_t base = (size_t)row * 1024 + t * 4;
  const float4 a = *(const float4*)(A + base);
  const bf16x4 p0 = *(const bf16x4*)(P0 + base);
  const bf16x4 p1 = *(const bf16x4*)(P1 + base);
  float x0 = a.x + (float)p0[0] + (float)p1[0];
  float x1 = a.y + (float)p0[1] + (float)p1[1];
  float x2 = a.z + (float)p0[2] + (float)p1[2];
  float x3 = a.w + (float)p0[3] + (float)p1[3];
  if (cb) {
    const float4 c = *(const float4*)(cb + t * 4);
    x0 += c.x; x1 += c.y; x2 += c.z; x3 += c.w;
  }
  float s = x0 + x1 + x2 + x3;
  float qq = x0 * x0 + x1 * x1 + x2 * x2 + x3 * x3;
#pragma unroll
  for (int o = 1; o < 64; o <<= 1) { s += __shfl_xor(s, o, 64); qq += __shfl_xor(qq, o, 64); }
  __shared__ float ss[4], qs[4];
  if ((t & 63) == 0) { ss[t >> 6] = s; qs[t >> 6] = qq; }
  __syncthreads();
  s = ss[0] + ss[1] + ss[2] + ss[3];
  qq = qs[0] + qs[1] + qs[2] + qs[3];
  const float mean = s * (1.f / 1024.f);
  const float var = qq * (1.f / 1024.f) - mean * mean;
  const float rstd = rsqrtf(var + 1e-5f);
  const float4 gv = *(const float4*)(g + t * 4);
  const float4 bev = *(const float4*)(be + t * 4);
  const float y0 = (x0 - mean) * rstd * gv.x + bev.x;
  const float y1 = (x1 - mean) * rstd * gv.y + bev.y;
  const float y2 = (x2 - mean) * rstd * gv.z + bev.z;
  const float y3 = (x3 - mean) * rstd * gv.w + bev.w;
  if (oF) {
    float4 r = {y0, y1, y2, y3};
    *(float4*)(oF + base) = r;
  }
  if (oB) {
    bf16x4 o4 = {(__bf16)y0, (__bf16)y1, (__bf16)y2, (__bf16)y3};
    *(bf16x4*)(oB + base) = o4;
  }
}

extern "C" void kernel_launch(void* const* d_in, const int* in_sizes, int n_in,
                              void* d_out, int out_size, void* d_ws, size_t ws_size,
                              hipStream_t stream) {
  const float* src    = (const float*)d_in[0];
  const float* pos    = (const float*)d_in[1];
  const float* qw     = (const float*)d_in[3];
  const float* kw     = (const float*)d_in[4];
  const float* vw     = (const float*)d_in[5];
  const float* rw     = (const float*)d_in[6];
  const float* ow     = (const float*)d_in[7];
  const float* rwbias = (const float*)d_in[8];
  const float* rrbias = (const float*)d_in[9];
  const float* w1     = (const float*)d_in[10];
  const float* b1     = (const float*)d_in[11];
  const float* w2     = (const float*)d_in[12];
  const float* b2     = (const float*)d_in[13];
  const float* g1     = (const float*)d_in[14];
  const float* be1    = (const float*)d_in[15];
  const float* g2     = (const float*)d_in[16];
  const float* be2    = (const float*)d_in[17];
  float* out = (float*)d_out;

  char* p = (char*)d_ws;
  auto alloc = [&](size_t bytes) { char* r = p; p += (bytes + 255) & ~(size_t)255; return r; };
  __bf16* qkB   = (__bf16*)alloc(4096ull * 2048 * 2);   // dead after attn
  __bf16* vTB   = (__bf16*)alloc(1024ull * 4096 * 2);   // dead after attn
  __bf16* kposB = (__bf16*)alloc(4100ull * 1024 * 2);   // dead after attn
  __bf16* avB   = (__bf16*)alloc(4096ull * 1024 * 2);   // dead after attn-out
  __bf16* srcB2 = (__bf16*)alloc(4096ull * 1024 * 2);   // dead after projections
  __bf16* posB  = (__bf16*)alloc(4100ull * 1024 * 2);   // dead after proj2
  float*  xF    = (float*)alloc(4096ull * 1024 * 4);
  __bf16* w2B   = (__bf16*)alloc(4096ull * 1024 * 2);
  __bf16* qkvT  = (__bf16*)alloc(3072ull * 1024 * 2);
  __bf16* rwT   = (__bf16*)alloc(1024ull * 1024 * 2);
  __bf16* owB   = (__bf16*)alloc(1024ull * 1024 * 2);
  __bf16* w1B   = (__bf16*)alloc(4096ull * 1024 * 2);   // dead after FFN1
  __bf16* xB    = (__bf16*)alloc(4096ull * 1024 * 2);   // dead after FFN1
  // aliases (disjoint lifetimes):
  __bf16* gB   = qkB;            // gelu 32MB over qkB+vTB+kposB
  __bf16* aoP0 = srcB2;          // attn-out bf16 partial0
  __bf16* aoP1 = posB;           // attn-out bf16 partial1
  __bf16* ffP0 = avB;            // ffn2 bf16 partial0
  __bf16* ffP1 = w1B;            // ffn2 bf16 partial1

  prep_all<<<11521, 256, 0, stream>>>(src, srcB2, pos, posB, ow, owB, w1, w1B,
                                      w2, w2B, qw, kw, vw, rw, qkvT, rwT);
  gemm256<2><<<dim3(16, 16), 512, 0, stream>>>(srcB2, qkvT, qkB, nullptr, 4096, 2048, 1024);
  proj2_kernel<<<1040, 256, 0, stream>>>(qkvT + 2048 * 1024, srcB2, posB, rwT, vTB, kposB);
  attn9<<<dim3(1024), 256, 0, stream>>>(qkB, vTB, kposB, rwbias, rrbias, avB);
  gemm_bt<128, 64, 2><<<dim3(16, 32, 2), 256, 0, stream>>>(avB, owB, nullptr, aoP0, aoP1, nullptr, 4096, 1024, 1024, 512);
  ln_fuse<<<4096, 256, 0, stream>>>(src, aoP0, aoP1, nullptr, g1, be1, xF, xB);
  gemm256<1><<<dim3(32, 16), 512, 0, stream>>>(xB, w1B, gB, b1, 4096, 4096, 1024);
  gemm_bt<128, 64, 2><<<dim3(16, 32, 2), 256, 0, stream>>>(gB, w2B, nullptr, ffP0, ffP1, nullptr, 4096, 1024, 4096, 2048);
  ln_fuse<<<4096, 256, 0, stream>>>(xF, ffP0, ffP1, b2, g2, be2, out, nullptr);
  (void)in_sizes; (void)n_in; (void)out_size; (void)ws_size;
}

// Round 13
// 307.558 us; speedup vs baseline: 1.0367x; 1.0367x over previous
//
#include <hip/hip_runtime.h>
#include <math.h>

typedef __bf16 bf16x8 __attribute__((ext_vector_type(8)));
typedef __bf16 bf16x4 __attribute__((ext_vector_type(4)));
typedef float f32x4 __attribute__((ext_vector_type(4)));

__device__ __forceinline__ void gload_lds16(const __bf16* g, __bf16* l) {
  __builtin_amdgcn_global_load_lds((const __attribute__((address_space(1))) void*)g,
                                   (__attribute__((address_space(3))) void*)l, 16, 0, 0);
}

__device__ __forceinline__ float gelu_exact(float v) {
  return 0.5f * v * (1.f + erff(v * 0.70710678118654752f));
}

// ---------------- fused prep: perm-src | 4x cvt | 4x transpose-cvt ----------------
__global__ __launch_bounds__(256) void prep_all(
    const float* __restrict__ src, __bf16* __restrict__ srcB2,
    const float* __restrict__ pos, __bf16* __restrict__ posB,
    const float* __restrict__ ow, __bf16* __restrict__ owB,
    const float* __restrict__ w1, __bf16* __restrict__ w1B,
    const float* __restrict__ w2, __bf16* __restrict__ w2B,
    const float* __restrict__ qw, const float* __restrict__ kw,
    const float* __restrict__ vw, const float* __restrict__ rw,
    __bf16* __restrict__ qkvT, __bf16* __restrict__ rwT) {
  __shared__ float t[32][33];
  int bid = blockIdx.x;
  const int tid = threadIdx.x;
  if (bid < 4096) {                       // src (i,b)-rows -> bf16 (b,i)-rows
    const int i = bid & 1023, b = bid >> 10;
    const float4 v = *(const float4*)(src + ((size_t)(i * 4 + b)) * 1024 + tid * 4);
    bf16x4 o = {(__bf16)v.x, (__bf16)v.y, (__bf16)v.z, (__bf16)v.w};
    *(bf16x4*)(srcB2 + (size_t)bid * 1024 + tid * 4) = o;
    return;
  }
  bid -= 4096;
  if (bid < 3329) {                       // straight converts
    const float* in; __bf16* out;
    if (bid < 1025) { in = pos; out = posB; }
    else if (bid < 1281) { bid -= 1025; in = ow; out = owB; }
    else if (bid < 2305) { bid -= 1281; in = w1; out = w1B; }
    else { bid -= 2305; in = w2; out = w2B; }
    const int base = bid * 4096 + tid * 4;
#pragma unroll
    for (int k2 = 0; k2 < 4; ++k2) {
      const int off = base + k2 * 1024;
      float4 v = *(const float4*)(in + off);
      bf16x4 o = {(__bf16)v.x, (__bf16)v.y, (__bf16)v.z, (__bf16)v.w};
      *(bf16x4*)(out + off) = o;
    }
    return;
  }
  bid -= 3329;                            // transpose-converts (4x 1024x1024)
  const int z = bid >> 10, rem = bid & 1023;
  const float* in; __bf16* out;
  switch (z) {
    case 0: in = qw; out = qkvT; break;
    case 1: in = kw; out = qkvT + 1024 * 1024; break;
    case 2: in = vw; out = qkvT + 2048 * 1024; break;
    default: in = rw; out = rwT; break;
  }
  const int c0 = (rem & 31) * 32, r0 = (rem >> 5) * 32;
  const int tx = tid & 31, ty = tid >> 5;
  for (int yy = ty; yy < 32; yy += 8)
    t[yy][tx] = in[(size_t)(r0 + yy) * 1024 + c0 + tx];
  __syncthreads();
  for (int yy = ty; yy < 32; yy += 8)
    out[(size_t)(c0 + yy) * 1024 + r0 + tx] = (__bf16)t[tx][yy];
}

// ---------------- bf16 MFMA GEMM body (2-phase, 128x64) ----------------
template<int BM, int BN, int MODE>
__device__ __forceinline__ void gemm_body(
    const __bf16* __restrict__ A, const __bf16* __restrict__ BT,
    float* __restrict__ Cf, __bf16* __restrict__ Cb,
    const float* __restrict__ bias, int M, int N, int K,
    int kStart, int kChunk, int mBase, int nBase, char* smemRaw) {
  constexpr int BK = 32;
  constexpr int ALOAD = (BM * BK) / 2048;
  constexpr int BLOAD = (BN * BK) / 2048;
  __bf16* lA = (__bf16*)smemRaw;                       // [2][BM*BK]
  __bf16* lB = (__bf16*)(smemRaw + 4 * BM * BK);       // [2][BN*BK]
  const int tid = threadIdx.x;
  const int w = tid >> 6, l = tid & 63;
  const int lr = l & 15, lk = l >> 4;
  const int srow = tid >> 2;
  const int scol = (tid & 3) * 8;
  const int wbase = w * 512;

  const __bf16* aSrc[ALOAD];
  const __bf16* bSrc[BLOAD];
#pragma unroll
  for (int i = 0; i < ALOAD; ++i) {
    int grow = mBase + srow + i * 64;
    grow = grow < M ? grow : M - 1;
    aSrc[i] = A + (size_t)grow * K + kStart + scol;
  }
#pragma unroll
  for (int i = 0; i < BLOAD; ++i) {
    const int grow = nBase + srow + i * 64;
    bSrc[i] = BT + (size_t)grow * K + kStart + scol;
  }
  auto stage = [&](int buf) {
#pragma unroll
    for (int i = 0; i < ALOAD; ++i) {
      gload_lds16(aSrc[i], &lA[buf * BM * BK + i * 2048 + wbase]);
      aSrc[i] += BK;
    }
#pragma unroll
    for (int i = 0; i < BLOAD; ++i) {
      gload_lds16(bSrc[i], &lB[buf * BN * BK + i * 2048 + wbase]);
      bSrc[i] += BK;
    }
  };

  constexpr int WM = BM / 2, WN = BN / 2;
  constexpr int MF = WM / 16, NF = WN / 16;
  const int wr = w >> 1, wc = w & 1;
  f32x4 acc[MF][NF] = {};

  const int nIter = kChunk / BK;
  stage(0);
  int cur = 0;
#pragma unroll 1
  for (int t = 0; t < nIter; ++t) {
    __syncthreads();
    if (t + 1 < nIter) stage(cur ^ 1);
    bf16x8 af[MF], bfr[NF];
#pragma unroll
    for (int mi = 0; mi < MF; ++mi)
      af[mi] = *(const bf16x8*)&lA[cur * BM * BK + (wr * WM + mi * 16 + lr) * BK + lk * 8];
#pragma unroll
    for (int nj = 0; nj < NF; ++nj)
      bfr[nj] = *(const bf16x8*)&lB[cur * BN * BK + (wc * WN + nj * 16 + lr) * BK + lk * 8];
#pragma unroll
    for (int mi = 0; mi < MF; ++mi)
#pragma unroll
      for (int nj = 0; nj < NF; ++nj)
        acc[mi][nj] = __builtin_amdgcn_mfma_f32_16x16x32_bf16(af[mi], bfr[nj], acc[mi][nj], 0, 0, 0);
    cur ^= 1;
  }
#pragma unroll
  for (int mi = 0; mi < MF; ++mi) {
#pragma unroll
    for (int nj = 0; nj < NF; ++nj) {
      const int col = nBase + wc * WN + nj * 16 + lr;
      const int row0 = mBase + wr * WM + mi * 16 + lk * 4;
#pragma unroll
      for (int j = 0; j < 4; ++j) {
        const int row = row0 + j;
        if (row < M) {
          float v = acc[mi][nj][j];
          if constexpr (MODE == 1) {
            v = gelu_exact(v + bias[col]);
            Cb[(size_t)row * N + col] = (__bf16)v;
          } else if constexpr (MODE == 2) {
            Cb[(size_t)row * N + col] = (__bf16)v;
          } else {
            Cf[(size_t)row * N + col] = v;
          }
        }
      }
    }
  }
}

template<int BM, int BN, int MODE>
__global__ __launch_bounds__(256)
void gemm_bt(const __bf16* __restrict__ A, const __bf16* __restrict__ BT,
             float* __restrict__ Cf, __bf16* __restrict__ Cb,
             __bf16* __restrict__ Cb2, const float* __restrict__ bias,
             int M, int N, int K, int kChunk) {
  __shared__ __align__(16) char smem[4 * (BM + BN) * 32];
  __bf16* cb = (blockIdx.z == 1) ? Cb2 : Cb;
  const int gx = gridDim.x;
  const int G = gx * gridDim.y;
  const int flat = blockIdx.y * gx + blockIdx.x;
  const int band = G >> 3;
  const int x8 = flat & 7, loc = flat >> 3;
  const int rpb = band / gx;
  const int ny = x8 * rpb + loc % rpb;
  const int nx = loc / rpb;
  gemm_body<BM, BN, MODE>(A, BT, Cf, cb, bias, M, N, K, blockIdx.z * kChunk,
                          kChunk, ny * BM, nx * BN, smem);
}

// ---- vT + kpos projections in one launch (1040 blocks, XCD-chunked) ----
__global__ __launch_bounds__(256)
void proj2_kernel(const __bf16* __restrict__ vwT, const __bf16* __restrict__ srcB2,
                  const __bf16* __restrict__ posB, const __bf16* __restrict__ rwT,
                  __bf16* __restrict__ vTB, __bf16* __restrict__ kposB) {
  __shared__ __align__(16) char smem[4 * (128 + 64) * 32];
  const int raw = blockIdx.x;
  int bid = (raw & 7) * 130 + (raw >> 3);   // 1040/8 = 130 per XCD
  if (bid < 512) {
    gemm_body<128, 64, 2>(vwT, srcB2, nullptr, vTB, nullptr, 1024, 4096, 1024,
                          0, 1024, (bid >> 6) * 128, (bid & 63) * 64, smem);
  } else {
    const int t = bid - 512;
    gemm_body<128, 64, 2>(posB, rwT, nullptr, kposB, nullptr, 4100, 1024, 1024,
                          0, 1024, (t >> 4) * 128, (t & 15) * 64, smem);
  }
}

// ---------------- 256x128-tile deep-pipeline GEMM (3-side counted-vmcnt) ----------------
template<int MODE>
__global__ __launch_bounds__(512)
void gemm256(const __bf16* __restrict__ A, const __bf16* __restrict__ BT,
             __bf16* __restrict__ Cb, const float* __restrict__ bias,
             int M, int N, int K) {
  __shared__ __align__(16) __bf16 sm[3 * 24576];
  const int tid = threadIdx.x;
  const int wid = tid >> 6, l = tid & 63;
  const int lcol = l & 15, lk = l >> 4;
  const int wm = wid >> 1, wn = wid & 1;
  const int gx = gridDim.x;
  const int G = gx * gridDim.y;
  const int flat = blockIdx.y * gx + blockIdx.x;
  const int band = G >> 3;
  const int x8 = flat & 7, loc = flat >> 3;
  const int rpb = band / gx;
  const int ny = x8 * rpb + loc % rpb;
  const int nx = loc / rpb;
  const int mBase = ny * 256, nBase = nx * 128;

  int rowj[2], gslotj[2];
#pragma unroll
  for (int j = 0; j < 2; ++j) {
    const int u = (wid * 2 + j) * 64 + l;
    rowj[j] = u >> 3;
    gslotj[j] = (u & 7) ^ (rowj[j] & 7);
  }
  auto issueHT = [&](int kt, int ht, int side) {
    __bf16* base = sm + side * 24576 + (ht == 2 ? 16384 : ht * 8192);
#pragma unroll
    for (int j = 0; j < 2; ++j) {
      const __bf16* src = (ht < 2)
        ? A + (size_t)(mBase + ht * 128 + rowj[j]) * K + kt * 64 + gslotj[j] * 8
        : BT + (size_t)(nBase + rowj[j]) * K + kt * 64 + gslotj[j] * 8;
      gload_lds16(src, base + (wid * 2 + j) * 512);
    }
  };

  const int nkt = K >> 6;
  issueHT(0, 0, 0); issueHT(0, 1, 0); issueHT(0, 2, 0);
  issueHT(1, 0, 1); issueHT(1, 1, 1); issueHT(1, 2, 1);

  f32x4 acc[4][4] = {};
#pragma unroll 1
  for (int j = 0; j < nkt; ++j) {
    asm volatile("s_waitcnt vmcnt(6)" ::: "memory");
    __builtin_amdgcn_s_barrier();
    __builtin_amdgcn_sched_barrier(0);
    const int side = j % 3;
    const int sn = (j + 2) % 3;
    const int ktn = (j + 2 < nkt) ? j + 2 : nkt - 1;
    const __bf16* Ab = sm + side * 24576;
    const __bf16* Bb = Ab + 16384;
    issueHT(ktn, 0, sn);
    bf16x8 af[4][2];
#pragma unroll
    for (int mi = 0; mi < 4; ++mi)
#pragma unroll
      for (int kk = 0; kk < 2; ++kk) {
        const int row = wm * 64 + mi * 16 + lcol;
        af[mi][kk] = *(const bf16x8*)&Ab[row * 64 + (((kk * 4 + lk) ^ (row & 7)) * 8)];
      }
    issueHT(ktn, 1, sn);
    bf16x8 bfv[4][2];
#pragma unroll
    for (int nj = 0; nj < 4; ++nj)
#pragma unroll
      for (int kk = 0; kk < 2; ++kk) {
        const int row = wn * 64 + nj * 16 + lcol;
        bfv[nj][kk] = *(const bf16x8*)&Bb[row * 64 + (((kk * 4 + lk) ^ (row & 7)) * 8)];
      }
    issueHT(ktn, 2, sn);
    __builtin_amdgcn_s_setprio(1);
#pragma unroll
    for (int mi = 0; mi < 4; ++mi)
#pragma unroll
      for (int nj = 0; nj < 4; ++nj) {
        acc[mi][nj] = __builtin_amdgcn_mfma_f32_16x16x32_bf16(af[mi][0], bfv[nj][0], acc[mi][nj], 0, 0, 0);
        acc[mi][nj] = __builtin_amdgcn_mfma_f32_16x16x32_bf16(af[mi][1], bfv[nj][1], acc[mi][nj], 0, 0, 0);
      }
    __builtin_amdgcn_s_setprio(0);
  }
#pragma unroll
  for (int mi = 0; mi < 4; ++mi)
#pragma unroll
    for (int nj = 0; nj < 4; ++nj) {
      const int col = nBase + wn * 64 + nj * 16 + lcol;
      const int row0 = mBase + wm * 64 + mi * 16 + lk * 4;
#pragma unroll
      for (int jj = 0; jj < 4; ++jj) {
        float v = acc[mi][nj][jj];
        if constexpr (MODE == 1) v = gelu_exact(v + bias[col]);
        Cb[(size_t)(row0 + jj) * N + col] = (__bf16)v;
      }
    }
}

// ---------------- 256x256-tile GEMM, BK=64, 8 waves of 128x64 (LDS-BW optimal) ----------
// FLOP/LDS-byte = 42.7 (vs 32 for 64x64 wave tiles) -> MFMA-bound. 2-phase dbuf,
// 128 KB LDS; BK=64 compute (~2400 cyc) >> HBM latency so the barrier drain is free.
// Requires M%256==0, N%256==0, K%64==0.
template<int MODE>
__global__ __launch_bounds__(512)
void gemm512(const __bf16* __restrict__ A, const __bf16* __restrict__ BT,
             __bf16* __restrict__ Cb, const float* __restrict__ bias,
             int M, int N, int K) {
  __shared__ __align__(16) __bf16 sm[2 * 32768];
  const int tid = threadIdx.x;
  const int w = tid >> 6, l = tid & 63;
  const int lcol = l & 15, lk = l >> 4;
  const int wm = w >> 2, wn = w & 3;          // 2 x 4 waves, wave tile 128x64
  const int gx = gridDim.x;
  const int G = gx * gridDim.y;
  const int flat = blockIdx.y * gx + blockIdx.x;
  const int band = G >> 3;
  const int x8 = flat & 7, loc = flat >> 3;
  const int rpb = band / gx;
  const int ny = x8 * rpb + loc % rpb;
  const int nx = loc / rpb;
  const int mBase = ny * 256, nBase = nx * 256;

  const int rT = tid >> 3;                    // 0..63
  const int gslot = ((tid & 7) ^ (rT & 7)) * 8;
  auto stage = [&](int side, int kt) {
#pragma unroll
    for (int i = 0; i < 4; ++i) {
      gload_lds16(A + (size_t)(mBase + i * 64 + rT) * K + kt * 64 + gslot,
                  sm + side * 32768 + i * 4096 + w * 512);
      gload_lds16(BT + (size_t)(nBase + i * 64 + rT) * K + kt * 64 + gslot,
                  sm + side * 32768 + 16384 + i * 4096 + w * 512);
    }
  };

  f32x4 acc[8][4] = {};
  const int nIter = K >> 6;
  stage(0, 0);
  int cur = 0;
#pragma unroll 1
  for (int t = 0; t < nIter; ++t) {
    __syncthreads();                           // side cur complete (drains vmcnt)
    if (t + 1 < nIter) stage(cur ^ 1, t + 1);
    const __bf16* Ab = sm + cur * 32768;
    const __bf16* Bb = Ab + 16384;
    bf16x8 bfv[4][2];
#pragma unroll
    for (int nj = 0; nj < 4; ++nj)
#pragma unroll
      for (int kk = 0; kk < 2; ++kk) {
        const int row = wn * 64 + nj * 16 + lcol;
        bfv[nj][kk] = *(const bf16x8*)&Bb[row * 64 + (((kk * 4 + lk) ^ (row & 7)) * 8)];
      }
    __builtin_amdgcn_s_setprio(1);
#pragma unroll
    for (int mi = 0; mi < 8; ++mi) {
      const int row = wm * 128 + mi * 16 + lcol;
      bf16x8 a0 = *(const bf16x8*)&Ab[row * 64 + ((lk ^ (row & 7)) * 8)];
      bf16x8 a1 = *(const bf16x8*)&Ab[row * 64 + (((4 + lk) ^ (row & 7)) * 8)];
#pragma unroll
      for (int nj = 0; nj < 4; ++nj) {
        acc[mi][nj] = __builtin_amdgcn_mfma_f32_16x16x32_bf16(a0, bfv[nj][0], acc[mi][nj], 0, 0, 0);
        acc[mi][nj] = __builtin_amdgcn_mfma_f32_16x16x32_bf16(a1, bfv[nj][1], acc[mi][nj], 0, 0, 0);
      }
    }
    __builtin_amdgcn_s_setprio(0);
    cur ^= 1;
  }
#pragma unroll
  for (int mi = 0; mi < 8; ++mi)
#pragma unroll
    for (int nj = 0; nj < 4; ++nj) {
      const int col = nBase + wn * 64 + nj * 16 + lcol;
      const int row0 = mBase + wm * 128 + mi * 16 + lk * 4;
#pragma unroll
      for (int jj = 0; jj < 4; ++jj) {
        float v = acc[mi][nj][jj];
        if constexpr (MODE == 1) v = gelu_exact(v + bias[col]);
        Cb[(size_t)(row0 + jj) * N + col] = (__bf16)v;
      }
    }
}

// ---------------- MFMA rel-pos attention v8: Z via ones-MFMA (best variant) ----------------
__global__ __launch_bounds__(256)
void attn8(const __bf16* __restrict__ qk, const __bf16* __restrict__ vT,
           const __bf16* __restrict__ kpos, const float* __restrict__ rwbias,
           const float* __restrict__ rrbias, __bf16* __restrict__ av) {
  constexpr float ALPHA = 0.125f * 1.44269504088896f;
  constexpr int PB = 132;
  __shared__ __align__(16) char smem[74240];
  __bf16* sP  = (__bf16*)(smem + 49152);
  __bf16* sbd = (__bf16*)(smem + 57344);

  const int flat = blockIdx.x;
  const int xcd = flat & 7, rr_ = flat >> 3;
  const int bn = xcd * 8 + (rr_ >> 4);
  const int it = rr_ & 15;
  const int b = bn >> 4, n = bn & 15;
  const int i0 = it * 64;
  const int tid = threadIdx.x;
  const int l = tid & 63;
  const int lcol = l & 15, lk = l >> 4;
  const int strip = (tid >> 6) * 16;
  const int wbase = tid & 192;
  const int nh64 = n * 64;
  const int q = strip + lcol;

  const int rB = tid >> 3;
  const int cs8 = ((tid & 7) ^ (rB & 7)) * 8;

  bf16x8 onesf;
#pragma unroll
  for (int u = 0; u < 8; ++u) onesf[u] = (__bf16)1.0f;

  bf16x8 qac[2], qlo[2], qhi[2];
  {
    const __bf16* qrow = qk + ((size_t)(b * 1024 + i0 + q)) * 2048 + nh64;
    int gH = i0 + q + 1; gH = gH < 1024 ? gH : 1023;
    const __bf16* qrowH = qk + ((size_t)(b * 1024 + gH)) * 2048 + nh64;
#pragma unroll
    for (int kk = 0; kk < 2; ++kk) {
      bf16x8 qv = *(const bf16x8*)(qrow + kk * 32 + lk * 8);
      bf16x8 qh = *(const bf16x8*)(qrowH + kk * 32 + lk * 8);
      const int dbase = nh64 + kk * 32 + lk * 8;
#pragma unroll
      for (int u = 0; u < 8; ++u) {
        const float rb = rrbias[dbase + u];
        qac[kk][u] = (__bf16)(((float)qv[u] + rwbias[dbase + u]) * ALPHA);
        qlo[kk][u] = (__bf16)(((float)qv[u] + rb) * ALPHA);
        qhi[kk][u] = (__bf16)(((float)qh[u] + rb) * ALPHA);
      }
    }
  }

#pragma unroll
  for (int kq = 0; kq < 2; ++kq) {
    const int r = kq * 32 + rB;
    const int dst = (kq * 256 + wbase) * 8;
    gload_lds16(kpos + ((size_t)((960 - i0 + r) * 4 + b)) * 1024 + nh64 + cs8,
                (__bf16*)(smem + 40960) + dst);
    gload_lds16(qk + ((size_t)(b * 1024 + r)) * 2048 + 1024 + nh64 + cs8,
                (__bf16*)(smem) + dst);
    const int rrel = r - i0;
    const int idx = (rrel <= 0) ? (1024 + rrel) : (rrel - 1);
    gload_lds16(kpos + ((size_t)(idx * 4 + b)) * 1024 + nh64 + cs8,
                (__bf16*)(smem + 16384) + dst);
    gload_lds16(vT + ((size_t)(nh64 + r)) * 4096 + b * 1024 + cs8,
                (__bf16*)(smem + 32768) + dst);
  }
  __syncthreads();
  {
    __bf16* kpl = (__bf16*)(smem + 40960);
    const int colb0 = (-i0 - 64) & 127;
#pragma unroll
    for (int fb = 0; fb < 4; ++fb) {
      const int row = fb * 16 + lcol;
      f32x4 g = {};
#pragma unroll
      for (int kk = 0; kk < 2; ++kk) {
        bf16x8 a = *(const bf16x8*)&kpl[row * 64 + (((kk * 4 + lk) ^ (lcol & 7)) * 8)];
        g = __builtin_amdgcn_mfma_f32_16x16x32_bf16(a, qlo[kk], g, 0, 0, 0);
      }
      bf16x4 gw = {(__bf16)g[0], (__bf16)g[1], (__bf16)g[2], (__bf16)g[3]};
      *(bf16x4*)&sbd[q * PB + ((colb0 + fb * 16 + lk * 4) & 127)] = gw;
    }
  }
  __syncthreads();

  f32x4 oacc[4] = {};
  f32x4 zq = {};
  size_t kS = (size_t)(b * 1024 + 64 + rB) * 2048 + 1024 + nh64 + cs8;
  size_t vS = (size_t)(nh64 + rB) * 4096 + b * 1024 + 64 + cs8;

#pragma unroll 1
  for (int jt = 0; jt < 16; ++jt) {
    const int cur = jt & 1, nxt = cur ^ 1;
    const int d0 = jt * 64 - i0;
    __bf16* sK   = (__bf16*)(smem + cur * 8192);
    __bf16* sKn  = (__bf16*)(smem + nxt * 8192);
    __bf16* sKP  = (__bf16*)(smem + 16384 + cur * 8192);
    __bf16* sKPn = (__bf16*)(smem + 16384 + nxt * 8192);
    __bf16* sVT  = (__bf16*)(smem + 32768 + cur * 8192);
    __bf16* sVTn = (__bf16*)(smem + 32768 + nxt * 8192);
#pragma unroll
    for (int kq = 0; kq < 2; ++kq) {
      const int dst = (kq * 256 + wbase) * 8;
      gload_lds16(qk + kS + kq * 65536, sKn + dst);
      gload_lds16(vT + vS + kq * 131072, sVTn + dst);
      const int rreln = d0 + 64 + kq * 32 + rB;
      const int idx = (rreln <= 0) ? (1024 + rreln) : (rreln - 1);
      gload_lds16(kpos + ((size_t)(idx * 4 + b)) * 1024 + nh64 + cs8, sKPn + dst);
    }
    kS += 131072; vS += 64;
    {
      const bf16x8 qg0 = (d0 >= 0) ? qhi[0] : qlo[0];
      const bf16x8 qg1 = (d0 >= 0) ? qhi[1] : qlo[1];
#pragma unroll
      for (int fb = 0; fb < 4; ++fb) {
        const int row = fb * 16 + lcol;
        f32x4 g = {};
        g = __builtin_amdgcn_mfma_f32_16x16x32_bf16(
            *(const bf16x8*)&sKP[row * 64 + ((lk ^ (lcol & 7)) * 8)], qg0, g, 0, 0, 0);
        g = __builtin_amdgcn_mfma_f32_16x16x32_bf16(
            *(const bf16x8*)&sKP[row * 64 + (((4 + lk) ^ (lcol & 7)) * 8)], qg1, g, 0, 0, 0);
        bf16x4 gw = {(__bf16)g[0], (__bf16)g[1], (__bf16)g[2], (__bf16)g[3]};
        *(bf16x4*)&sbd[q * PB + ((d0 + fb * 16 + lk * 4) & 127)] = gw;
      }
      if (d0 == 0) {
        const int cl = tid >> 2, part = tid & 3;
        const __bf16* qs = qk + ((size_t)(b * 1024 + i0 + cl)) * 2048 + nh64 + part * 16;
        bf16x8 a0 = *(const bf16x8*)qs;
        bf16x8 a1 = *(const bf16x8*)(qs + 8);
        bf16x8 k0 = *(const bf16x8*)&sKP[(2 * part) * 8];
        bf16x8 k1 = *(const bf16x8*)&sKP[(2 * part + 1) * 8];
        float s64 = 0.f;
#pragma unroll
        for (int u = 0; u < 8; ++u)
          s64 += ((float)a0[u] + rrbias[nh64 + part * 16 + u]) * (float)k0[u]
               + ((float)a1[u] + rrbias[nh64 + part * 16 + 8 + u]) * (float)k1[u];
        s64 += __shfl_xor(s64, 1, 64);
        s64 += __shfl_xor(s64, 2, 64);
        if (part == 0) sbd[cl * PB] = (__bf16)(s64 * ALPHA);
      }
    }
    f32x4 sc[4];
#pragma unroll
    for (int fk = 0; fk < 4; ++fk) {
      const int row = fk * 16 + lcol;
      f32x4 a = {};
#pragma unroll
      for (int kk = 0; kk < 2; ++kk) {
        bf16x8 kf = *(const bf16x8*)&sK[row * 64 + (((kk * 4 + lk) ^ (lcol & 7)) * 8)];
        a = __builtin_amdgcn_mfma_f32_16x16x32_bf16(kf, qac[kk], a, 0, 0, 0);
      }
      sc[fk] = a;
    }
    {
      const int rowb = q * PB;
      const int sb = d0 - q;
#pragma unroll
      for (int fk = 0; fk < 4; ++fk) {
        const int cb = sb + fk * 16 + lk * 4;
        float e0 = exp2f(sc[fk][0] + (float)sbd[rowb + ((cb) & 127)]);
        float e1 = exp2f(sc[fk][1] + (float)sbd[rowb + ((cb + 1) & 127)]);
        float e2 = exp2f(sc[fk][2] + (float)sbd[rowb + ((cb + 2) & 127)]);
        float e3 = exp2f(sc[fk][3] + (float)sbd[rowb + ((cb + 3) & 127)]);
        bf16x4 pw = {(__bf16)e0, (__bf16)e1, (__bf16)e2, (__bf16)e3};
        *(bf16x4*)&sP[q * 64 + (((fk * 2 + (lk >> 1)) ^ (q & 7)) * 8) + (lk & 1) * 4] = pw;
      }
    }
#pragma unroll
    for (int kk = 0; kk < 2; ++kk) {
      bf16x8 pa = *(const bf16x8*)&sP[q * 64 + (((kk * 4 + lk) ^ (q & 7)) * 8)];
      zq = __builtin_amdgcn_mfma_f32_16x16x32_bf16(pa, onesf, zq, 0, 0, 0);
#pragma unroll
      for (int fd = 0; fd < 4; ++fd) {
        const int vrow = fd * 16 + lcol;
        bf16x8 bv = *(const bf16x8*)&sVT[vrow * 64 + (((kk * 4 + lk) ^ (lcol & 7)) * 8)];
        oacc[fd] = __builtin_amdgcn_mfma_f32_16x16x32_bf16(pa, bv, oacc[fd], 0, 0, 0);
      }
    }
    __syncthreads();
  }
#pragma unroll
  for (int jj = 0; jj < 4; ++jj) {
    const float rz = 1.f / zq[jj];
    const int ig = i0 + strip + lk * 4 + jj;
    __bf16* dst = av + ((size_t)(ig * 4 + b)) * 1024 + nh64;
#pragma unroll
    for (int fd = 0; fd < 4; ++fd)
      dst[fd * 16 + lcol] = (__bf16)(oacc[fd][jj] * rz);
  }
}

// ---------------- fused residual + LayerNorm (two bf16 partial addends) ----------------
__global__ __launch_bounds__(256)
void ln_fuse(const float* __restrict__ A, const __bf16* __restrict__ P0,
             const __bf16* __restrict__ P1, const float* __restrict__ cb,
             const float* __restrict__ g, const float* __restrict__ be,
             float* __restrict__ oF, __bf16* __restrict__ oB) {
  const int row = blockIdx.x, t = threadIdx.x;
  const size_t base = (size_t)row * 1024 + t * 4;
  const float4 a = *(const float4*)(A + base);
  const bf16x4 p0 = *(const bf16x4*)(P0 + base);
  const bf16x4 p1 = *(const bf16x4*)(P1 + base);
  float x0 = a.x + (float)p0[0] + (float)p1[0];
  float x1 = a.y + (float)p0[1] + (float)p1[1];
  float x2 = a.z + (float)p0[2] + (float)p1[2];
  float x3 = a.w + (float)p0[3] + (float)p1[3];
  if (cb) {
    const float4 c = *(const float4*)(cb + t * 4);
    x0 += c.x; x1 += c.y; x2 += c.z; x3 += c.w;
  }
  float s = x0 + x1 + x2 + x3;
  float qq = x0 * x0 + x1 * x1 + x2 * x2 + x3 * x3;
#pragma unroll
  for (int o = 1; o < 64; o <<= 1) { s += __shfl_xor(s, o, 64); qq += __shfl_xor(qq, o, 64); }
  __shared__ float ss[4], qs[4];
  if ((t & 63) == 0) { ss[t >> 6] = s; qs[t >> 6] = qq; }
  __syncthreads();
  s = ss[0] + ss[1] + ss[2] + ss[3];
  qq = qs[0] + qs[1] + qs[2] + qs[3];
  const float mean = s * (1.f / 1024.f);
  const float var = qq * (1.f / 1024.f) - mean * mean;
  const float rstd = rsqrtf(var + 1e-5f);
  const float4 gv = *(const float4*)(g + t * 4);
  const float4 bev = *(const float4*)(be + t * 4);
  const float y0 = (x0 - mean) * rstd * gv.x + bev.x;
  const float y1 = (x1 - mean) * rstd * gv.y + bev.y;
  const float y2 = (x2 - mean) * rstd * gv.z + bev.z;
  const float y3 = (x3 - mean) * rstd * gv.w + bev.w;
  if (oF) {
    float4 r = {y0, y1, y2, y3};
    *(float4*)(oF + base) = r;
  }
  if (oB) {
    bf16x4 o4 = {(__bf16)y0, (__bf16)y1, (__bf16)y2, (__bf16)y3};
    *(bf16x4*)(oB + base) = o4;
  }
}

extern "C" void kernel_launch(void* const* d_in, const int* in_sizes, int n_in,
                              void* d_out, int out_size, void* d_ws, size_t ws_size,
                              hipStream_t stream) {
  const float* src    = (const float*)d_in[0];
  const float* pos    = (const float*)d_in[1];
  const float* qw     = (const float*)d_in[3];
  const float* kw     = (const float*)d_in[4];
  const float* vw     = (const float*)d_in[5];
  const float* rw     = (const float*)d_in[6];
  const float* ow     = (const float*)d_in[7];
  const float* rwbias = (const float*)d_in[8];
  const float* rrbias = (const float*)d_in[9];
  const float* w1     = (const float*)d_in[10];
  const float* b1     = (const float*)d_in[11];
  const float* w2     = (const float*)d_in[12];
  const float* b2     = (const float*)d_in[13];
  const float* g1     = (const float*)d_in[14];
  const float* be1    = (const float*)d_in[15];
  const float* g2     = (const float*)d_in[16];
  const float* be2    = (const float*)d_in[17];
  float* out = (float*)d_out;

  char* p = (char*)d_ws;
  auto alloc = [&](size_t bytes) { char* r = p; p += (bytes + 255) & ~(size_t)255; return r; };
  __bf16* qkB   = (__bf16*)alloc(4096ull * 2048 * 2);   // dead after attn
  __bf16* vTB   = (__bf16*)alloc(1024ull * 4096 * 2);   // dead after attn
  __bf16* kposB = (__bf16*)alloc(4100ull * 1024 * 2);   // dead after attn
  __bf16* avB   = (__bf16*)alloc(4096ull * 1024 * 2);   // dead after attn-out
  __bf16* srcB2 = (__bf16*)alloc(4096ull * 1024 * 2);   // dead after projections
  __bf16* posB  = (__bf16*)alloc(4100ull * 1024 * 2);   // dead after proj2
  float*  xF    = (float*)alloc(4096ull * 1024 * 4);
  __bf16* w2B   = (__bf16*)alloc(4096ull * 1024 * 2);
  __bf16* qkvT  = (__bf16*)alloc(3072ull * 1024 * 2);
  __bf16* rwT   = (__bf16*)alloc(1024ull * 1024 * 2);
  __bf16* owB   = (__bf16*)alloc(1024ull * 1024 * 2);
  __bf16* w1B   = (__bf16*)alloc(4096ull * 1024 * 2);   // dead after FFN1
  __bf16* xB    = (__bf16*)alloc(4096ull * 1024 * 2);   // dead after FFN1
  // aliases (disjoint lifetimes):
  __bf16* gB   = qkB;            // gelu 32MB over qkB+vTB+kposB
  __bf16* aoP0 = srcB2;          // attn-out bf16 partial0
  __bf16* aoP1 = posB;           // attn-out bf16 partial1
  __bf16* ffP0 = avB;            // ffn2 bf16 partial0
  __bf16* ffP1 = w1B;            // ffn2 bf16 partial1

  prep_all<<<11521, 256, 0, stream>>>(src, srcB2, pos, posB, ow, owB, w1, w1B,
                                      w2, w2B, qw, kw, vw, rw, qkvT, rwT);
  gemm256<2><<<dim3(16, 16), 512, 0, stream>>>(srcB2, qkvT, qkB, nullptr, 4096, 2048, 1024);
  proj2_kernel<<<1040, 256, 0, stream>>>(qkvT + 2048 * 1024, srcB2, posB, rwT, vTB, kposB);
  attn8<<<dim3(1024), 256, 0, stream>>>(qkB, vTB, kposB, rwbias, rrbias, avB);
  gemm_bt<128, 64, 2><<<dim3(16, 32, 2), 256, 0, stream>>>(avB, owB, nullptr, aoP0, aoP1, nullptr, 4096, 1024, 1024, 512);
  ln_fuse<<<4096, 256, 0, stream>>>(src, aoP0, aoP1, nullptr, g1, be1, xF, xB);
  gemm512<1><<<dim3(16, 16), 512, 0, stream>>>(xB, w1B, gB, b1, 4096, 4096, 1024);
  gemm_bt<128, 64, 2><<<dim3(16, 32, 2), 256, 0, stream>>>(gB, w2B, nullptr, ffP0, ffP1, nullptr, 4096, 1024, 4096, 2048);
  ln_fuse<<<4096, 256, 0, stream>>>(xF, ffP0, ffP1, b2, g2, be2, out, nullptr);
  (void)in_sizes; (void)n_in; (void)out_size; (void)ws_size;
}

// Round 14
// 290.716 us; speedup vs baseline: 1.0968x; 1.0579x over previous
//
#include <hip/hip_runtime.h>
#include <math.h>

typedef __bf16 bf16x8 __attribute__((ext_vector_type(8)));
typedef __bf16 bf16x4 __attribute__((ext_vector_type(4)));
typedef float f32x4 __attribute__((ext_vector_type(4)));

__device__ __forceinline__ void gload_lds16(const __bf16* g, __bf16* l) {
  __builtin_amdgcn_global_load_lds((const __attribute__((address_space(1))) void*)g,
                                   (__attribute__((address_space(3))) void*)l, 16, 0, 0);
}

__device__ __forceinline__ float gelu_exact(float v) {
  return 0.5f * v * (1.f + erff(v * 0.70710678118654752f));
}

// ---------------- fused prep: perm-src | 4x cvt | 4x transpose-cvt ----------------
__global__ __launch_bounds__(256) void prep_all(
    const float* __restrict__ src, __bf16* __restrict__ srcB2,
    const float* __restrict__ pos, __bf16* __restrict__ posB,
    const float* __restrict__ ow, __bf16* __restrict__ owB,
    const float* __restrict__ w1, __bf16* __restrict__ w1B,
    const float* __restrict__ w2, __bf16* __restrict__ w2B,
    const float* __restrict__ qw, const float* __restrict__ kw,
    const float* __restrict__ vw, const float* __restrict__ rw,
    __bf16* __restrict__ qkvT, __bf16* __restrict__ rwT) {
  __shared__ float t[32][33];
  int bid = blockIdx.x;
  const int tid = threadIdx.x;
  if (bid < 4096) {                       // src (i,b)-rows -> bf16 (b,i)-rows
    const int i = bid & 1023, b = bid >> 10;
    const float4 v = *(const float4*)(src + ((size_t)(i * 4 + b)) * 1024 + tid * 4);
    bf16x4 o = {(__bf16)v.x, (__bf16)v.y, (__bf16)v.z, (__bf16)v.w};
    *(bf16x4*)(srcB2 + (size_t)bid * 1024 + tid * 4) = o;
    return;
  }
  bid -= 4096;
  if (bid < 3329) {                       // straight converts
    const float* in; __bf16* out;
    if (bid < 1025) { in = pos; out = posB; }
    else if (bid < 1281) { bid -= 1025; in = ow; out = owB; }
    else if (bid < 2305) { bid -= 1281; in = w1; out = w1B; }
    else { bid -= 2305; in = w2; out = w2B; }
    const int base = bid * 4096 + tid * 4;
#pragma unroll
    for (int k2 = 0; k2 < 4; ++k2) {
      const int off = base + k2 * 1024;
      float4 v = *(const float4*)(in + off);
      bf16x4 o = {(__bf16)v.x, (__bf16)v.y, (__bf16)v.z, (__bf16)v.w};
      *(bf16x4*)(out + off) = o;
    }
    return;
  }
  bid -= 3329;                            // transpose-converts (4x 1024x1024)
  const int z = bid >> 10, rem = bid & 1023;
  const float* in; __bf16* out;
  switch (z) {
    case 0: in = qw; out = qkvT; break;
    case 1: in = kw; out = qkvT + 1024 * 1024; break;
    case 2: in = vw; out = qkvT + 2048 * 1024; break;
    default: in = rw; out = rwT; break;
  }
  const int c0 = (rem & 31) * 32, r0 = (rem >> 5) * 32;
  const int tx = tid & 31, ty = tid >> 5;
  for (int yy = ty; yy < 32; yy += 8)
    t[yy][tx] = in[(size_t)(r0 + yy) * 1024 + c0 + tx];
  __syncthreads();
  for (int yy = ty; yy < 32; yy += 8)
    out[(size_t)(c0 + yy) * 1024 + r0 + tx] = (__bf16)t[tx][yy];
}

// ---------------- bf16 MFMA GEMM body (2-phase, 128x64) ----------------
template<int BM, int BN, int MODE>
__device__ __forceinline__ void gemm_body(
    const __bf16* __restrict__ A, const __bf16* __restrict__ BT,
    float* __restrict__ Cf, __bf16* __restrict__ Cb,
    const float* __restrict__ bias, int M, int N, int K,
    int kStart, int kChunk, int mBase, int nBase, char* smemRaw) {
  constexpr int BK = 32;
  constexpr int ALOAD = (BM * BK) / 2048;
  constexpr int BLOAD = (BN * BK) / 2048;
  __bf16* lA = (__bf16*)smemRaw;                       // [2][BM*BK]
  __bf16* lB = (__bf16*)(smemRaw + 4 * BM * BK);       // [2][BN*BK]
  const int tid = threadIdx.x;
  const int w = tid >> 6, l = tid & 63;
  const int lr = l & 15, lk = l >> 4;
  const int srow = tid >> 2;
  const int scol = (tid & 3) * 8;
  const int wbase = w * 512;

  const __bf16* aSrc[ALOAD];
  const __bf16* bSrc[BLOAD];
#pragma unroll
  for (int i = 0; i < ALOAD; ++i) {
    int grow = mBase + srow + i * 64;
    grow = grow < M ? grow : M - 1;
    aSrc[i] = A + (size_t)grow * K + kStart + scol;
  }
#pragma unroll
  for (int i = 0; i < BLOAD; ++i) {
    const int grow = nBase + srow + i * 64;
    bSrc[i] = BT + (size_t)grow * K + kStart + scol;
  }
  auto stage = [&](int buf) {
#pragma unroll
    for (int i = 0; i < ALOAD; ++i) {
      gload_lds16(aSrc[i], &lA[buf * BM * BK + i * 2048 + wbase]);
      aSrc[i] += BK;
    }
#pragma unroll
    for (int i = 0; i < BLOAD; ++i) {
      gload_lds16(bSrc[i], &lB[buf * BN * BK + i * 2048 + wbase]);
      bSrc[i] += BK;
    }
  };

  constexpr int WM = BM / 2, WN = BN / 2;
  constexpr int MF = WM / 16, NF = WN / 16;
  const int wr = w >> 1, wc = w & 1;
  f32x4 acc[MF][NF] = {};

  const int nIter = kChunk / BK;
  stage(0);
  int cur = 0;
#pragma unroll 1
  for (int t = 0; t < nIter; ++t) {
    __syncthreads();
    if (t + 1 < nIter) stage(cur ^ 1);
    bf16x8 af[MF], bfr[NF];
#pragma unroll
    for (int mi = 0; mi < MF; ++mi)
      af[mi] = *(const bf16x8*)&lA[cur * BM * BK + (wr * WM + mi * 16 + lr) * BK + lk * 8];
#pragma unroll
    for (int nj = 0; nj < NF; ++nj)
      bfr[nj] = *(const bf16x8*)&lB[cur * BN * BK + (wc * WN + nj * 16 + lr) * BK + lk * 8];
#pragma unroll
    for (int mi = 0; mi < MF; ++mi)
#pragma unroll
      for (int nj = 0; nj < NF; ++nj)
        acc[mi][nj] = __builtin_amdgcn_mfma_f32_16x16x32_bf16(af[mi], bfr[nj], acc[mi][nj], 0, 0, 0);
    cur ^= 1;
  }
#pragma unroll
  for (int mi = 0; mi < MF; ++mi) {
#pragma unroll
    for (int nj = 0; nj < NF; ++nj) {
      const int col = nBase + wc * WN + nj * 16 + lr;
      const int row0 = mBase + wr * WM + mi * 16 + lk * 4;
#pragma unroll
      for (int j = 0; j < 4; ++j) {
        const int row = row0 + j;
        if (row < M) {
          float v = acc[mi][nj][j];
          if constexpr (MODE == 1) {
            v = gelu_exact(v + bias[col]);
            Cb[(size_t)row * N + col] = (__bf16)v;
          } else if constexpr (MODE == 2) {
            Cb[(size_t)row * N + col] = (__bf16)v;
          } else {
            Cf[(size_t)row * N + col] = v;
          }
        }
      }
    }
  }
}

template<int BM, int BN, int MODE>
__global__ __launch_bounds__(256)
void gemm_bt(const __bf16* __restrict__ A, const __bf16* __restrict__ BT,
             float* __restrict__ Cf, __bf16* __restrict__ Cb,
             __bf16* __restrict__ Cb2, const float* __restrict__ bias,
             int M, int N, int K, int kChunk) {
  __shared__ __align__(16) char smem[4 * (BM + BN) * 32];
  __bf16* cb = (blockIdx.z == 1) ? Cb2 : Cb;
  const int gx = gridDim.x;
  const int G = gx * gridDim.y;
  const int flat = blockIdx.y * gx + blockIdx.x;
  const int band = G >> 3;
  const int x8 = flat & 7, loc = flat >> 3;
  const int rpb = band / gx;
  const int ny = x8 * rpb + loc % rpb;
  const int nx = loc / rpb;
  gemm_body<BM, BN, MODE>(A, BT, Cf, cb, bias, M, N, K, blockIdx.z * kChunk,
                          kChunk, ny * BM, nx * BN, smem);
}

// ---- vT + kpos projections in one launch (1040 blocks, XCD-chunked) ----
__global__ __launch_bounds__(256)
void proj2_kernel(const __bf16* __restrict__ vwT, const __bf16* __restrict__ srcB2,
                  const __bf16* __restrict__ posB, const __bf16* __restrict__ rwT,
                  __bf16* __restrict__ vTB, __bf16* __restrict__ kposB) {
  __shared__ __align__(16) char smem[4 * (128 + 64) * 32];
  const int raw = blockIdx.x;
  int bid = (raw & 7) * 130 + (raw >> 3);   // 1040/8 = 130 per XCD
  if (bid < 512) {
    gemm_body<128, 64, 2>(vwT, srcB2, nullptr, vTB, nullptr, 1024, 4096, 1024,
                          0, 1024, (bid >> 6) * 128, (bid & 63) * 64, smem);
  } else {
    const int t = bid - 512;
    gemm_body<128, 64, 2>(posB, rwT, nullptr, kposB, nullptr, 4100, 1024, 1024,
                          0, 1024, (t >> 4) * 128, (t & 15) * 64, smem);
  }
}

// ---------------- 256x128-tile deep-pipeline GEMM (3-side counted-vmcnt) ----------------
template<int MODE>
__global__ __launch_bounds__(512)
void gemm256(const __bf16* __restrict__ A, const __bf16* __restrict__ BT,
             __bf16* __restrict__ Cb, const float* __restrict__ bias,
             int M, int N, int K) {
  __shared__ __align__(16) __bf16 sm[3 * 24576];
  const int tid = threadIdx.x;
  const int wid = tid >> 6, l = tid & 63;
  const int lcol = l & 15, lk = l >> 4;
  const int wm = wid >> 1, wn = wid & 1;
  const int gx = gridDim.x;
  const int G = gx * gridDim.y;
  const int flat = blockIdx.y * gx + blockIdx.x;
  const int band = G >> 3;
  const int x8 = flat & 7, loc = flat >> 3;
  const int rpb = band / gx;
  const int ny = x8 * rpb + loc % rpb;
  const int nx = loc / rpb;
  const int mBase = ny * 256, nBase = nx * 128;

  int rowj[2], gslotj[2];
#pragma unroll
  for (int j = 0; j < 2; ++j) {
    const int u = (wid * 2 + j) * 64 + l;
    rowj[j] = u >> 3;
    gslotj[j] = (u & 7) ^ (rowj[j] & 7);
  }
  auto issueHT = [&](int kt, int ht, int side) {
    __bf16* base = sm + side * 24576 + (ht == 2 ? 16384 : ht * 8192);
#pragma unroll
    for (int j = 0; j < 2; ++j) {
      const __bf16* src = (ht < 2)
        ? A + (size_t)(mBase + ht * 128 + rowj[j]) * K + kt * 64 + gslotj[j] * 8
        : BT + (size_t)(nBase + rowj[j]) * K + kt * 64 + gslotj[j] * 8;
      gload_lds16(src, base + (wid * 2 + j) * 512);
    }
  };

  const int nkt = K >> 6;
  issueHT(0, 0, 0); issueHT(0, 1, 0); issueHT(0, 2, 0);
  issueHT(1, 0, 1); issueHT(1, 1, 1); issueHT(1, 2, 1);

  f32x4 acc[4][4] = {};
#pragma unroll 1
  for (int j = 0; j < nkt; ++j) {
    asm volatile("s_waitcnt vmcnt(6)" ::: "memory");
    __builtin_amdgcn_s_barrier();
    __builtin_amdgcn_sched_barrier(0);
    const int side = j % 3;
    const int sn = (j + 2) % 3;
    const int ktn = (j + 2 < nkt) ? j + 2 : nkt - 1;
    const __bf16* Ab = sm + side * 24576;
    const __bf16* Bb = Ab + 16384;
    issueHT(ktn, 0, sn);
    bf16x8 af[4][2];
#pragma unroll
    for (int mi = 0; mi < 4; ++mi)
#pragma unroll
      for (int kk = 0; kk < 2; ++kk) {
        const int row = wm * 64 + mi * 16 + lcol;
        af[mi][kk] = *(const bf16x8*)&Ab[row * 64 + (((kk * 4 + lk) ^ (row & 7)) * 8)];
      }
    issueHT(ktn, 1, sn);
    bf16x8 bfv[4][2];
#pragma unroll
    for (int nj = 0; nj < 4; ++nj)
#pragma unroll
      for (int kk = 0; kk < 2; ++kk) {
        const int row = wn * 64 + nj * 16 + lcol;
        bfv[nj][kk] = *(const bf16x8*)&Bb[row * 64 + (((kk * 4 + lk) ^ (row & 7)) * 8)];
      }
    issueHT(ktn, 2, sn);
    __builtin_amdgcn_s_setprio(1);
#pragma unroll
    for (int mi = 0; mi < 4; ++mi)
#pragma unroll
      for (int nj = 0; nj < 4; ++nj) {
        acc[mi][nj] = __builtin_amdgcn_mfma_f32_16x16x32_bf16(af[mi][0], bfv[nj][0], acc[mi][nj], 0, 0, 0);
        acc[mi][nj] = __builtin_amdgcn_mfma_f32_16x16x32_bf16(af[mi][1], bfv[nj][1], acc[mi][nj], 0, 0, 0);
      }
    __builtin_amdgcn_s_setprio(0);
  }
#pragma unroll
  for (int mi = 0; mi < 4; ++mi)
#pragma unroll
    for (int nj = 0; nj < 4; ++nj) {
      const int col = nBase + wn * 64 + nj * 16 + lcol;
      const int row0 = mBase + wm * 64 + mi * 16 + lk * 4;
#pragma unroll
      for (int jj = 0; jj < 4; ++jj) {
        float v = acc[mi][nj][jj];
        if constexpr (MODE == 1) v = gelu_exact(v + bias[col]);
        Cb[(size_t)(row0 + jj) * N + col] = (__bf16)v;
      }
    }
}

// ---------------- 256x256-tile GEMM, BK=64, 8 waves of 128x64 (LDS-BW optimal) ----------
// Split-K: gridDim.z selects kStart and partial output Cb[z]. bf16 out.
template<int MODE>
__global__ __launch_bounds__(512)
void gemm512(const __bf16* __restrict__ A, const __bf16* __restrict__ BT,
             __bf16* __restrict__ Cb0, __bf16* __restrict__ Cb1,
             __bf16* __restrict__ Cb2, __bf16* __restrict__ Cb3,
             const float* __restrict__ bias, int M, int N, int K, int kChunk) {
  __shared__ __align__(16) __bf16 sm[2 * 32768];
  const int tid = threadIdx.x;
  const int w = tid >> 6, l = tid & 63;
  const int lcol = l & 15, lk = l >> 4;
  const int wm = w >> 2, wn = w & 3;          // 2 x 4 waves, wave tile 128x64
  const int gx = gridDim.x;
  const int G = gx * gridDim.y;
  const int flat = blockIdx.y * gx + blockIdx.x;
  const int band = G >> 3;
  const int x8 = flat & 7, loc = flat >> 3;
  const int rpb = band / gx;
  const int ny = x8 * rpb + loc % rpb;
  const int nx = loc / rpb;
  const int mBase = ny * 256, nBase = nx * 256;
  const int kStart = blockIdx.z * kChunk;
  __bf16* Cb = (blockIdx.z == 0) ? Cb0 : (blockIdx.z == 1) ? Cb1
             : (blockIdx.z == 2) ? Cb2 : Cb3;

  const int rT = tid >> 3;                    // 0..63
  const int gslot = ((tid & 7) ^ (rT & 7)) * 8;
  auto stage = [&](int side, int kt) {
#pragma unroll
    for (int i = 0; i < 4; ++i) {
      gload_lds16(A + (size_t)(mBase + i * 64 + rT) * K + kStart + kt * 64 + gslot,
                  sm + side * 32768 + i * 4096 + w * 512);
      gload_lds16(BT + (size_t)(nBase + i * 64 + rT) * K + kStart + kt * 64 + gslot,
                  sm + side * 32768 + 16384 + i * 4096 + w * 512);
    }
  };

  f32x4 acc[8][4] = {};
  const int nIter = kChunk >> 6;
  stage(0, 0);
  int cur = 0;
#pragma unroll 1
  for (int t = 0; t < nIter; ++t) {
    __syncthreads();                           // side cur complete (drains vmcnt)
    if (t + 1 < nIter) stage(cur ^ 1, t + 1);
    const __bf16* Ab = sm + cur * 32768;
    const __bf16* Bb = Ab + 16384;
    bf16x8 bfv[4][2];
#pragma unroll
    for (int nj = 0; nj < 4; ++nj)
#pragma unroll
      for (int kk = 0; kk < 2; ++kk) {
        const int row = wn * 64 + nj * 16 + lcol;
        bfv[nj][kk] = *(const bf16x8*)&Bb[row * 64 + (((kk * 4 + lk) ^ (row & 7)) * 8)];
      }
    __builtin_amdgcn_s_setprio(1);
#pragma unroll
    for (int mi = 0; mi < 8; ++mi) {
      const int row = wm * 128 + mi * 16 + lcol;
      bf16x8 a0 = *(const bf16x8*)&Ab[row * 64 + ((lk ^ (row & 7)) * 8)];
      bf16x8 a1 = *(const bf16x8*)&Ab[row * 64 + (((4 + lk) ^ (row & 7)) * 8)];
#pragma unroll
      for (int nj = 0; nj < 4; ++nj) {
        acc[mi][nj] = __builtin_amdgcn_mfma_f32_16x16x32_bf16(a0, bfv[nj][0], acc[mi][nj], 0, 0, 0);
        acc[mi][nj] = __builtin_amdgcn_mfma_f32_16x16x32_bf16(a1, bfv[nj][1], acc[mi][nj], 0, 0, 0);
      }
    }
    __builtin_amdgcn_s_setprio(0);
    cur ^= 1;
  }
#pragma unroll
  for (int mi = 0; mi < 8; ++mi)
#pragma unroll
    for (int nj = 0; nj < 4; ++nj) {
      const int col = nBase + wn * 64 + nj * 16 + lcol;
      const int row0 = mBase + wm * 128 + mi * 16 + lk * 4;
#pragma unroll
      for (int jj = 0; jj < 4; ++jj) {
        float v = acc[mi][nj][jj];
        if constexpr (MODE == 1) v = gelu_exact(v + bias[col]);
        Cb[(size_t)(row0 + jj) * N + col] = (__bf16)v;
      }
    }
}

// ---------------- MFMA rel-pos attention v8 + setprio on MFMA clusters ----------------
__global__ __launch_bounds__(256)
void attn8(const __bf16* __restrict__ qk, const __bf16* __restrict__ vT,
           const __bf16* __restrict__ kpos, const float* __restrict__ rwbias,
           const float* __restrict__ rrbias, __bf16* __restrict__ av) {
  constexpr float ALPHA = 0.125f * 1.44269504088896f;
  constexpr int PB = 132;
  __shared__ __align__(16) char smem[74240];
  __bf16* sP  = (__bf16*)(smem + 49152);
  __bf16* sbd = (__bf16*)(smem + 57344);

  const int flat = blockIdx.x;
  const int xcd = flat & 7, rr_ = flat >> 3;
  const int bn = xcd * 8 + (rr_ >> 4);
  const int it = rr_ & 15;
  const int b = bn >> 4, n = bn & 15;
  const int i0 = it * 64;
  const int tid = threadIdx.x;
  const int l = tid & 63;
  const int lcol = l & 15, lk = l >> 4;
  const int strip = (tid >> 6) * 16;
  const int wbase = tid & 192;
  const int nh64 = n * 64;
  const int q = strip + lcol;

  const int rB = tid >> 3;
  const int cs8 = ((tid & 7) ^ (rB & 7)) * 8;

  bf16x8 onesf;
#pragma unroll
  for (int u = 0; u < 8; ++u) onesf[u] = (__bf16)1.0f;

  bf16x8 qac[2], qlo[2], qhi[2];
  {
    const __bf16* qrow = qk + ((size_t)(b * 1024 + i0 + q)) * 2048 + nh64;
    int gH = i0 + q + 1; gH = gH < 1024 ? gH : 1023;
    const __bf16* qrowH = qk + ((size_t)(b * 1024 + gH)) * 2048 + nh64;
#pragma unroll
    for (int kk = 0; kk < 2; ++kk) {
      bf16x8 qv = *(const bf16x8*)(qrow + kk * 32 + lk * 8);
      bf16x8 qh = *(const bf16x8*)(qrowH + kk * 32 + lk * 8);
      const int dbase = nh64 + kk * 32 + lk * 8;
#pragma unroll
      for (int u = 0; u < 8; ++u) {
        const float rb = rrbias[dbase + u];
        qac[kk][u] = (__bf16)(((float)qv[u] + rwbias[dbase + u]) * ALPHA);
        qlo[kk][u] = (__bf16)(((float)qv[u] + rb) * ALPHA);
        qhi[kk][u] = (__bf16)(((float)qh[u] + rb) * ALPHA);
      }
    }
  }

#pragma unroll
  for (int kq = 0; kq < 2; ++kq) {
    const int r = kq * 32 + rB;
    const int dst = (kq * 256 + wbase) * 8;
    gload_lds16(kpos + ((size_t)((960 - i0 + r) * 4 + b)) * 1024 + nh64 + cs8,
                (__bf16*)(smem + 40960) + dst);
    gload_lds16(qk + ((size_t)(b * 1024 + r)) * 2048 + 1024 + nh64 + cs8,
                (__bf16*)(smem) + dst);
    const int rrel = r - i0;
    const int idx = (rrel <= 0) ? (1024 + rrel) : (rrel - 1);
    gload_lds16(kpos + ((size_t)(idx * 4 + b)) * 1024 + nh64 + cs8,
                (__bf16*)(smem + 16384) + dst);
    gload_lds16(vT + ((size_t)(nh64 + r)) * 4096 + b * 1024 + cs8,
                (__bf16*)(smem + 32768) + dst);
  }
  __syncthreads();
  {
    __bf16* kpl = (__bf16*)(smem + 40960);
    const int colb0 = (-i0 - 64) & 127;
#pragma unroll
    for (int fb = 0; fb < 4; ++fb) {
      const int row = fb * 16 + lcol;
      f32x4 g = {};
#pragma unroll
      for (int kk = 0; kk < 2; ++kk) {
        bf16x8 a = *(const bf16x8*)&kpl[row * 64 + (((kk * 4 + lk) ^ (lcol & 7)) * 8)];
        g = __builtin_amdgcn_mfma_f32_16x16x32_bf16(a, qlo[kk], g, 0, 0, 0);
      }
      bf16x4 gw = {(__bf16)g[0], (__bf16)g[1], (__bf16)g[2], (__bf16)g[3]};
      *(bf16x4*)&sbd[q * PB + ((colb0 + fb * 16 + lk * 4) & 127)] = gw;
    }
  }
  __syncthreads();

  f32x4 oacc[4] = {};
  f32x4 zq = {};
  size_t kS = (size_t)(b * 1024 + 64 + rB) * 2048 + 1024 + nh64 + cs8;
  size_t vS = (size_t)(nh64 + rB) * 4096 + b * 1024 + 64 + cs8;

#pragma unroll 1
  for (int jt = 0; jt < 16; ++jt) {
    const int cur = jt & 1, nxt = cur ^ 1;
    const int d0 = jt * 64 - i0;
    __bf16* sK   = (__bf16*)(smem + cur * 8192);
    __bf16* sKn  = (__bf16*)(smem + nxt * 8192);
    __bf16* sKP  = (__bf16*)(smem + 16384 + cur * 8192);
    __bf16* sKPn = (__bf16*)(smem + 16384 + nxt * 8192);
    __bf16* sVT  = (__bf16*)(smem + 32768 + cur * 8192);
    __bf16* sVTn = (__bf16*)(smem + 32768 + nxt * 8192);
#pragma unroll
    for (int kq = 0; kq < 2; ++kq) {
      const int dst = (kq * 256 + wbase) * 8;
      gload_lds16(qk + kS + kq * 65536, sKn + dst);
      gload_lds16(vT + vS + kq * 131072, sVTn + dst);
      const int rreln = d0 + 64 + kq * 32 + rB;
      const int idx = (rreln <= 0) ? (1024 + rreln) : (rreln - 1);
      gload_lds16(kpos + ((size_t)(idx * 4 + b)) * 1024 + nh64 + cs8, sKPn + dst);
    }
    kS += 131072; vS += 64;
    {
      const bf16x8 qg0 = (d0 >= 0) ? qhi[0] : qlo[0];
      const bf16x8 qg1 = (d0 >= 0) ? qhi[1] : qlo[1];
      __builtin_amdgcn_s_setprio(1);
#pragma unroll
      for (int fb = 0; fb < 4; ++fb) {
        const int row = fb * 16 + lcol;
        f32x4 g = {};
        g = __builtin_amdgcn_mfma_f32_16x16x32_bf16(
            *(const bf16x8*)&sKP[row * 64 + ((lk ^ (lcol & 7)) * 8)], qg0, g, 0, 0, 0);
        g = __builtin_amdgcn_mfma_f32_16x16x32_bf16(
            *(const bf16x8*)&sKP[row * 64 + (((4 + lk) ^ (lcol & 7)) * 8)], qg1, g, 0, 0, 0);
        bf16x4 gw = {(__bf16)g[0], (__bf16)g[1], (__bf16)g[2], (__bf16)g[3]};
        *(bf16x4*)&sbd[q * PB + ((d0 + fb * 16 + lk * 4) & 127)] = gw;
      }
      __builtin_amdgcn_s_setprio(0);
      if (d0 == 0) {
        const int cl = tid >> 2, part = tid & 3;
        const __bf16* qs = qk + ((size_t)(b * 1024 + i0 + cl)) * 2048 + nh64 + part * 16;
        bf16x8 a0 = *(const bf16x8*)qs;
        bf16x8 a1 = *(const bf16x8*)(qs + 8);
        bf16x8 k0 = *(const bf16x8*)&sKP[(2 * part) * 8];
        bf16x8 k1 = *(const bf16x8*)&sKP[(2 * part + 1) * 8];
        float s64 = 0.f;
#pragma unroll
        for (int u = 0; u < 8; ++u)
          s64 += ((float)a0[u] + rrbias[nh64 + part * 16 + u]) * (float)k0[u]
               + ((float)a1[u] + rrbias[nh64 + part * 16 + 8 + u]) * (float)k1[u];
        s64 += __shfl_xor(s64, 1, 64);
        s64 += __shfl_xor(s64, 2, 64);
        if (part == 0) sbd[cl * PB] = (__bf16)(s64 * ALPHA);
      }
    }
    f32x4 sc[4];
    __builtin_amdgcn_s_setprio(1);
#pragma unroll
    for (int fk = 0; fk < 4; ++fk) {
      const int row = fk * 16 + lcol;
      f32x4 a = {};
#pragma unroll
      for (int kk = 0; kk < 2; ++kk) {
        bf16x8 kf = *(const bf16x8*)&sK[row * 64 + (((kk * 4 + lk) ^ (lcol & 7)) * 8)];
        a = __builtin_amdgcn_mfma_f32_16x16x32_bf16(kf, qac[kk], a, 0, 0, 0);
      }
      sc[fk] = a;
    }
    __builtin_amdgcn_s_setprio(0);
    {
      const int rowb = q * PB;
      const int sb = d0 - q;
#pragma unroll
      for (int fk = 0; fk < 4; ++fk) {
        const int cb = sb + fk * 16 + lk * 4;
        float e0 = exp2f(sc[fk][0] + (float)sbd[rowb + ((cb) & 127)]);
        float e1 = exp2f(sc[fk][1] + (float)sbd[rowb + ((cb + 1) & 127)]);
        float e2 = exp2f(sc[fk][2] + (float)sbd[rowb + ((cb + 2) & 127)]);
        float e3 = exp2f(sc[fk][3] + (float)sbd[rowb + ((cb + 3) & 127)]);
        bf16x4 pw = {(__bf16)e0, (__bf16)e1, (__bf16)e2, (__bf16)e3};
        *(bf16x4*)&sP[q * 64 + (((fk * 2 + (lk >> 1)) ^ (q & 7)) * 8) + (lk & 1) * 4] = pw;
      }
    }
    __builtin_amdgcn_s_setprio(1);
#pragma unroll
    for (int kk = 0; kk < 2; ++kk) {
      bf16x8 pa = *(const bf16x8*)&sP[q * 64 + (((kk * 4 + lk) ^ (q & 7)) * 8)];
      zq = __builtin_amdgcn_mfma_f32_16x16x32_bf16(pa, onesf, zq, 0, 0, 0);
#pragma unroll
      for (int fd = 0; fd < 4; ++fd) {
        const int vrow = fd * 16 + lcol;
        bf16x8 bv = *(const bf16x8*)&sVT[vrow * 64 + (((kk * 4 + lk) ^ (lcol & 7)) * 8)];
        oacc[fd] = __builtin_amdgcn_mfma_f32_16x16x32_bf16(pa, bv, oacc[fd], 0, 0, 0);
      }
    }
    __builtin_amdgcn_s_setprio(0);
    __syncthreads();
  }
#pragma unroll
  for (int jj = 0; jj < 4; ++jj) {
    const float rz = 1.f / zq[jj];
    const int ig = i0 + strip + lk * 4 + jj;
    __bf16* dst = av + ((size_t)(ig * 4 + b)) * 1024 + nh64;
#pragma unroll
    for (int fd = 0; fd < 4; ++fd)
      dst[fd * 16 + lcol] = (__bf16)(oacc[fd][jj] * rz);
  }
}

// ---------------- fused residual + LayerNorm (2 or 4 bf16 partial addends) ----------------
__global__ __launch_bounds__(256)
void ln_fuse(const float* __restrict__ A, const __bf16* __restrict__ P0,
             const __bf16* __restrict__ P1, const __bf16* __restrict__ P2,
             const __bf16* __restrict__ P3, const float* __restrict__ cb,
             const float* __restrict__ g, const float* __restrict__ be,
             float* __restrict__ oF, __bf16* __restrict__ oB) {
  const int row = blockIdx.x, t = threadIdx.x;
  const size_t base = (size_t)row * 1024 + t * 4;
  const float4 a = *(const float4*)(A + base);
  const bf16x4 p0 = *(const bf16x4*)(P0 + base);
  const bf16x4 p1 = *(const bf16x4*)(P1 + base);
  float x0 = a.x + (float)p0[0] + (float)p1[0];
  float x1 = a.y + (float)p0[1] + (float)p1[1];
  float x2 = a.z + (float)p0[2] + (float)p1[2];
  float x3 = a.w + (float)p0[3] + (float)p1[3];
  if (P2) {
    const bf16x4 p2 = *(const bf16x4*)(P2 + base);
    const bf16x4 p3 = *(const bf16x4*)(P3 + base);
    x0 += (float)p2[0] + (float)p3[0];
    x1 += (float)p2[1] + (float)p3[1];
    x2 += (float)p2[2] + (float)p3[2];
    x3 += (float)p2[3] + (float)p3[3];
  }
  if (cb) {
    const float4 c = *(const float4*)(cb + t * 4);
    x0 += c.x; x1 += c.y; x2 += c.z; x3 += c.w;
  }
  float s = x0 + x1 + x2 + x3;
  float qq = x0 * x0 + x1 * x1 + x2 * x2 + x3 * x3;
#pragma unroll
  for (int o = 1; o < 64; o <<= 1) { s += __shfl_xor(s, o, 64); qq += __shfl_xor(qq, o, 64); }
  __shared__ float ss[4], qs[4];
  if ((t & 63) == 0) { ss[t >> 6] = s; qs[t >> 6] = qq; }
  __syncthreads();
  s = ss[0] + ss[1] + ss[2] + ss[3];
  qq = qs[0] + qs[1] + qs[2] + qs[3];
  const float mean = s * (1.f / 1024.f);
  const float var = qq * (1.f / 1024.f) - mean * mean;
  const float rstd = rsqrtf(var + 1e-5f);
  const float4 gv = *(const float4*)(g + t * 4);
  const float4 bev = *(const float4*)(be + t * 4);
  const float y0 = (x0 - mean) * rstd * gv.x + bev.x;
  const float y1 = (x1 - mean) * rstd * gv.y + bev.y;
  const float y2 = (x2 - mean) * rstd * gv.z + bev.z;
  const float y3 = (x3 - mean) * rstd * gv.w + bev.w;
  if (oF) {
    float4 r = {y0, y1, y2, y3};
    *(float4*)(oF + base) = r;
  }
  if (oB) {
    bf16x4 o4 = {(__bf16)y0, (__bf16)y1, (__bf16)y2, (__bf16)y3};
    *(bf16x4*)(oB + base) = o4;
  }
}

extern "C" void kernel_launch(void* const* d_in, const int* in_sizes, int n_in,
                              void* d_out, int out_size, void* d_ws, size_t ws_size,
                              hipStream_t stream) {
  const float* src    = (const float*)d_in[0];
  const float* pos    = (const float*)d_in[1];
  const float* qw     = (const float*)d_in[3];
  const float* kw     = (const float*)d_in[4];
  const float* vw     = (const float*)d_in[5];
  const float* rw     = (const float*)d_in[6];
  const float* ow     = (const float*)d_in[7];
  const float* rwbias = (const float*)d_in[8];
  const float* rrbias = (const float*)d_in[9];
  const float* w1     = (const float*)d_in[10];
  const float* b1     = (const float*)d_in[11];
  const float* w2     = (const float*)d_in[12];
  const float* b2     = (const float*)d_in[13];
  const float* g1     = (const float*)d_in[14];
  const float* be1    = (const float*)d_in[15];
  const float* g2     = (const float*)d_in[16];
  const float* be2    = (const float*)d_in[17];
  float* out = (float*)d_out;

  char* p = (char*)d_ws;
  auto alloc = [&](size_t bytes) { char* r = p; p += (bytes + 255) & ~(size_t)255; return r; };
  __bf16* qkB   = (__bf16*)alloc(4096ull * 2048 * 2);   // dead after attn
  __bf16* vTB   = (__bf16*)alloc(1024ull * 4096 * 2);   // dead after attn
  __bf16* kposB = (__bf16*)alloc(4100ull * 1024 * 2);   // dead after attn
  __bf16* avB   = (__bf16*)alloc(4096ull * 1024 * 2);   // dead after attn-out
  __bf16* srcB2 = (__bf16*)alloc(4096ull * 1024 * 2);   // dead after projections
  __bf16* posB  = (__bf16*)alloc(4100ull * 1024 * 2);   // dead after proj2
  float*  xF    = (float*)alloc(4096ull * 1024 * 4);
  __bf16* w2B   = (__bf16*)alloc(4096ull * 1024 * 2);
  __bf16* qkvT  = (__bf16*)alloc(3072ull * 1024 * 2);
  __bf16* rwT   = (__bf16*)alloc(1024ull * 1024 * 2);
  __bf16* owB   = (__bf16*)alloc(1024ull * 1024 * 2);
  __bf16* w1B   = (__bf16*)alloc(4096ull * 1024 * 2);   // dead after FFN1
  __bf16* xB    = (__bf16*)alloc(4096ull * 1024 * 2);   // dead after FFN1
  // aliases (disjoint lifetimes):
  __bf16* gB   = qkB;            // gelu 32MB over qkB+vTB+kposB
  __bf16* aoP0 = srcB2;          // attn-out bf16 partial0
  __bf16* aoP1 = posB;           // attn-out bf16 partial1
  __bf16* ffP0 = avB;            // ffn2 bf16 partial0 (dead after attn-out)
  __bf16* ffP1 = w1B;            // ffn2 bf16 partial1 (dead after FFN1)
  __bf16* ffP2 = kposB;          // ffn2 bf16 partial2 (dead after attn; gB uses qkB+vTB only... )
  __bf16* ffP3 = xB;             // ffn2 bf16 partial3 (dead after FFN1)

  // NOTE: gB spans qkB..(qkB+32MB) = qkB(16MB)+vTB(8MB)+kposB(8MB region start).
  // gB actually needs 4096*4096*2 = 32MB: qkB 16MB + vTB 8MB + kposB 8MB -> kposB IS
  // part of gB. So ffP2 must NOT alias kposB. Use owB? owB is 2MB (too small).
  // Use the tail region: qkvT (6MB) + rwT (2MB) = 8MB contiguous, both dead after proj2.
  ffP2 = qkvT;

  prep_all<<<11521, 256, 0, stream>>>(src, srcB2, pos, posB, ow, owB, w1, w1B,
                                      w2, w2B, qw, kw, vw, rw, qkvT, rwT);
  gemm256<2><<<dim3(16, 16), 512, 0, stream>>>(srcB2, qkvT, qkB, nullptr, 4096, 2048, 1024);
  proj2_kernel<<<1040, 256, 0, stream>>>(qkvT + 2048 * 1024, srcB2, posB, rwT, vTB, kposB);
  attn8<<<dim3(1024), 256, 0, stream>>>(qkB, vTB, kposB, rwbias, rrbias, avB);
  gemm_bt<128, 64, 2><<<dim3(16, 32, 2), 256, 0, stream>>>(avB, owB, nullptr, aoP0, aoP1, nullptr, 4096, 1024, 1024, 512);
  ln_fuse<<<4096, 256, 0, stream>>>(src, aoP0, aoP1, nullptr, nullptr, nullptr, g1, be1, xF, xB);
  gemm512<1><<<dim3(16, 16), 512, 0, stream>>>(xB, w1B, gB, nullptr, nullptr, nullptr, b1, 4096, 4096, 1024, 1024);
  gemm512<2><<<dim3(4, 16, 4), 512, 0, stream>>>(gB, w2B, ffP0, ffP1, ffP2, ffP3, nullptr, 4096, 1024, 4096, 1024);
  ln_fuse<<<4096, 256, 0, stream>>>(xF, ffP0, ffP1, ffP2, ffP3, b2, g2, be2, out, nullptr);
  (void)in_sizes; (void)n_in; (void)out_size; (void)ws_size;
}

// Round 15
// 286.156 us; speedup vs baseline: 1.1143x; 1.0159x over previous
//
#include <hip/hip_runtime.h>
#include <math.h>

typedef __bf16 bf16x8 __attribute__((ext_vector_type(8)));
typedef __bf16 bf16x4 __attribute__((ext_vector_type(4)));
typedef float f32x4 __attribute__((ext_vector_type(4)));

__device__ __forceinline__ void gload_lds16(const __bf16* g, __bf16* l) {
  __builtin_amdgcn_global_load_lds((const __attribute__((address_space(1))) void*)g,
                                   (__attribute__((address_space(3))) void*)l, 16, 0, 0);
}

__device__ __forceinline__ float gelu_exact(float v) {
  return 0.5f * v * (1.f + erff(v * 0.70710678118654752f));
}

// ---------------- fused prep: perm-src | 4x cvt | 4x transpose-cvt ----------------
__global__ __launch_bounds__(256) void prep_all(
    const float* __restrict__ src, __bf16* __restrict__ srcB2,
    const float* __restrict__ pos, __bf16* __restrict__ posB,
    const float* __restrict__ ow, __bf16* __restrict__ owB,
    const float* __restrict__ w1, __bf16* __restrict__ w1B,
    const float* __restrict__ w2, __bf16* __restrict__ w2B,
    const float* __restrict__ qw, const float* __restrict__ kw,
    const float* __restrict__ vw, const float* __restrict__ rw,
    __bf16* __restrict__ qkvT, __bf16* __restrict__ rwT) {
  __shared__ float t[32][33];
  int bid = blockIdx.x;
  const int tid = threadIdx.x;
  if (bid < 4096) {                       // src (i,b)-rows -> bf16 (b,i)-rows
    const int i = bid & 1023, b = bid >> 10;
    const float4 v = *(const float4*)(src + ((size_t)(i * 4 + b)) * 1024 + tid * 4);
    bf16x4 o = {(__bf16)v.x, (__bf16)v.y, (__bf16)v.z, (__bf16)v.w};
    *(bf16x4*)(srcB2 + (size_t)bid * 1024 + tid * 4) = o;
    return;
  }
  bid -= 4096;
  if (bid < 3329) {                       // straight converts
    const float* in; __bf16* out;
    if (bid < 1025) { in = pos; out = posB; }
    else if (bid < 1281) { bid -= 1025; in = ow; out = owB; }
    else if (bid < 2305) { bid -= 1281; in = w1; out = w1B; }
    else { bid -= 2305; in = w2; out = w2B; }
    const int base = bid * 4096 + tid * 4;
#pragma unroll
    for (int k2 = 0; k2 < 4; ++k2) {
      const int off = base + k2 * 1024;
      float4 v = *(const float4*)(in + off);
      bf16x4 o = {(__bf16)v.x, (__bf16)v.y, (__bf16)v.z, (__bf16)v.w};
      *(bf16x4*)(out + off) = o;
    }
    return;
  }
  bid -= 3329;                            // transpose-converts (4x 1024x1024)
  const int z = bid >> 10, rem = bid & 1023;
  const float* in; __bf16* out;
  switch (z) {
    case 0: in = qw; out = qkvT; break;
    case 1: in = kw; out = qkvT + 1024 * 1024; break;
    case 2: in = vw; out = qkvT + 2048 * 1024; break;
    default: in = rw; out = rwT; break;
  }
  const int c0 = (rem & 31) * 32, r0 = (rem >> 5) * 32;
  const int tx = tid & 31, ty = tid >> 5;
  for (int yy = ty; yy < 32; yy += 8)
    t[yy][tx] = in[(size_t)(r0 + yy) * 1024 + c0 + tx];
  __syncthreads();
  for (int yy = ty; yy < 32; yy += 8)
    out[(size_t)(c0 + yy) * 1024 + r0 + tx] = (__bf16)t[tx][yy];
}

// ---------------- bf16 MFMA GEMM body (2-phase, 128x64) ----------------
template<int BM, int BN, int MODE>
__device__ __forceinline__ void gemm_body(
    const __bf16* __restrict__ A, const __bf16* __restrict__ BT,
    float* __restrict__ Cf, __bf16* __restrict__ Cb,
    const float* __restrict__ bias, int M, int N, int K,
    int kStart, int kChunk, int mBase, int nBase, char* smemRaw) {
  constexpr int BK = 32;
  constexpr int ALOAD = (BM * BK) / 2048;
  constexpr int BLOAD = (BN * BK) / 2048;
  __bf16* lA = (__bf16*)smemRaw;                       // [2][BM*BK]
  __bf16* lB = (__bf16*)(smemRaw + 4 * BM * BK);       // [2][BN*BK]
  const int tid = threadIdx.x;
  const int w = tid >> 6, l = tid & 63;
  const int lr = l & 15, lk = l >> 4;
  const int srow = tid >> 2;
  const int scol = (tid & 3) * 8;
  const int wbase = w * 512;

  const __bf16* aSrc[ALOAD];
  const __bf16* bSrc[BLOAD];
#pragma unroll
  for (int i = 0; i < ALOAD; ++i) {
    int grow = mBase + srow + i * 64;
    grow = grow < M ? grow : M - 1;
    aSrc[i] = A + (size_t)grow * K + kStart + scol;
  }
#pragma unroll
  for (int i = 0; i < BLOAD; ++i) {
    const int grow = nBase + srow + i * 64;
    bSrc[i] = BT + (size_t)grow * K + kStart + scol;
  }
  auto stage = [&](int buf) {
#pragma unroll
    for (int i = 0; i < ALOAD; ++i) {
      gload_lds16(aSrc[i], &lA[buf * BM * BK + i * 2048 + wbase]);
      aSrc[i] += BK;
    }
#pragma unroll
    for (int i = 0; i < BLOAD; ++i) {
      gload_lds16(bSrc[i], &lB[buf * BN * BK + i * 2048 + wbase]);
      bSrc[i] += BK;
    }
  };

  constexpr int WM = BM / 2, WN = BN / 2;
  constexpr int MF = WM / 16, NF = WN / 16;
  const int wr = w >> 1, wc = w & 1;
  f32x4 acc[MF][NF] = {};

  const int nIter = kChunk / BK;
  stage(0);
  int cur = 0;
#pragma unroll 1
  for (int t = 0; t < nIter; ++t) {
    __syncthreads();
    if (t + 1 < nIter) stage(cur ^ 1);
    bf16x8 af[MF], bfr[NF];
#pragma unroll
    for (int mi = 0; mi < MF; ++mi)
      af[mi] = *(const bf16x8*)&lA[cur * BM * BK + (wr * WM + mi * 16 + lr) * BK + lk * 8];
#pragma unroll
    for (int nj = 0; nj < NF; ++nj)
      bfr[nj] = *(const bf16x8*)&lB[cur * BN * BK + (wc * WN + nj * 16 + lr) * BK + lk * 8];
#pragma unroll
    for (int mi = 0; mi < MF; ++mi)
#pragma unroll
      for (int nj = 0; nj < NF; ++nj)
        acc[mi][nj] = __builtin_amdgcn_mfma_f32_16x16x32_bf16(af[mi], bfr[nj], acc[mi][nj], 0, 0, 0);
    cur ^= 1;
  }
#pragma unroll
  for (int mi = 0; mi < MF; ++mi) {
#pragma unroll
    for (int nj = 0; nj < NF; ++nj) {
      const int col = nBase + wc * WN + nj * 16 + lr;
      const int row0 = mBase + wr * WM + mi * 16 + lk * 4;
#pragma unroll
      for (int j = 0; j < 4; ++j) {
        const int row = row0 + j;
        if (row < M) {
          float v = acc[mi][nj][j];
          if constexpr (MODE == 1) {
            v = gelu_exact(v + bias[col]);
            Cb[(size_t)row * N + col] = (__bf16)v;
          } else if constexpr (MODE == 2) {
            Cb[(size_t)row * N + col] = (__bf16)v;
          } else {
            Cf[(size_t)row * N + col] = v;
          }
        }
      }
    }
  }
}

// ---- vT + kpos projections in one launch (1040 blocks, XCD-chunked) ----
__global__ __launch_bounds__(256)
void proj2_kernel(const __bf16* __restrict__ vwT, const __bf16* __restrict__ srcB2,
                  const __bf16* __restrict__ posB, const __bf16* __restrict__ rwT,
                  __bf16* __restrict__ vTB, __bf16* __restrict__ kposB) {
  __shared__ __align__(16) char smem[4 * (128 + 64) * 32];
  const int raw = blockIdx.x;
  int bid = (raw & 7) * 130 + (raw >> 3);   // 1040/8 = 130 per XCD
  if (bid < 512) {
    gemm_body<128, 64, 2>(vwT, srcB2, nullptr, vTB, nullptr, 1024, 4096, 1024,
                          0, 1024, (bid >> 6) * 128, (bid & 63) * 64, smem);
  } else {
    const int t = bid - 512;
    gemm_body<128, 64, 2>(posB, rwT, nullptr, kposB, nullptr, 4100, 1024, 1024,
                          0, 1024, (t >> 4) * 128, (t & 15) * 64, smem);
  }
}

// ---------------- 256x128-tile deep-pipeline GEMM (3-side counted-vmcnt) ----------------
template<int MODE>
__global__ __launch_bounds__(512)
void gemm256(const __bf16* __restrict__ A, const __bf16* __restrict__ BT,
             __bf16* __restrict__ Cb, const float* __restrict__ bias,
             int M, int N, int K) {
  __shared__ __align__(16) __bf16 sm[3 * 24576];
  const int tid = threadIdx.x;
  const int wid = tid >> 6, l = tid & 63;
  const int lcol = l & 15, lk = l >> 4;
  const int wm = wid >> 1, wn = wid & 1;
  const int gx = gridDim.x;
  const int G = gx * gridDim.y;
  const int flat = blockIdx.y * gx + blockIdx.x;
  const int band = G >> 3;
  const int x8 = flat & 7, loc = flat >> 3;
  const int rpb = band / gx;
  const int ny = x8 * rpb + loc % rpb;
  const int nx = loc / rpb;
  const int mBase = ny * 256, nBase = nx * 128;

  int rowj[2], gslotj[2];
#pragma unroll
  for (int j = 0; j < 2; ++j) {
    const int u = (wid * 2 + j) * 64 + l;
    rowj[j] = u >> 3;
    gslotj[j] = (u & 7) ^ (rowj[j] & 7);
  }
  auto issueHT = [&](int kt, int ht, int side) {
    __bf16* base = sm + side * 24576 + (ht == 2 ? 16384 : ht * 8192);
#pragma unroll
    for (int j = 0; j < 2; ++j) {
      const __bf16* src = (ht < 2)
        ? A + (size_t)(mBase + ht * 128 + rowj[j]) * K + kt * 64 + gslotj[j] * 8
        : BT + (size_t)(nBase + rowj[j]) * K + kt * 64 + gslotj[j] * 8;
      gload_lds16(src, base + (wid * 2 + j) * 512);
    }
  };

  const int nkt = K >> 6;
  issueHT(0, 0, 0); issueHT(0, 1, 0); issueHT(0, 2, 0);
  issueHT(1, 0, 1); issueHT(1, 1, 1); issueHT(1, 2, 1);

  f32x4 acc[4][4] = {};
#pragma unroll 1
  for (int j = 0; j < nkt; ++j) {
    asm volatile("s_waitcnt vmcnt(6)" ::: "memory");
    __builtin_amdgcn_s_barrier();
    __builtin_amdgcn_sched_barrier(0);
    const int side = j % 3;
    const int sn = (j + 2) % 3;
    const int ktn = (j + 2 < nkt) ? j + 2 : nkt - 1;
    const __bf16* Ab = sm + side * 24576;
    const __bf16* Bb = Ab + 16384;
    issueHT(ktn, 0, sn);
    bf16x8 af[4][2];
#pragma unroll
    for (int mi = 0; mi < 4; ++mi)
#pragma unroll
      for (int kk = 0; kk < 2; ++kk) {
        const int row = wm * 64 + mi * 16 + lcol;
        af[mi][kk] = *(const bf16x8*)&Ab[row * 64 + (((kk * 4 + lk) ^ (row & 7)) * 8)];
      }
    issueHT(ktn, 1, sn);
    bf16x8 bfv[4][2];
#pragma unroll
    for (int nj = 0; nj < 4; ++nj)
#pragma unroll
      for (int kk = 0; kk < 2; ++kk) {
        const int row = wn * 64 + nj * 16 + lcol;
        bfv[nj][kk] = *(const bf16x8*)&Bb[row * 64 + (((kk * 4 + lk) ^ (row & 7)) * 8)];
      }
    issueHT(ktn, 2, sn);
    __builtin_amdgcn_s_setprio(1);
#pragma unroll
    for (int mi = 0; mi < 4; ++mi)
#pragma unroll
      for (int nj = 0; nj < 4; ++nj) {
        acc[mi][nj] = __builtin_amdgcn_mfma_f32_16x16x32_bf16(af[mi][0], bfv[nj][0], acc[mi][nj], 0, 0, 0);
        acc[mi][nj] = __builtin_amdgcn_mfma_f32_16x16x32_bf16(af[mi][1], bfv[nj][1], acc[mi][nj], 0, 0, 0);
      }
    __builtin_amdgcn_s_setprio(0);
  }
#pragma unroll
  for (int mi = 0; mi < 4; ++mi)
#pragma unroll
    for (int nj = 0; nj < 4; ++nj) {
      const int col = nBase + wn * 64 + nj * 16 + lcol;
      const int row0 = mBase + wm * 64 + mi * 16 + lk * 4;
#pragma unroll
      for (int jj = 0; jj < 4; ++jj) {
        float v = acc[mi][nj][jj];
        if constexpr (MODE == 1) v = gelu_exact(v + bias[col]);
        Cb[(size_t)(row0 + jj) * N + col] = (__bf16)v;
      }
    }
}

// ---------------- 256x256-tile GEMM, BK=64, 8 waves of 128x64 (LDS-BW optimal) ----------
// Split-K: gridDim.z selects kStart and partial output Cb[z]. bf16 out.
template<int MODE>
__global__ __launch_bounds__(512)
void gemm512(const __bf16* __restrict__ A, const __bf16* __restrict__ BT,
             __bf16* __restrict__ Cb0, __bf16* __restrict__ Cb1,
             __bf16* __restrict__ Cb2, __bf16* __restrict__ Cb3,
             const float* __restrict__ bias, int M, int N, int K, int kChunk) {
  __shared__ __align__(16) __bf16 sm[2 * 32768];
  const int tid = threadIdx.x;
  const int w = tid >> 6, l = tid & 63;
  const int lcol = l & 15, lk = l >> 4;
  const int wm = w >> 2, wn = w & 3;          // 2 x 4 waves, wave tile 128x64
  const int gx = gridDim.x;
  const int G = gx * gridDim.y;
  const int flat = blockIdx.y * gx + blockIdx.x;
  const int band = G >> 3;
  const int x8 = flat & 7, loc = flat >> 3;
  const int rpb = band / gx;
  const int ny = x8 * rpb + loc % rpb;
  const int nx = loc / rpb;
  const int mBase = ny * 256, nBase = nx * 256;
  const int kStart = blockIdx.z * kChunk;
  __bf16* Cb = (blockIdx.z == 0) ? Cb0 : (blockIdx.z == 1) ? Cb1
             : (blockIdx.z == 2) ? Cb2 : Cb3;

  const int rT = tid >> 3;                    // 0..63
  const int gslot = ((tid & 7) ^ (rT & 7)) * 8;
  auto stage = [&](int side, int kt) {
#pragma unroll
    for (int i = 0; i < 4; ++i) {
      gload_lds16(A + (size_t)(mBase + i * 64 + rT) * K + kStart + kt * 64 + gslot,
                  sm + side * 32768 + i * 4096 + w * 512);
      gload_lds16(BT + (size_t)(nBase + i * 64 + rT) * K + kStart + kt * 64 + gslot,
                  sm + side * 32768 + 16384 + i * 4096 + w * 512);
    }
  };

  f32x4 acc[8][4] = {};
  const int nIter = kChunk >> 6;
  stage(0, 0);
  int cur = 0;
#pragma unroll 1
  for (int t = 0; t < nIter; ++t) {
    __syncthreads();                           // side cur complete (drains vmcnt)
    if (t + 1 < nIter) stage(cur ^ 1, t + 1);
    const __bf16* Ab = sm + cur * 32768;
    const __bf16* Bb = Ab + 16384;
    bf16x8 bfv[4][2];
#pragma unroll
    for (int nj = 0; nj < 4; ++nj)
#pragma unroll
      for (int kk = 0; kk < 2; ++kk) {
        const int row = wn * 64 + nj * 16 + lcol;
        bfv[nj][kk] = *(const bf16x8*)&Bb[row * 64 + (((kk * 4 + lk) ^ (row & 7)) * 8)];
      }
    __builtin_amdgcn_s_setprio(1);
#pragma unroll
    for (int mi = 0; mi < 8; ++mi) {
      const int row = wm * 128 + mi * 16 + lcol;
      bf16x8 a0 = *(const bf16x8*)&Ab[row * 64 + ((lk ^ (row & 7)) * 8)];
      bf16x8 a1 = *(const bf16x8*)&Ab[row * 64 + (((4 + lk) ^ (row & 7)) * 8)];
#pragma unroll
      for (int nj = 0; nj < 4; ++nj) {
        acc[mi][nj] = __builtin_amdgcn_mfma_f32_16x16x32_bf16(a0, bfv[nj][0], acc[mi][nj], 0, 0, 0);
        acc[mi][nj] = __builtin_amdgcn_mfma_f32_16x16x32_bf16(a1, bfv[nj][1], acc[mi][nj], 0, 0, 0);
      }
    }
    __builtin_amdgcn_s_setprio(0);
    cur ^= 1;
  }
#pragma unroll
  for (int mi = 0; mi < 8; ++mi)
#pragma unroll
    for (int nj = 0; nj < 4; ++nj) {
      const int col = nBase + wn * 64 + nj * 16 + lcol;
      const int row0 = mBase + wm * 128 + mi * 16 + lk * 4;
#pragma unroll
      for (int jj = 0; jj < 4; ++jj) {
        float v = acc[mi][nj][jj];
        if constexpr (MODE == 1) v = gelu_exact(v + bias[col]);
        Cb[(size_t)(row0 + jj) * N + col] = (__bf16)v;
      }
    }
}

// ---------------- MFMA rel-pos attention v8 + setprio on MFMA clusters ----------------
__global__ __launch_bounds__(256)
void attn8(const __bf16* __restrict__ qk, const __bf16* __restrict__ vT,
           const __bf16* __restrict__ kpos, const float* __restrict__ rwbias,
           const float* __restrict__ rrbias, __bf16* __restrict__ av) {
  constexpr float ALPHA = 0.125f * 1.44269504088896f;
  constexpr int PB = 132;
  __shared__ __align__(16) char smem[74240];
  __bf16* sP  = (__bf16*)(smem + 49152);
  __bf16* sbd = (__bf16*)(smem + 57344);

  const int flat = blockIdx.x;
  const int xcd = flat & 7, rr_ = flat >> 3;
  const int bn = xcd * 8 + (rr_ >> 4);
  const int it = rr_ & 15;
  const int b = bn >> 4, n = bn & 15;
  const int i0 = it * 64;
  const int tid = threadIdx.x;
  const int l = tid & 63;
  const int lcol = l & 15, lk = l >> 4;
  const int strip = (tid >> 6) * 16;
  const int wbase = tid & 192;
  const int nh64 = n * 64;
  const int q = strip + lcol;

  const int rB = tid >> 3;
  const int cs8 = ((tid & 7) ^ (rB & 7)) * 8;

  bf16x8 onesf;
#pragma unroll
  for (int u = 0; u < 8; ++u) onesf[u] = (__bf16)1.0f;

  bf16x8 qac[2], qlo[2], qhi[2];
  {
    const __bf16* qrow = qk + ((size_t)(b * 1024 + i0 + q)) * 2048 + nh64;
    int gH = i0 + q + 1; gH = gH < 1024 ? gH : 1023;
    const __bf16* qrowH = qk + ((size_t)(b * 1024 + gH)) * 2048 + nh64;
#pragma unroll
    for (int kk = 0; kk < 2; ++kk) {
      bf16x8 qv = *(const bf16x8*)(qrow + kk * 32 + lk * 8);
      bf16x8 qh = *(const bf16x8*)(qrowH + kk * 32 + lk * 8);
      const int dbase = nh64 + kk * 32 + lk * 8;
#pragma unroll
      for (int u = 0; u < 8; ++u) {
        const float rb = rrbias[dbase + u];
        qac[kk][u] = (__bf16)(((float)qv[u] + rwbias[dbase + u]) * ALPHA);
        qlo[kk][u] = (__bf16)(((float)qv[u] + rb) * ALPHA);
        qhi[kk][u] = (__bf16)(((float)qh[u] + rb) * ALPHA);
      }
    }
  }

#pragma unroll
  for (int kq = 0; kq < 2; ++kq) {
    const int r = kq * 32 + rB;
    const int dst = (kq * 256 + wbase) * 8;
    gload_lds16(kpos + ((size_t)((960 - i0 + r) * 4 + b)) * 1024 + nh64 + cs8,
                (__bf16*)(smem + 40960) + dst);
    gload_lds16(qk + ((size_t)(b * 1024 + r)) * 2048 + 1024 + nh64 + cs8,
                (__bf16*)(smem) + dst);
    const int rrel = r - i0;
    const int idx = (rrel <= 0) ? (1024 + rrel) : (rrel - 1);
    gload_lds16(kpos + ((size_t)(idx * 4 + b)) * 1024 + nh64 + cs8,
                (__bf16*)(smem + 16384) + dst);
    gload_lds16(vT + ((size_t)(nh64 + r)) * 4096 + b * 1024 + cs8,
                (__bf16*)(smem + 32768) + dst);
  }
  __syncthreads();
  {
    __bf16* kpl = (__bf16*)(smem + 40960);
    const int colb0 = (-i0 - 64) & 127;
#pragma unroll
    for (int fb = 0; fb < 4; ++fb) {
      const int row = fb * 16 + lcol;
      f32x4 g = {};
#pragma unroll
      for (int kk = 0; kk < 2; ++kk) {
        bf16x8 a = *(const bf16x8*)&kpl[row * 64 + (((kk * 4 + lk) ^ (lcol & 7)) * 8)];
        g = __builtin_amdgcn_mfma_f32_16x16x32_bf16(a, qlo[kk], g, 0, 0, 0);
      }
      bf16x4 gw = {(__bf16)g[0], (__bf16)g[1], (__bf16)g[2], (__bf16)g[3]};
      *(bf16x4*)&sbd[q * PB + ((colb0 + fb * 16 + lk * 4) & 127)] = gw;
    }
  }
  __syncthreads();

  f32x4 oacc[4] = {};
  f32x4 zq = {};
  size_t kS = (size_t)(b * 1024 + 64 + rB) * 2048 + 1024 + nh64 + cs8;
  size_t vS = (size_t)(nh64 + rB) * 4096 + b * 1024 + 64 + cs8;

#pragma unroll 1
  for (int jt = 0; jt < 16; ++jt) {
    const int cur = jt & 1, nxt = cur ^ 1;
    const int d0 = jt * 64 - i0;
    __bf16* sK   = (__bf16*)(smem + cur * 8192);
    __bf16* sKn  = (__bf16*)(smem + nxt * 8192);
    __bf16* sKP  = (__bf16*)(smem + 16384 + cur * 8192);
    __bf16* sKPn = (__bf16*)(smem + 16384 + nxt * 8192);
    __bf16* sVT  = (__bf16*)(smem + 32768 + cur * 8192);
    __bf16* sVTn = (__bf16*)(smem + 32768 + nxt * 8192);
#pragma unroll
    for (int kq = 0; kq < 2; ++kq) {
      const int dst = (kq * 256 + wbase) * 8;
      gload_lds16(qk + kS + kq * 65536, sKn + dst);
      gload_lds16(vT + vS + kq * 131072, sVTn + dst);
      const int rreln = d0 + 64 + kq * 32 + rB;
      const int idx = (rreln <= 0) ? (1024 + rreln) : (rreln - 1);
      gload_lds16(kpos + ((size_t)(idx * 4 + b)) * 1024 + nh64 + cs8, sKPn + dst);
    }
    kS += 131072; vS += 64;
    {
      const bf16x8 qg0 = (d0 >= 0) ? qhi[0] : qlo[0];
      const bf16x8 qg1 = (d0 >= 0) ? qhi[1] : qlo[1];
      __builtin_amdgcn_s_setprio(1);
#pragma unroll
      for (int fb = 0; fb < 4; ++fb) {
        const int row = fb * 16 + lcol;
        f32x4 g = {};
        g = __builtin_amdgcn_mfma_f32_16x16x32_bf16(
            *(const bf16x8*)&sKP[row * 64 + ((lk ^ (lcol & 7)) * 8)], qg0, g, 0, 0, 0);
        g = __builtin_amdgcn_mfma_f32_16x16x32_bf16(
            *(const bf16x8*)&sKP[row * 64 + (((4 + lk) ^ (lcol & 7)) * 8)], qg1, g, 0, 0, 0);
        bf16x4 gw = {(__bf16)g[0], (__bf16)g[1], (__bf16)g[2], (__bf16)g[3]};
        *(bf16x4*)&sbd[q * PB + ((d0 + fb * 16 + lk * 4) & 127)] = gw;
      }
      __builtin_amdgcn_s_setprio(0);
      if (d0 == 0) {
        const int cl = tid >> 2, part = tid & 3;
        const __bf16* qs = qk + ((size_t)(b * 1024 + i0 + cl)) * 2048 + nh64 + part * 16;
        bf16x8 a0 = *(const bf16x8*)qs;
        bf16x8 a1 = *(const bf16x8*)(qs + 8);
        bf16x8 k0 = *(const bf16x8*)&sKP[(2 * part) * 8];
        bf16x8 k1 = *(const bf16x8*)&sKP[(2 * part + 1) * 8];
        float s64 = 0.f;
#pragma unroll
        for (int u = 0; u < 8; ++u)
          s64 += ((float)a0[u] + rrbias[nh64 + part * 16 + u]) * (float)k0[u]
               + ((float)a1[u] + rrbias[nh64 + part * 16 + 8 + u]) * (float)k1[u];
        s64 += __shfl_xor(s64, 1, 64);
        s64 += __shfl_xor(s64, 2, 64);
        if (part == 0) sbd[cl * PB] = (__bf16)(s64 * ALPHA);
      }
    }
    f32x4 sc[4];
    __builtin_amdgcn_s_setprio(1);
#pragma unroll
    for (int fk = 0; fk < 4; ++fk) {
      const int row = fk * 16 + lcol;
      f32x4 a = {};
#pragma unroll
      for (int kk = 0; kk < 2; ++kk) {
        bf16x8 kf = *(const bf16x8*)&sK[row * 64 + (((kk * 4 + lk) ^ (lcol & 7)) * 8)];
        a = __builtin_amdgcn_mfma_f32_16x16x32_bf16(kf, qac[kk], a, 0, 0, 0);
      }
      sc[fk] = a;
    }
    __builtin_amdgcn_s_setprio(0);
    {
      const int rowb = q * PB;
      const int sb = d0 - q;
#pragma unroll
      for (int fk = 0; fk < 4; ++fk) {
        const int cb = sb + fk * 16 + lk * 4;
        float e0 = exp2f(sc[fk][0] + (float)sbd[rowb + ((cb) & 127)]);
        float e1 = exp2f(sc[fk][1] + (float)sbd[rowb + ((cb + 1) & 127)]);
        float e2 = exp2f(sc[fk][2] + (float)sbd[rowb + ((cb + 2) & 127)]);
        float e3 = exp2f(sc[fk][3] + (float)sbd[rowb + ((cb + 3) & 127)]);
        bf16x4 pw = {(__bf16)e0, (__bf16)e1, (__bf16)e2, (__bf16)e3};
        *(bf16x4*)&sP[q * 64 + (((fk * 2 + (lk >> 1)) ^ (q & 7)) * 8) + (lk & 1) * 4] = pw;
      }
    }
    __builtin_amdgcn_s_setprio(1);
#pragma unroll
    for (int kk = 0; kk < 2; ++kk) {
      bf16x8 pa = *(const bf16x8*)&sP[q * 64 + (((kk * 4 + lk) ^ (q & 7)) * 8)];
      zq = __builtin_amdgcn_mfma_f32_16x16x32_bf16(pa, onesf, zq, 0, 0, 0);
#pragma unroll
      for (int fd = 0; fd < 4; ++fd) {
        const int vrow = fd * 16 + lcol;
        bf16x8 bv = *(const bf16x8*)&sVT[vrow * 64 + (((kk * 4 + lk) ^ (lcol & 7)) * 8)];
        oacc[fd] = __builtin_amdgcn_mfma_f32_16x16x32_bf16(pa, bv, oacc[fd], 0, 0, 0);
      }
    }
    __builtin_amdgcn_s_setprio(0);
    __syncthreads();
  }
#pragma unroll
  for (int jj = 0; jj < 4; ++jj) {
    const float rz = 1.f / zq[jj];
    const int ig = i0 + strip + lk * 4 + jj;
    __bf16* dst = av + ((size_t)(ig * 4 + b)) * 1024 + nh64;
#pragma unroll
    for (int fd = 0; fd < 4; ++fd)
      dst[fd * 16 + lcol] = (__bf16)(oacc[fd][jj] * rz);
  }
}

// ---------------- fused residual + LayerNorm (f32 or bf16 base, 4 bf16 partials) ----------------
__global__ __launch_bounds__(256)
void ln_fuse(const float* __restrict__ A, const __bf16* __restrict__ Ab,
             const __bf16* __restrict__ P0, const __bf16* __restrict__ P1,
             const __bf16* __restrict__ P2, const __bf16* __restrict__ P3,
             const float* __restrict__ cb, const float* __restrict__ g,
             const float* __restrict__ be, float* __restrict__ oF,
             __bf16* __restrict__ oB) {
  const int row = blockIdx.x, t = threadIdx.x;
  const size_t base = (size_t)row * 1024 + t * 4;
  float x0, x1, x2, x3;
  if (A) {
    const float4 a = *(const float4*)(A + base);
    x0 = a.x; x1 = a.y; x2 = a.z; x3 = a.w;
  } else {
    const bf16x4 a = *(const bf16x4*)(Ab + base);
    x0 = (float)a[0]; x1 = (float)a[1]; x2 = (float)a[2]; x3 = (float)a[3];
  }
  const bf16x4 p0 = *(const bf16x4*)(P0 + base);
  const bf16x4 p1 = *(const bf16x4*)(P1 + base);
  const bf16x4 p2 = *(const bf16x4*)(P2 + base);
  const bf16x4 p3 = *(const bf16x4*)(P3 + base);
  x0 += (float)p0[0] + (float)p1[0] + (float)p2[0] + (float)p3[0];
  x1 += (float)p0[1] + (float)p1[1] + (float)p2[1] + (float)p3[1];
  x2 += (float)p0[2] + (float)p1[2] + (float)p2[2] + (float)p3[2];
  x3 += (float)p0[3] + (float)p1[3] + (float)p2[3] + (float)p3[3];
  if (cb) {
    const float4 c = *(const float4*)(cb + t * 4);
    x0 += c.x; x1 += c.y; x2 += c.z; x3 += c.w;
  }
  float s = x0 + x1 + x2 + x3;
  float qq = x0 * x0 + x1 * x1 + x2 * x2 + x3 * x3;
#pragma unroll
  for (int o = 1; o < 64; o <<= 1) { s += __shfl_xor(s, o, 64); qq += __shfl_xor(qq, o, 64); }
  __shared__ float ss[4], qs[4];
  if ((t & 63) == 0) { ss[t >> 6] = s; qs[t >> 6] = qq; }
  __syncthreads();
  s = ss[0] + ss[1] + ss[2] + ss[3];
  qq = qs[0] + qs[1] + qs[2] + qs[3];
  const float mean = s * (1.f / 1024.f);
  const float var = qq * (1.f / 1024.f) - mean * mean;
  const float rstd = rsqrtf(var + 1e-5f);
  const float4 gv = *(const float4*)(g + t * 4);
  const float4 bev = *(const float4*)(be + t * 4);
  const float y0 = (x0 - mean) * rstd * gv.x + bev.x;
  const float y1 = (x1 - mean) * rstd * gv.y + bev.y;
  const float y2 = (x2 - mean) * rstd * gv.z + bev.z;
  const float y3 = (x3 - mean) * rstd * gv.w + bev.w;
  if (oF) {
    float4 r = {y0, y1, y2, y3};
    *(float4*)(oF + base) = r;
  }
  if (oB) {
    bf16x4 o4 = {(__bf16)y0, (__bf16)y1, (__bf16)y2, (__bf16)y3};
    *(bf16x4*)(oB + base) = o4;
  }
}

extern "C" void kernel_launch(void* const* d_in, const int* in_sizes, int n_in,
                              void* d_out, int out_size, void* d_ws, size_t ws_size,
                              hipStream_t stream) {
  const float* src    = (const float*)d_in[0];
  const float* pos    = (const float*)d_in[1];
  const float* qw     = (const float*)d_in[3];
  const float* kw     = (const float*)d_in[4];
  const float* vw     = (const float*)d_in[5];
  const float* rw     = (const float*)d_in[6];
  const float* ow     = (const float*)d_in[7];
  const float* rwbias = (const float*)d_in[8];
  const float* rrbias = (const float*)d_in[9];
  const float* w1     = (const float*)d_in[10];
  const float* b1     = (const float*)d_in[11];
  const float* w2     = (const float*)d_in[12];
  const float* b2     = (const float*)d_in[13];
  const float* g1     = (const float*)d_in[14];
  const float* be1    = (const float*)d_in[15];
  const float* g2     = (const float*)d_in[16];
  const float* be2    = (const float*)d_in[17];
  float* out = (float*)d_out;

  char* p = (char*)d_ws;
  auto alloc = [&](size_t bytes) { char* r = p; p += (bytes + 255) & ~(size_t)255; return r; };
  __bf16* qkB   = (__bf16*)alloc(4096ull * 2048 * 2);   // dead after attn
  __bf16* vTB   = (__bf16*)alloc(1024ull * 4096 * 2);   // dead after attn
  __bf16* kposB = (__bf16*)alloc(4100ull * 1024 * 2);   // dead after attn
  __bf16* avB   = (__bf16*)alloc(4096ull * 1024 * 2);   // dead after attn-out
  __bf16* srcB2 = (__bf16*)alloc(4096ull * 1024 * 2);   // dead after projections
  __bf16* posB  = (__bf16*)alloc(4100ull * 1024 * 2);   // dead after proj2
  float*  xF    = (float*)alloc(4096ull * 1024 * 4);    // scratch: 2x 8MB partial slots
  __bf16* w2B   = (__bf16*)alloc(4096ull * 1024 * 2);
  __bf16* qkvT  = (__bf16*)alloc(3072ull * 1024 * 2);
  __bf16* rwT   = (__bf16*)alloc(1024ull * 1024 * 2);
  __bf16* owB   = (__bf16*)alloc(1024ull * 1024 * 2);
  __bf16* w1B   = (__bf16*)alloc(4096ull * 1024 * 2);   // dead after FFN1
  __bf16* xB    = (__bf16*)alloc(4096ull * 1024 * 2);   // live until LN2 (residual)
  // aliases (disjoint lifetimes):
  __bf16* gB   = qkB;                  // gelu 32MB over qkB+vTB+kposB
  __bf16* xS0  = (__bf16*)xF;          // scratch slot A (8MB)
  __bf16* xS1  = (__bf16*)xF + 4194304;// scratch slot B (8MB)
  // attn-out partials: srcB2, posB (dead after proj chain), xS0, xS1
  // ffn2 partials: avB (dead after attn-out), w1B (dead after FFN1), xS0, xS1

  prep_all<<<11521, 256, 0, stream>>>(src, srcB2, pos, posB, ow, owB, w1, w1B,
                                      w2, w2B, qw, kw, vw, rw, qkvT, rwT);
  gemm256<2><<<dim3(16, 16), 512, 0, stream>>>(srcB2, qkvT, qkB, nullptr, 4096, 2048, 1024);
  proj2_kernel<<<1040, 256, 0, stream>>>(qkvT + 2048 * 1024, srcB2, posB, rwT, vTB, kposB);
  attn8<<<dim3(1024), 256, 0, stream>>>(qkB, vTB, kposB, rwbias, rrbias, avB);
  // attn-out: 256^2-tile split-K=4 (kChunk=256), bf16 partials
  gemm512<2><<<dim3(4, 16, 4), 512, 0, stream>>>(avB, owB, srcB2, posB, xS0, xS1, nullptr, 4096, 1024, 1024, 256);
  ln_fuse<<<4096, 256, 0, stream>>>(src, nullptr, srcB2, posB, xS0, xS1, nullptr, g1, be1, nullptr, xB);
  gemm512<1><<<dim3(16, 16), 512, 0, stream>>>(xB, w1B, gB, nullptr, nullptr, nullptr, b1, 4096, 4096, 1024, 1024);
  gemm512<2><<<dim3(4, 16, 4), 512, 0, stream>>>(gB, w2B, avB, w1B, xS0, xS1, nullptr, 4096, 1024, 4096, 1024);
  ln_fuse<<<4096, 256, 0, stream>>>(nullptr, xB, avB, w1B, xS0, xS1, b2, g2, be2, out, nullptr);
  (void)in_sizes; (void)n_in; (void)out_size; (void)ws_size;
}

// Round 16
// 285.198 us; speedup vs baseline: 1.1180x; 1.0034x over previous
//
#include <hip/hip_runtime.h>
#include <math.h>

typedef __bf16 bf16x8 __attribute__((ext_vector_type(8)));
typedef __bf16 bf16x4 __attribute__((ext_vector_type(4)));
typedef float f32x4 __attribute__((ext_vector_type(4)));

__device__ __forceinline__ void gload_lds16(const __bf16* g, __bf16* l) {
  __builtin_amdgcn_global_load_lds((const __attribute__((address_space(1))) void*)g,
                                   (__attribute__((address_space(3))) void*)l, 16, 0, 0);
}

__device__ __forceinline__ float gelu_exact(float v) {
  return 0.5f * v * (1.f + erff(v * 0.70710678118654752f));
}

// ---------------- fused prep: perm-src | 4x cvt | 4x transpose-cvt ----------------
__global__ __launch_bounds__(256) void prep_all(
    const float* __restrict__ src, __bf16* __restrict__ srcB2,
    const float* __restrict__ pos, __bf16* __restrict__ posB,
    const float* __restrict__ ow, __bf16* __restrict__ owB,
    const float* __restrict__ w1, __bf16* __restrict__ w1B,
    const float* __restrict__ w2, __bf16* __restrict__ w2B,
    const float* __restrict__ qw, const float* __restrict__ kw,
    const float* __restrict__ vw, const float* __restrict__ rw,
    __bf16* __restrict__ qkvT, __bf16* __restrict__ rwT) {
  __shared__ float t[32][33];
  int bid = blockIdx.x;
  const int tid = threadIdx.x;
  if (bid < 4096) {                       // src (i,b)-rows -> bf16 (b,i)-rows
    const int i = bid & 1023, b = bid >> 10;
    const float4 v = *(const float4*)(src + ((size_t)(i * 4 + b)) * 1024 + tid * 4);
    bf16x4 o = {(__bf16)v.x, (__bf16)v.y, (__bf16)v.z, (__bf16)v.w};
    *(bf16x4*)(srcB2 + (size_t)bid * 1024 + tid * 4) = o;
    return;
  }
  bid -= 4096;
  if (bid < 3329) {                       // straight converts
    const float* in; __bf16* out;
    if (bid < 1025) { in = pos; out = posB; }
    else if (bid < 1281) { bid -= 1025; in = ow; out = owB; }
    else if (bid < 2305) { bid -= 1281; in = w1; out = w1B; }
    else { bid -= 2305; in = w2; out = w2B; }
    const int base = bid * 4096 + tid * 4;
#pragma unroll
    for (int k2 = 0; k2 < 4; ++k2) {
      const int off = base + k2 * 1024;
      float4 v = *(const float4*)(in + off);
      bf16x4 o = {(__bf16)v.x, (__bf16)v.y, (__bf16)v.z, (__bf16)v.w};
      *(bf16x4*)(out + off) = o;
    }
    return;
  }
  bid -= 3329;                            // transpose-converts (4x 1024x1024)
  const int z = bid >> 10, rem = bid & 1023;
  const float* in; __bf16* out;
  switch (z) {
    case 0: in = qw; out = qkvT; break;
    case 1: in = kw; out = qkvT + 1024 * 1024; break;
    case 2: in = vw; out = qkvT + 2048 * 1024; break;
    default: in = rw; out = rwT; break;
  }
  const int c0 = (rem & 31) * 32, r0 = (rem >> 5) * 32;
  const int tx = tid & 31, ty = tid >> 5;
  for (int yy = ty; yy < 32; yy += 8)
    t[yy][tx] = in[(size_t)(r0 + yy) * 1024 + c0 + tx];
  __syncthreads();
  for (int yy = ty; yy < 32; yy += 8)
    out[(size_t)(c0 + yy) * 1024 + r0 + tx] = (__bf16)t[tx][yy];
}

// ---------------- bf16 MFMA GEMM body (2-phase, 128x64) ----------------
template<int BM, int BN, int MODE>
__device__ __forceinline__ void gemm_body(
    const __bf16* __restrict__ A, const __bf16* __restrict__ BT,
    float* __restrict__ Cf, __bf16* __restrict__ Cb,
    const float* __restrict__ bias, int M, int N, int K,
    int kStart, int kChunk, int mBase, int nBase, char* smemRaw) {
  constexpr int BK = 32;
  constexpr int ALOAD = (BM * BK) / 2048;
  constexpr int BLOAD = (BN * BK) / 2048;
  __bf16* lA = (__bf16*)smemRaw;                       // [2][BM*BK]
  __bf16* lB = (__bf16*)(smemRaw + 4 * BM * BK);       // [2][BN*BK]
  const int tid = threadIdx.x;
  const int w = tid >> 6, l = tid & 63;
  const int lr = l & 15, lk = l >> 4;
  const int srow = tid >> 2;
  const int scol = (tid & 3) * 8;
  const int wbase = w * 512;

  const __bf16* aSrc[ALOAD];
  const __bf16* bSrc[BLOAD];
#pragma unroll
  for (int i = 0; i < ALOAD; ++i) {
    int grow = mBase + srow + i * 64;
    grow = grow < M ? grow : M - 1;
    aSrc[i] = A + (size_t)grow * K + kStart + scol;
  }
#pragma unroll
  for (int i = 0; i < BLOAD; ++i) {
    const int grow = nBase + srow + i * 64;
    bSrc[i] = BT + (size_t)grow * K + kStart + scol;
  }
  auto stage = [&](int buf) {
#pragma unroll
    for (int i = 0; i < ALOAD; ++i) {
      gload_lds16(aSrc[i], &lA[buf * BM * BK + i * 2048 + wbase]);
      aSrc[i] += BK;
    }
#pragma unroll
    for (int i = 0; i < BLOAD; ++i) {
      gload_lds16(bSrc[i], &lB[buf * BN * BK + i * 2048 + wbase]);
      bSrc[i] += BK;
    }
  };

  constexpr int WM = BM / 2, WN = BN / 2;
  constexpr int MF = WM / 16, NF = WN / 16;
  const int wr = w >> 1, wc = w & 1;
  f32x4 acc[MF][NF] = {};

  const int nIter = kChunk / BK;
  stage(0);
  int cur = 0;
#pragma unroll 1
  for (int t = 0; t < nIter; ++t) {
    __syncthreads();
    if (t + 1 < nIter) stage(cur ^ 1);
    bf16x8 af[MF], bfr[NF];
#pragma unroll
    for (int mi = 0; mi < MF; ++mi)
      af[mi] = *(const bf16x8*)&lA[cur * BM * BK + (wr * WM + mi * 16 + lr) * BK + lk * 8];
#pragma unroll
    for (int nj = 0; nj < NF; ++nj)
      bfr[nj] = *(const bf16x8*)&lB[cur * BN * BK + (wc * WN + nj * 16 + lr) * BK + lk * 8];
#pragma unroll
    for (int mi = 0; mi < MF; ++mi)
#pragma unroll
      for (int nj = 0; nj < NF; ++nj)
        acc[mi][nj] = __builtin_amdgcn_mfma_f32_16x16x32_bf16(af[mi], bfr[nj], acc[mi][nj], 0, 0, 0);
    cur ^= 1;
  }
#pragma unroll
  for (int mi = 0; mi < MF; ++mi) {
#pragma unroll
    for (int nj = 0; nj < NF; ++nj) {
      const int col = nBase + wc * WN + nj * 16 + lr;
      const int row0 = mBase + wr * WM + mi * 16 + lk * 4;
#pragma unroll
      for (int j = 0; j < 4; ++j) {
        const int row = row0 + j;
        if (row < M) {
          float v = acc[mi][nj][j];
          if constexpr (MODE == 1) {
            v = gelu_exact(v + bias[col]);
            Cb[(size_t)row * N + col] = (__bf16)v;
          } else if constexpr (MODE == 2) {
            Cb[(size_t)row * N + col] = (__bf16)v;
          } else {
            Cf[(size_t)row * N + col] = v;
          }
        }
      }
    }
  }
}

// ---- vT + kpos projections in one launch (1040 blocks, XCD-chunked) ----
__global__ __launch_bounds__(256)
void proj2_kernel(const __bf16* __restrict__ vwT, const __bf16* __restrict__ srcB2,
                  const __bf16* __restrict__ posB, const __bf16* __restrict__ rwT,
                  __bf16* __restrict__ vTB, __bf16* __restrict__ kposB) {
  __shared__ __align__(16) char smem[4 * (128 + 64) * 32];
  const int raw = blockIdx.x;
  int bid = (raw & 7) * 130 + (raw >> 3);   // 1040/8 = 130 per XCD
  if (bid < 512) {
    gemm_body<128, 64, 2>(vwT, srcB2, nullptr, vTB, nullptr, 1024, 4096, 1024,
                          0, 1024, (bid >> 6) * 128, (bid & 63) * 64, smem);
  } else {
    const int t = bid - 512;
    gemm_body<128, 64, 2>(posB, rwT, nullptr, kposB, nullptr, 4100, 1024, 1024,
                          0, 1024, (t >> 4) * 128, (t & 15) * 64, smem);
  }
}

// ---------------- 256x128-tile deep-pipeline GEMM (3-side counted-vmcnt) ----------------
template<int MODE>
__global__ __launch_bounds__(512)
void gemm256(const __bf16* __restrict__ A, const __bf16* __restrict__ BT,
             __bf16* __restrict__ Cb, const float* __restrict__ bias,
             int M, int N, int K) {
  __shared__ __align__(16) __bf16 sm[3 * 24576];
  const int tid = threadIdx.x;
  const int wid = tid >> 6, l = tid & 63;
  const int lcol = l & 15, lk = l >> 4;
  const int wm = wid >> 1, wn = wid & 1;
  const int gx = gridDim.x;
  const int G = gx * gridDim.y;
  const int flat = blockIdx.y * gx + blockIdx.x;
  const int band = G >> 3;
  const int x8 = flat & 7, loc = flat >> 3;
  const int rpb = band / gx;
  const int ny = x8 * rpb + loc % rpb;
  const int nx = loc / rpb;
  const int mBase = ny * 256, nBase = nx * 128;

  int rowj[2], gslotj[2];
#pragma unroll
  for (int j = 0; j < 2; ++j) {
    const int u = (wid * 2 + j) * 64 + l;
    rowj[j] = u >> 3;
    gslotj[j] = (u & 7) ^ (rowj[j] & 7);
  }
  auto issueHT = [&](int kt, int ht, int side) {
    __bf16* base = sm + side * 24576 + (ht == 2 ? 16384 : ht * 8192);
#pragma unroll
    for (int j = 0; j < 2; ++j) {
      const __bf16* src = (ht < 2)
        ? A + (size_t)(mBase + ht * 128 + rowj[j]) * K + kt * 64 + gslotj[j] * 8
        : BT + (size_t)(nBase + rowj[j]) * K + kt * 64 + gslotj[j] * 8;
      gload_lds16(src, base + (wid * 2 + j) * 512);
    }
  };

  const int nkt = K >> 6;
  issueHT(0, 0, 0); issueHT(0, 1, 0); issueHT(0, 2, 0);
  issueHT(1, 0, 1); issueHT(1, 1, 1); issueHT(1, 2, 1);

  f32x4 acc[4][4] = {};
#pragma unroll 1
  for (int j = 0; j < nkt; ++j) {
    asm volatile("s_waitcnt vmcnt(6)" ::: "memory");
    __builtin_amdgcn_s_barrier();
    __builtin_amdgcn_sched_barrier(0);
    const int side = j % 3;
    const int sn = (j + 2) % 3;
    const int ktn = (j + 2 < nkt) ? j + 2 : nkt - 1;
    const __bf16* Ab = sm + side * 24576;
    const __bf16* Bb = Ab + 16384;
    issueHT(ktn, 0, sn);
    bf16x8 af[4][2];
#pragma unroll
    for (int mi = 0; mi < 4; ++mi)
#pragma unroll
      for (int kk = 0; kk < 2; ++kk) {
        const int row = wm * 64 + mi * 16 + lcol;
        af[mi][kk] = *(const bf16x8*)&Ab[row * 64 + (((kk * 4 + lk) ^ (row & 7)) * 8)];
      }
    issueHT(ktn, 1, sn);
    bf16x8 bfv[4][2];
#pragma unroll
    for (int nj = 0; nj < 4; ++nj)
#pragma unroll
      for (int kk = 0; kk < 2; ++kk) {
        const int row = wn * 64 + nj * 16 + lcol;
        bfv[nj][kk] = *(const bf16x8*)&Bb[row * 64 + (((kk * 4 + lk) ^ (row & 7)) * 8)];
      }
    issueHT(ktn, 2, sn);
    __builtin_amdgcn_s_setprio(1);
#pragma unroll
    for (int mi = 0; mi < 4; ++mi)
#pragma unroll
      for (int nj = 0; nj < 4; ++nj) {
        acc[mi][nj] = __builtin_amdgcn_mfma_f32_16x16x32_bf16(af[mi][0], bfv[nj][0], acc[mi][nj], 0, 0, 0);
        acc[mi][nj] = __builtin_amdgcn_mfma_f32_16x16x32_bf16(af[mi][1], bfv[nj][1], acc[mi][nj], 0, 0, 0);
      }
    __builtin_amdgcn_s_setprio(0);
  }
#pragma unroll
  for (int mi = 0; mi < 4; ++mi)
#pragma unroll
    for (int nj = 0; nj < 4; ++nj) {
      const int col = nBase + wn * 64 + nj * 16 + lcol;
      const int row0 = mBase + wm * 64 + mi * 16 + lk * 4;
#pragma unroll
      for (int jj = 0; jj < 4; ++jj) {
        float v = acc[mi][nj][jj];
        if constexpr (MODE == 1) v = gelu_exact(v + bias[col]);
        Cb[(size_t)(row0 + jj) * N + col] = (__bf16)v;
      }
    }
}

// ---------------- 256x256-tile GEMM, BK=64, 8 waves of 128x64 (LDS-BW optimal) ----------
template<int MODE>
__global__ __launch_bounds__(512)
void gemm512(const __bf16* __restrict__ A, const __bf16* __restrict__ BT,
             __bf16* __restrict__ Cb0, __bf16* __restrict__ Cb1,
             __bf16* __restrict__ Cb2, __bf16* __restrict__ Cb3,
             const float* __restrict__ bias, int M, int N, int K, int kChunk) {
  __shared__ __align__(16) __bf16 sm[2 * 32768];
  const int tid = threadIdx.x;
  const int w = tid >> 6, l = tid & 63;
  const int lcol = l & 15, lk = l >> 4;
  const int wm = w >> 2, wn = w & 3;          // 2 x 4 waves, wave tile 128x64
  const int gx = gridDim.x;
  const int G = gx * gridDim.y;
  const int flat = blockIdx.y * gx + blockIdx.x;
  const int band = G >> 3;
  const int x8 = flat & 7, loc = flat >> 3;
  const int rpb = band / gx;
  const int ny = x8 * rpb + loc % rpb;
  const int nx = loc / rpb;
  const int mBase = ny * 256, nBase = nx * 256;
  const int kStart = blockIdx.z * kChunk;
  __bf16* Cb = (blockIdx.z == 0) ? Cb0 : (blockIdx.z == 1) ? Cb1
             : (blockIdx.z == 2) ? Cb2 : Cb3;

  const int rT = tid >> 3;                    // 0..63
  const int gslot = ((tid & 7) ^ (rT & 7)) * 8;
  auto stage = [&](int side, int kt) {
#pragma unroll
    for (int i = 0; i < 4; ++i) {
      gload_lds16(A + (size_t)(mBase + i * 64 + rT) * K + kStart + kt * 64 + gslot,
                  sm + side * 32768 + i * 4096 + w * 512);
      gload_lds16(BT + (size_t)(nBase + i * 64 + rT) * K + kStart + kt * 64 + gslot,
                  sm + side * 32768 + 16384 + i * 4096 + w * 512);
    }
  };

  f32x4 acc[8][4] = {};
  const int nIter = kChunk >> 6;
  stage(0, 0);
  int cur = 0;
#pragma unroll 1
  for (int t = 0; t < nIter; ++t) {
    __syncthreads();                           // side cur complete (drains vmcnt)
    if (t + 1 < nIter) stage(cur ^ 1, t + 1);
    const __bf16* Ab = sm + cur * 32768;
    const __bf16* Bb = Ab + 16384;
    bf16x8 bfv[4][2];
#pragma unroll
    for (int nj = 0; nj < 4; ++nj)
#pragma unroll
      for (int kk = 0; kk < 2; ++kk) {
        const int row = wn * 64 + nj * 16 + lcol;
        bfv[nj][kk] = *(const bf16x8*)&Bb[row * 64 + (((kk * 4 + lk) ^ (row & 7)) * 8)];
      }
    __builtin_amdgcn_s_setprio(1);
#pragma unroll
    for (int mi = 0; mi < 8; ++mi) {
      const int row = wm * 128 + mi * 16 + lcol;
      bf16x8 a0 = *(const bf16x8*)&Ab[row * 64 + ((lk ^ (row & 7)) * 8)];
      bf16x8 a1 = *(const bf16x8*)&Ab[row * 64 + (((4 + lk) ^ (row & 7)) * 8)];
#pragma unroll
      for (int nj = 0; nj < 4; ++nj) {
        acc[mi][nj] = __builtin_amdgcn_mfma_f32_16x16x32_bf16(a0, bfv[nj][0], acc[mi][nj], 0, 0, 0);
        acc[mi][nj] = __builtin_amdgcn_mfma_f32_16x16x32_bf16(a1, bfv[nj][1], acc[mi][nj], 0, 0, 0);
      }
    }
    __builtin_amdgcn_s_setprio(0);
    cur ^= 1;
  }
#pragma unroll
  for (int mi = 0; mi < 8; ++mi)
#pragma unroll
    for (int nj = 0; nj < 4; ++nj) {
      const int col = nBase + wn * 64 + nj * 16 + lcol;
      const int row0 = mBase + wm * 128 + mi * 16 + lk * 4;
#pragma unroll
      for (int jj = 0; jj < 4; ++jj) {
        float v = acc[mi][nj][jj];
        if constexpr (MODE == 1) v = gelu_exact(v + bias[col]);
        Cb[(size_t)(row0 + jj) * N + col] = (__bf16)v;
      }
    }
}

// ---------------- MFMA rel-pos attention v10: split jt loop (lo/hi q-frags hoisted) ----
__global__ __launch_bounds__(256)
void attn10(const __bf16* __restrict__ qk, const __bf16* __restrict__ vT,
            const __bf16* __restrict__ kpos, const float* __restrict__ rwbias,
            const float* __restrict__ rrbias, __bf16* __restrict__ av) {
  constexpr float ALPHA = 0.125f * 1.44269504088896f;
  constexpr int PB = 132;
  __shared__ __align__(16) char smem[74240];
  __bf16* sP  = (__bf16*)(smem + 49152);
  __bf16* sbd = (__bf16*)(smem + 57344);

  const int flat = blockIdx.x;
  const int xcd = flat & 7, rr_ = flat >> 3;
  const int bn = xcd * 8 + (rr_ >> 4);
  const int it = rr_ & 15;
  const int b = bn >> 4, n = bn & 15;
  const int i0 = it * 64;
  const int tid = threadIdx.x;
  const int l = tid & 63;
  const int lcol = l & 15, lk = l >> 4;
  const int strip = (tid >> 6) * 16;
  const int wbase = tid & 192;
  const int nh64 = n * 64;
  const int q = strip + lcol;

  const int rB = tid >> 3;
  const int cs8 = ((tid & 7) ^ (rB & 7)) * 8;

  bf16x8 onesf;
#pragma unroll
  for (int u = 0; u < 8; ++u) onesf[u] = (__bf16)1.0f;

  bf16x8 qac[2], qlo[2], qhi[2];
  {
    const __bf16* qrow = qk + ((size_t)(b * 1024 + i0 + q)) * 2048 + nh64;
    int gH = i0 + q + 1; gH = gH < 1024 ? gH : 1023;
    const __bf16* qrowH = qk + ((size_t)(b * 1024 + gH)) * 2048 + nh64;
#pragma unroll
    for (int kk = 0; kk < 2; ++kk) {
      bf16x8 qv = *(const bf16x8*)(qrow + kk * 32 + lk * 8);
      bf16x8 qh = *(const bf16x8*)(qrowH + kk * 32 + lk * 8);
      const int dbase = nh64 + kk * 32 + lk * 8;
#pragma unroll
      for (int u = 0; u < 8; ++u) {
        const float rb = rrbias[dbase + u];
        qac[kk][u] = (__bf16)(((float)qv[u] + rwbias[dbase + u]) * ALPHA);
        qlo[kk][u] = (__bf16)(((float)qv[u] + rb) * ALPHA);
        qhi[kk][u] = (__bf16)(((float)qh[u] + rb) * ALPHA);
      }
    }
  }

#pragma unroll
  for (int kq = 0; kq < 2; ++kq) {
    const int r = kq * 32 + rB;
    const int dst = (kq * 256 + wbase) * 8;
    gload_lds16(kpos + ((size_t)((960 - i0 + r) * 4 + b)) * 1024 + nh64 + cs8,
                (__bf16*)(smem + 40960) + dst);
    gload_lds16(qk + ((size_t)(b * 1024 + r)) * 2048 + 1024 + nh64 + cs8,
                (__bf16*)(smem) + dst);
    const int rrel = r - i0;
    const int idx = (rrel <= 0) ? (1024 + rrel) : (rrel - 1);
    gload_lds16(kpos + ((size_t)(idx * 4 + b)) * 1024 + nh64 + cs8,
                (__bf16*)(smem + 16384) + dst);
    gload_lds16(vT + ((size_t)(nh64 + r)) * 4096 + b * 1024 + cs8,
                (__bf16*)(smem + 32768) + dst);
  }
  __syncthreads();
  {
    __bf16* kpl = (__bf16*)(smem + 40960);
    const int colb0 = (-i0 - 64) & 127;
#pragma unroll
    for (int fb = 0; fb < 4; ++fb) {
      const int row = fb * 16 + lcol;
      f32x4 g = {};
#pragma unroll
      for (int kk = 0; kk < 2; ++kk) {
        bf16x8 a = *(const bf16x8*)&kpl[row * 64 + (((kk * 4 + lk) ^ (lcol & 7)) * 8)];
        g = __builtin_amdgcn_mfma_f32_16x16x32_bf16(a, qlo[kk], g, 0, 0, 0);
      }
      bf16x4 gw = {(__bf16)g[0], (__bf16)g[1], (__bf16)g[2], (__bf16)g[3]};
      *(bf16x4*)&sbd[q * PB + ((colb0 + fb * 16 + lk * 4) & 127)] = gw;
    }
  }
  __syncthreads();

  f32x4 oacc[4] = {};
  f32x4 zq = {};
  size_t kS = (size_t)(b * 1024 + 64 + rB) * 2048 + 1024 + nh64 + cs8;
  size_t vS = (size_t)(nh64 + rB) * 4096 + b * 1024 + 64 + cs8;

  auto jtStep = [&](int jt, const bf16x8 (&qg)[2], bool dofix) {
    const int cur = jt & 1, nxt = cur ^ 1;
    const int d0 = jt * 64 - i0;
    __bf16* sK   = (__bf16*)(smem + cur * 8192);
    __bf16* sKn  = (__bf16*)(smem + nxt * 8192);
    __bf16* sKP  = (__bf16*)(smem + 16384 + cur * 8192);
    __bf16* sKPn = (__bf16*)(smem + 16384 + nxt * 8192);
    __bf16* sVT  = (__bf16*)(smem + 32768 + cur * 8192);
    __bf16* sVTn = (__bf16*)(smem + 32768 + nxt * 8192);
#pragma unroll
    for (int kq = 0; kq < 2; ++kq) {
      const int dst = (kq * 256 + wbase) * 8;
      gload_lds16(qk + kS + kq * 65536, sKn + dst);
      gload_lds16(vT + vS + kq * 131072, sVTn + dst);
      const int rreln = d0 + 64 + kq * 32 + rB;
      const int idx = (rreln <= 0) ? (1024 + rreln) : (rreln - 1);
      gload_lds16(kpos + ((size_t)(idx * 4 + b)) * 1024 + nh64 + cs8, sKPn + dst);
    }
    kS += 131072; vS += 64;
    {
      __builtin_amdgcn_s_setprio(1);
#pragma unroll
      for (int fb = 0; fb < 4; ++fb) {
        const int row = fb * 16 + lcol;
        f32x4 g = {};
        g = __builtin_amdgcn_mfma_f32_16x16x32_bf16(
            *(const bf16x8*)&sKP[row * 64 + ((lk ^ (lcol & 7)) * 8)], qg[0], g, 0, 0, 0);
        g = __builtin_amdgcn_mfma_f32_16x16x32_bf16(
            *(const bf16x8*)&sKP[row * 64 + (((4 + lk) ^ (lcol & 7)) * 8)], qg[1], g, 0, 0, 0);
        bf16x4 gw = {(__bf16)g[0], (__bf16)g[1], (__bf16)g[2], (__bf16)g[3]};
        *(bf16x4*)&sbd[q * PB + ((d0 + fb * 16 + lk * 4) & 127)] = gw;
      }
      __builtin_amdgcn_s_setprio(0);
      if (dofix) {                 // col rrel=0 (needs lo q-rows): once per block
        const int cl = tid >> 2, part = tid & 3;
        const __bf16* qs = qk + ((size_t)(b * 1024 + i0 + cl)) * 2048 + nh64 + part * 16;
        bf16x8 a0 = *(const bf16x8*)qs;
        bf16x8 a1 = *(const bf16x8*)(qs + 8);
        bf16x8 k0 = *(const bf16x8*)&sKP[(2 * part) * 8];
        bf16x8 k1 = *(const bf16x8*)&sKP[(2 * part + 1) * 8];
        float s64 = 0.f;
#pragma unroll
        for (int u = 0; u < 8; ++u)
          s64 += ((float)a0[u] + rrbias[nh64 + part * 16 + u]) * (float)k0[u]
               + ((float)a1[u] + rrbias[nh64 + part * 16 + 8 + u]) * (float)k1[u];
        s64 += __shfl_xor(s64, 1, 64);
        s64 += __shfl_xor(s64, 2, 64);
        if (part == 0) sbd[cl * PB] = (__bf16)(s64 * ALPHA);
      }
    }
    f32x4 sc[4];
    __builtin_amdgcn_s_setprio(1);
#pragma unroll
    for (int fk = 0; fk < 4; ++fk) {
      const int row = fk * 16 + lcol;
      f32x4 a = {};
#pragma unroll
      for (int kk = 0; kk < 2; ++kk) {
        bf16x8 kf = *(const bf16x8*)&sK[row * 64 + (((kk * 4 + lk) ^ (lcol & 7)) * 8)];
        a = __builtin_amdgcn_mfma_f32_16x16x32_bf16(kf, qac[kk], a, 0, 0, 0);
      }
      sc[fk] = a;
    }
    __builtin_amdgcn_s_setprio(0);
    {
      const int rowb = q * PB;
      const int sb = d0 - q;
#pragma unroll
      for (int fk = 0; fk < 4; ++fk) {
        const int cb = sb + fk * 16 + lk * 4;
        float e0 = exp2f(sc[fk][0] + (float)sbd[rowb + ((cb) & 127)]);
        float e1 = exp2f(sc[fk][1] + (float)sbd[rowb + ((cb + 1) & 127)]);
        float e2 = exp2f(sc[fk][2] + (float)sbd[rowb + ((cb + 2) & 127)]);
        float e3 = exp2f(sc[fk][3] + (float)sbd[rowb + ((cb + 3) & 127)]);
        bf16x4 pw = {(__bf16)e0, (__bf16)e1, (__bf16)e2, (__bf16)e3};
        *(bf16x4*)&sP[q * 64 + (((fk * 2 + (lk >> 1)) ^ (q & 7)) * 8) + (lk & 1) * 4] = pw;
      }
    }
    __builtin_amdgcn_s_setprio(1);
#pragma unroll
    for (int kk = 0; kk < 2; ++kk) {
      bf16x8 pa = *(const bf16x8*)&sP[q * 64 + (((kk * 4 + lk) ^ (q & 7)) * 8)];
      zq = __builtin_amdgcn_mfma_f32_16x16x32_bf16(pa, onesf, zq, 0, 0, 0);
#pragma unroll
      for (int fd = 0; fd < 4; ++fd) {
        const int vrow = fd * 16 + lcol;
        bf16x8 bv = *(const bf16x8*)&sVT[vrow * 64 + (((kk * 4 + lk) ^ (lcol & 7)) * 8)];
        oacc[fd] = __builtin_amdgcn_mfma_f32_16x16x32_bf16(pa, bv, oacc[fd], 0, 0, 0);
      }
    }
    __builtin_amdgcn_s_setprio(0);
    __syncthreads();
  };

#pragma unroll 1
  for (int jt = 0; jt < it; ++jt) jtStep(jt, qlo, false);   // d0 < 0
  jtStep(it, qhi, true);                                    // d0 == 0 (+col-0 fix)
#pragma unroll 1
  for (int jt = it + 1; jt < 16; ++jt) jtStep(jt, qhi, false); // d0 > 0

#pragma unroll
  for (int jj = 0; jj < 4; ++jj) {
    const float rz = 1.f / zq[jj];
    const int ig = i0 + strip + lk * 4 + jj;
    __bf16* dst = av + ((size_t)(ig * 4 + b)) * 1024 + nh64;
#pragma unroll
    for (int fd = 0; fd < 4; ++fd)
      dst[fd * 16 + lcol] = (__bf16)(oacc[fd][jj] * rz);
  }
}

// ---------------- fused residual + LayerNorm (f32 or bf16 base, 4 bf16 partials) ----------------
__global__ __launch_bounds__(256)
void ln_fuse(const float* __restrict__ A, const __bf16* __restrict__ Ab,
             const __bf16* __restrict__ P0, const __bf16* __restrict__ P1,
             const __bf16* __restrict__ P2, const __bf16* __restrict__ P3,
             const float* __restrict__ cb, const float* __restrict__ g,
             const float* __restrict__ be, float* __restrict__ oF,
             __bf16* __restrict__ oB) {
  const int row = blockIdx.x, t = threadIdx.x;
  const size_t base = (size_t)row * 1024 + t * 4;
  float x0, x1, x2, x3;
  if (A) {
    const float4 a = *(const float4*)(A + base);
    x0 = a.x; x1 = a.y; x2 = a.z; x3 = a.w;
  } else {
    const bf16x4 a = *(const bf16x4*)(Ab + base);
    x0 = (float)a[0]; x1 = (float)a[1]; x2 = (float)a[2]; x3 = (float)a[3];
  }
  const bf16x4 p0 = *(const bf16x4*)(P0 + base);
  const bf16x4 p1 = *(const bf16x4*)(P1 + base);
  const bf16x4 p2 = *(const bf16x4*)(P2 + base);
  const bf16x4 p3 = *(const bf16x4*)(P3 + base);
  x0 += (float)p0[0] + (float)p1[0] + (float)p2[0] + (float)p3[0];
  x1 += (float)p0[1] + (float)p1[1] + (float)p2[1] + (float)p3[1];
  x2 += (float)p0[2] + (float)p1[2] + (float)p2[2] + (float)p3[2];
  x3 += (float)p0[3] + (float)p1[3] + (float)p2[3] + (float)p3[3];
  if (cb) {
    const float4 c = *(const float4*)(cb + t * 4);
    x0 += c.x; x1 += c.y; x2 += c.z; x3 += c.w;
  }
  float s = x0 + x1 + x2 + x3;
  float qq = x0 * x0 + x1 * x1 + x2 * x2 + x3 * x3;
#pragma unroll
  for (int o = 1; o < 64; o <<= 1) { s += __shfl_xor(s, o, 64); qq += __shfl_xor(qq, o, 64); }
  __shared__ float ss[4], qs[4];
  if ((t & 63) == 0) { ss[t >> 6] = s; qs[t >> 6] = qq; }
  __syncthreads();
  s = ss[0] + ss[1] + ss[2] + ss[3];
  qq = qs[0] + qs[1] + qs[2] + qs[3];
  const float mean = s * (1.f / 1024.f);
  const float var = qq * (1.f / 1024.f) - mean * mean;
  const float rstd = rsqrtf(var + 1e-5f);
  const float4 gv = *(const float4*)(g + t * 4);
  const float4 bev = *(const float4*)(be + t * 4);
  const float y0 = (x0 - mean) * rstd * gv.x + bev.x;
  const float y1 = (x1 - mean) * rstd * gv.y + bev.y;
  const float y2 = (x2 - mean) * rstd * gv.z + bev.z;
  const float y3 = (x3 - mean) * rstd * gv.w + bev.w;
  if (oF) {
    float4 r = {y0, y1, y2, y3};
    *(float4*)(oF + base) = r;
  }
  if (oB) {
    bf16x4 o4 = {(__bf16)y0, (__bf16)y1, (__bf16)y2, (__bf16)y3};
    *(bf16x4*)(oB + base) = o4;
  }
}

extern "C" void kernel_launch(void* const* d_in, const int* in_sizes, int n_in,
                              void* d_out, int out_size, void* d_ws, size_t ws_size,
                              hipStream_t stream) {
  const float* src    = (const float*)d_in[0];
  const float* pos    = (const float*)d_in[1];
  const float* qw     = (const float*)d_in[3];
  const float* kw     = (const float*)d_in[4];
  const float* vw     = (const float*)d_in[5];
  const float* rw     = (const float*)d_in[6];
  const float* ow     = (const float*)d_in[7];
  const float* rwbias = (const float*)d_in[8];
  const float* rrbias = (const float*)d_in[9];
  const float* w1     = (const float*)d_in[10];
  const float* b1     = (const float*)d_in[11];
  const float* w2     = (const float*)d_in[12];
  const float* b2     = (const float*)d_in[13];
  const float* g1     = (const float*)d_in[14];
  const float* be1    = (const float*)d_in[15];
  const float* g2     = (const float*)d_in[16];
  const float* be2    = (const float*)d_in[17];
  float* out = (float*)d_out;

  char* p = (char*)d_ws;
  auto alloc = [&](size_t bytes) { char* r = p; p += (bytes + 255) & ~(size_t)255; return r; };
  __bf16* qkB   = (__bf16*)alloc(4096ull * 2048 * 2);   // dead after attn
  __bf16* vTB   = (__bf16*)alloc(1024ull * 4096 * 2);   // dead after attn
  __bf16* kposB = (__bf16*)alloc(4100ull * 1024 * 2);   // dead after attn
  __bf16* avB   = (__bf16*)alloc(4096ull * 1024 * 2);   // dead after attn-out
  __bf16* srcB2 = (__bf16*)alloc(4096ull * 1024 * 2);   // dead after projections
  __bf16* posB  = (__bf16*)alloc(4100ull * 1024 * 2);   // dead after proj2
  float*  xF    = (float*)alloc(4096ull * 1024 * 4);    // scratch: 2x 8MB partial slots
  __bf16* w2B   = (__bf16*)alloc(4096ull * 1024 * 2);
  __bf16* qkvT  = (__bf16*)alloc(3072ull * 1024 * 2);
  __bf16* rwT   = (__bf16*)alloc(1024ull * 1024 * 2);
  __bf16* owB   = (__bf16*)alloc(1024ull * 1024 * 2);
  __bf16* w1B   = (__bf16*)alloc(4096ull * 1024 * 2);   // dead after FFN1
  __bf16* xB    = (__bf16*)alloc(4096ull * 1024 * 2);   // live until LN2 (residual)
  // aliases (disjoint lifetimes):
  __bf16* gB   = qkB;                  // gelu 32MB over qkB+vTB+kposB
  __bf16* xS0  = (__bf16*)xF;          // scratch slot A (8MB)
  __bf16* xS1  = (__bf16*)xF + 4194304;// scratch slot B (8MB)

  prep_all<<<11521, 256, 0, stream>>>(src, srcB2, pos, posB, ow, owB, w1, w1B,
                                      w2, w2B, qw, kw, vw, rw, qkvT, rwT);
  gemm256<2><<<dim3(16, 16), 512, 0, stream>>>(srcB2, qkvT, qkB, nullptr, 4096, 2048, 1024);
  proj2_kernel<<<1040, 256, 0, stream>>>(qkvT + 2048 * 1024, srcB2, posB, rwT, vTB, kposB);
  attn10<<<dim3(1024), 256, 0, stream>>>(qkB, vTB, kposB, rwbias, rrbias, avB);
  gemm512<2><<<dim3(4, 16, 4), 512, 0, stream>>>(avB, owB, srcB2, posB, xS0, xS1, nullptr, 4096, 1024, 1024, 256);
  ln_fuse<<<4096, 256, 0, stream>>>(src, nullptr, srcB2, posB, xS0, xS1, nullptr, g1, be1, nullptr, xB);
  gemm512<1><<<dim3(16, 16), 512, 0, stream>>>(xB, w1B, gB, nullptr, nullptr, nullptr, b1, 4096, 4096, 1024, 1024);
  gemm512<2><<<dim3(4, 16, 4), 512, 0, stream>>>(gB, w2B, avB, w1B, xS0, xS1, nullptr, 4096, 1024, 4096, 1024);
  ln_fuse<<<4096, 256, 0, stream>>>(nullptr, xB, avB, w1B, xS0, xS1, b2, g2, be2, out, nullptr);
  (void)in_sizes; (void)n_in; (void)out_size; (void)ws_size;
}

// Round 17
// 283.671 us; speedup vs baseline: 1.1240x; 1.0054x over previous
//
#include <hip/hip_runtime.h>
#include <math.h>

typedef __bf16 bf16x8 __attribute__((ext_vector_type(8)));
typedef __bf16 bf16x4 __attribute__((ext_vector_type(4)));
typedef float f32x4 __attribute__((ext_vector_type(4)));

__device__ __forceinline__ void gload_lds16(const __bf16* g, __bf16* l) {
  __builtin_amdgcn_global_load_lds((const __attribute__((address_space(1))) void*)g,
                                   (__attribute__((address_space(3))) void*)l, 16, 0, 0);
}

__device__ __forceinline__ float gelu_exact(float v) {
  return 0.5f * v * (1.f + erff(v * 0.70710678118654752f));
}

// ---------------- fused prep: perm-src | 4x cvt | 4x transpose-cvt ----------------
__global__ __launch_bounds__(256) void prep_all(
    const float* __restrict__ src, __bf16* __restrict__ srcB2,
    const float* __restrict__ pos, __bf16* __restrict__ posB,
    const float* __restrict__ ow, __bf16* __restrict__ owB,
    const float* __restrict__ w1, __bf16* __restrict__ w1B,
    const float* __restrict__ w2, __bf16* __restrict__ w2B,
    const float* __restrict__ qw, const float* __restrict__ kw,
    const float* __restrict__ vw, const float* __restrict__ rw,
    __bf16* __restrict__ qkvT, __bf16* __restrict__ rwT) {
  __shared__ float t[32][33];
  int bid = blockIdx.x;
  const int tid = threadIdx.x;
  if (bid < 4096) {                       // src (i,b)-rows -> bf16 (b,i)-rows
    const int i = bid & 1023, b = bid >> 10;
    const float4 v = *(const float4*)(src + ((size_t)(i * 4 + b)) * 1024 + tid * 4);
    bf16x4 o = {(__bf16)v.x, (__bf16)v.y, (__bf16)v.z, (__bf16)v.w};
    *(bf16x4*)(srcB2 + (size_t)bid * 1024 + tid * 4) = o;
    return;
  }
  bid -= 4096;
  if (bid < 3329) {                       // straight converts
    const float* in; __bf16* out;
    if (bid < 1025) { in = pos; out = posB; }
    else if (bid < 1281) { bid -= 1025; in = ow; out = owB; }
    else if (bid < 2305) { bid -= 1281; in = w1; out = w1B; }
    else { bid -= 2305; in = w2; out = w2B; }
    const int base = bid * 4096 + tid * 4;
#pragma unroll
    for (int k2 = 0; k2 < 4; ++k2) {
      const int off = base + k2 * 1024;
      float4 v = *(const float4*)(in + off);
      bf16x4 o = {(__bf16)v.x, (__bf16)v.y, (__bf16)v.z, (__bf16)v.w};
      *(bf16x4*)(out + off) = o;
    }
    return;
  }
  bid -= 3329;                            // transpose-converts (4x 1024x1024)
  const int z = bid >> 10, rem = bid & 1023;
  const float* in; __bf16* out;
  switch (z) {
    case 0: in = qw; out = qkvT; break;
    case 1: in = kw; out = qkvT + 1024 * 1024; break;
    case 2: in = vw; out = qkvT + 2048 * 1024; break;
    default: in = rw; out = rwT; break;
  }
  const int c0 = (rem & 31) * 32, r0 = (rem >> 5) * 32;
  const int tx = tid & 31, ty = tid >> 5;
  for (int yy = ty; yy < 32; yy += 8)
    t[yy][tx] = in[(size_t)(r0 + yy) * 1024 + c0 + tx];
  __syncthreads();
  for (int yy = ty; yy < 32; yy += 8)
    out[(size_t)(c0 + yy) * 1024 + r0 + tx] = (__bf16)t[tx][yy];
}

// ---------------- bf16 MFMA GEMM body (2-phase, 128x64) ----------------
template<int BM, int BN, int MODE>
__device__ __forceinline__ void gemm_body(
    const __bf16* __restrict__ A, const __bf16* __restrict__ BT,
    float* __restrict__ Cf, __bf16* __restrict__ Cb,
    const float* __restrict__ bias, int M, int N, int K,
    int kStart, int kChunk, int mBase, int nBase, char* smemRaw) {
  constexpr int BK = 32;
  constexpr int ALOAD = (BM * BK) / 2048;
  constexpr int BLOAD = (BN * BK) / 2048;
  __bf16* lA = (__bf16*)smemRaw;                       // [2][BM*BK]
  __bf16* lB = (__bf16*)(smemRaw + 4 * BM * BK);       // [2][BN*BK]
  const int tid = threadIdx.x;
  const int w = tid >> 6, l = tid & 63;
  const int lr = l & 15, lk = l >> 4;
  const int srow = tid >> 2;
  const int scol = (tid & 3) * 8;
  const int wbase = w * 512;

  const __bf16* aSrc[ALOAD];
  const __bf16* bSrc[BLOAD];
#pragma unroll
  for (int i = 0; i < ALOAD; ++i) {
    int grow = mBase + srow + i * 64;
    grow = grow < M ? grow : M - 1;
    aSrc[i] = A + (size_t)grow * K + kStart + scol;
  }
#pragma unroll
  for (int i = 0; i < BLOAD; ++i) {
    const int grow = nBase + srow + i * 64;
    bSrc[i] = BT + (size_t)grow * K + kStart + scol;
  }
  auto stage = [&](int buf) {
#pragma unroll
    for (int i = 0; i < ALOAD; ++i) {
      gload_lds16(aSrc[i], &lA[buf * BM * BK + i * 2048 + wbase]);
      aSrc[i] += BK;
    }
#pragma unroll
    for (int i = 0; i < BLOAD; ++i) {
      gload_lds16(bSrc[i], &lB[buf * BN * BK + i * 2048 + wbase]);
      bSrc[i] += BK;
    }
  };

  constexpr int WM = BM / 2, WN = BN / 2;
  constexpr int MF = WM / 16, NF = WN / 16;
  const int wr = w >> 1, wc = w & 1;
  f32x4 acc[MF][NF] = {};

  const int nIter = kChunk / BK;
  stage(0);
  int cur = 0;
#pragma unroll 1
  for (int t = 0; t < nIter; ++t) {
    __syncthreads();
    if (t + 1 < nIter) stage(cur ^ 1);
    bf16x8 af[MF], bfr[NF];
#pragma unroll
    for (int mi = 0; mi < MF; ++mi)
      af[mi] = *(const bf16x8*)&lA[cur * BM * BK + (wr * WM + mi * 16 + lr) * BK + lk * 8];
#pragma unroll
    for (int nj = 0; nj < NF; ++nj)
      bfr[nj] = *(const bf16x8*)&lB[cur * BN * BK + (wc * WN + nj * 16 + lr) * BK + lk * 8];
#pragma unroll
    for (int mi = 0; mi < MF; ++mi)
#pragma unroll
      for (int nj = 0; nj < NF; ++nj)
        acc[mi][nj] = __builtin_amdgcn_mfma_f32_16x16x32_bf16(af[mi], bfr[nj], acc[mi][nj], 0, 0, 0);
    cur ^= 1;
  }
#pragma unroll
  for (int mi = 0; mi < MF; ++mi) {
#pragma unroll
    for (int nj = 0; nj < NF; ++nj) {
      const int col = nBase + wc * WN + nj * 16 + lr;
      const int row0 = mBase + wr * WM + mi * 16 + lk * 4;
#pragma unroll
      for (int j = 0; j < 4; ++j) {
        const int row = row0 + j;
        if (row < M) {
          float v = acc[mi][nj][j];
          if constexpr (MODE == 1) {
            v = gelu_exact(v + bias[col]);
            Cb[(size_t)row * N + col] = (__bf16)v;
          } else if constexpr (MODE == 2) {
            Cb[(size_t)row * N + col] = (__bf16)v;
          } else {
            Cf[(size_t)row * N + col] = v;
          }
        }
      }
    }
  }
}

// ---- vT + kpos projections in one launch (1040 blocks, XCD-chunked) ----
__global__ __launch_bounds__(256)
void proj2_kernel(const __bf16* __restrict__ vwT, const __bf16* __restrict__ srcB2,
                  const __bf16* __restrict__ posB, const __bf16* __restrict__ rwT,
                  __bf16* __restrict__ vTB, __bf16* __restrict__ kposB) {
  __shared__ __align__(16) char smem[4 * (128 + 64) * 32];
  const int raw = blockIdx.x;
  int bid = (raw & 7) * 130 + (raw >> 3);   // 1040/8 = 130 per XCD
  if (bid < 512) {
    gemm_body<128, 64, 2>(vwT, srcB2, nullptr, vTB, nullptr, 1024, 4096, 1024,
                          0, 1024, (bid >> 6) * 128, (bid & 63) * 64, smem);
  } else {
    const int t = bid - 512;
    gemm_body<128, 64, 2>(posB, rwT, nullptr, kposB, nullptr, 4100, 1024, 1024,
                          0, 1024, (t >> 4) * 128, (t & 15) * 64, smem);
  }
}

// ---------------- 256x128-tile deep-pipeline GEMM (3-side counted-vmcnt) ----------------
template<int MODE>
__global__ __launch_bounds__(512)
void gemm256(const __bf16* __restrict__ A, const __bf16* __restrict__ BT,
             __bf16* __restrict__ Cb, const float* __restrict__ bias,
             int M, int N, int K) {
  __shared__ __align__(16) __bf16 sm[3 * 24576];
  const int tid = threadIdx.x;
  const int wid = tid >> 6, l = tid & 63;
  const int lcol = l & 15, lk = l >> 4;
  const int wm = wid >> 1, wn = wid & 1;
  const int gx = gridDim.x;
  const int G = gx * gridDim.y;
  const int flat = blockIdx.y * gx + blockIdx.x;
  const int band = G >> 3;
  const int x8 = flat & 7, loc = flat >> 3;
  const int rpb = band / gx;
  const int ny = x8 * rpb + loc % rpb;
  const int nx = loc / rpb;
  const int mBase = ny * 256, nBase = nx * 128;

  int rowj[2], gslotj[2];
#pragma unroll
  for (int j = 0; j < 2; ++j) {
    const int u = (wid * 2 + j) * 64 + l;
    rowj[j] = u >> 3;
    gslotj[j] = (u & 7) ^ (rowj[j] & 7);
  }
  auto issueHT = [&](int kt, int ht, int side) {
    __bf16* base = sm + side * 24576 + (ht == 2 ? 16384 : ht * 8192);
#pragma unroll
    for (int j = 0; j < 2; ++j) {
      const __bf16* src = (ht < 2)
        ? A + (size_t)(mBase + ht * 128 + rowj[j]) * K + kt * 64 + gslotj[j] * 8
        : BT + (size_t)(nBase + rowj[j]) * K + kt * 64 + gslotj[j] * 8;
      gload_lds16(src, base + (wid * 2 + j) * 512);
    }
  };

  const int nkt = K >> 6;
  issueHT(0, 0, 0); issueHT(0, 1, 0); issueHT(0, 2, 0);
  issueHT(1, 0, 1); issueHT(1, 1, 1); issueHT(1, 2, 1);

  f32x4 acc[4][4] = {};
#pragma unroll 1
  for (int j = 0; j < nkt; ++j) {
    asm volatile("s_waitcnt vmcnt(6)" ::: "memory");
    __builtin_amdgcn_s_barrier();
    __builtin_amdgcn_sched_barrier(0);
    const int side = j % 3;
    const int sn = (j + 2) % 3;
    const int ktn = (j + 2 < nkt) ? j + 2 : nkt - 1;
    const __bf16* Ab = sm + side * 24576;
    const __bf16* Bb = Ab + 16384;
    issueHT(ktn, 0, sn);
    bf16x8 af[4][2];
#pragma unroll
    for (int mi = 0; mi < 4; ++mi)
#pragma unroll
      for (int kk = 0; kk < 2; ++kk) {
        const int row = wm * 64 + mi * 16 + lcol;
        af[mi][kk] = *(const bf16x8*)&Ab[row * 64 + (((kk * 4 + lk) ^ (row & 7)) * 8)];
      }
    issueHT(ktn, 1, sn);
    bf16x8 bfv[4][2];
#pragma unroll
    for (int nj = 0; nj < 4; ++nj)
#pragma unroll
      for (int kk = 0; kk < 2; ++kk) {
        const int row = wn * 64 + nj * 16 + lcol;
        bfv[nj][kk] = *(const bf16x8*)&Bb[row * 64 + (((kk * 4 + lk) ^ (row & 7)) * 8)];
      }
    issueHT(ktn, 2, sn);
    __builtin_amdgcn_s_setprio(1);
#pragma unroll
    for (int mi = 0; mi < 4; ++mi)
#pragma unroll
      for (int nj = 0; nj < 4; ++nj) {
        acc[mi][nj] = __builtin_amdgcn_mfma_f32_16x16x32_bf16(af[mi][0], bfv[nj][0], acc[mi][nj], 0, 0, 0);
        acc[mi][nj] = __builtin_amdgcn_mfma_f32_16x16x32_bf16(af[mi][1], bfv[nj][1], acc[mi][nj], 0, 0, 0);
      }
    __builtin_amdgcn_s_setprio(0);
  }
#pragma unroll
  for (int mi = 0; mi < 4; ++mi)
#pragma unroll
    for (int nj = 0; nj < 4; ++nj) {
      const int col = nBase + wn * 64 + nj * 16 + lcol;
      const int row0 = mBase + wm * 64 + mi * 16 + lk * 4;
#pragma unroll
      for (int jj = 0; jj < 4; ++jj) {
        float v = acc[mi][nj][jj];
        if constexpr (MODE == 1) v = gelu_exact(v + bias[col]);
        Cb[(size_t)(row0 + jj) * N + col] = (__bf16)v;
      }
    }
}

// ---------------- 256x256-tile GEMM, BK=64, 8 waves of 128x64 (LDS-BW optimal) ----------
template<int MODE>
__global__ __launch_bounds__(512)
void gemm512(const __bf16* __restrict__ A, const __bf16* __restrict__ BT,
             __bf16* __restrict__ Cb0, __bf16* __restrict__ Cb1,
             __bf16* __restrict__ Cb2, __bf16* __restrict__ Cb3,
             const float* __restrict__ bias, int M, int N, int K, int kChunk) {
  __shared__ __align__(16) __bf16 sm[2 * 32768];
  const int tid = threadIdx.x;
  const int w = tid >> 6, l = tid & 63;
  const int lcol = l & 15, lk = l >> 4;
  const int wm = w >> 2, wn = w & 3;          // 2 x 4 waves, wave tile 128x64
  const int gx = gridDim.x;
  const int G = gx * gridDim.y;
  const int flat = blockIdx.y * gx + blockIdx.x;
  const int band = G >> 3;
  const int x8 = flat & 7, loc = flat >> 3;
  const int rpb = band / gx;
  const int ny = x8 * rpb + loc % rpb;
  const int nx = loc / rpb;
  const int mBase = ny * 256, nBase = nx * 256;
  const int kStart = blockIdx.z * kChunk;
  __bf16* Cb = (blockIdx.z == 0) ? Cb0 : (blockIdx.z == 1) ? Cb1
             : (blockIdx.z == 2) ? Cb2 : Cb3;

  const int rT = tid >> 3;                    // 0..63
  const int gslot = ((tid & 7) ^ (rT & 7)) * 8;
  auto stage = [&](int side, int kt) {
#pragma unroll
    for (int i = 0; i < 4; ++i) {
      gload_lds16(A + (size_t)(mBase + i * 64 + rT) * K + kStart + kt * 64 + gslot,
                  sm + side * 32768 + i * 4096 + w * 512);
      gload_lds16(BT + (size_t)(nBase + i * 64 + rT) * K + kStart + kt * 64 + gslot,
                  sm + side * 32768 + 16384 + i * 4096 + w * 512);
    }
  };

  f32x4 acc[8][4] = {};
  const int nIter = kChunk >> 6;
  stage(0, 0);
  int cur = 0;
#pragma unroll 1
  for (int t = 0; t < nIter; ++t) {
    __syncthreads();                           // side cur complete (drains vmcnt)
    if (t + 1 < nIter) stage(cur ^ 1, t + 1);
    const __bf16* Ab = sm + cur * 32768;
    const __bf16* Bb = Ab + 16384;
    bf16x8 bfv[4][2];
#pragma unroll
    for (int nj = 0; nj < 4; ++nj)
#pragma unroll
      for (int kk = 0; kk < 2; ++kk) {
        const int row = wn * 64 + nj * 16 + lcol;
        bfv[nj][kk] = *(const bf16x8*)&Bb[row * 64 + (((kk * 4 + lk) ^ (row & 7)) * 8)];
      }
    __builtin_amdgcn_s_setprio(1);
#pragma unroll
    for (int mi = 0; mi < 8; ++mi) {
      const int row = wm * 128 + mi * 16 + lcol;
      bf16x8 a0 = *(const bf16x8*)&Ab[row * 64 + ((lk ^ (row & 7)) * 8)];
      bf16x8 a1 = *(const bf16x8*)&Ab[row * 64 + (((4 + lk) ^ (row & 7)) * 8)];
#pragma unroll
      for (int nj = 0; nj < 4; ++nj) {
        acc[mi][nj] = __builtin_amdgcn_mfma_f32_16x16x32_bf16(a0, bfv[nj][0], acc[mi][nj], 0, 0, 0);
        acc[mi][nj] = __builtin_amdgcn_mfma_f32_16x16x32_bf16(a1, bfv[nj][1], acc[mi][nj], 0, 0, 0);
      }
    }
    __builtin_amdgcn_s_setprio(0);
    cur ^= 1;
  }
#pragma unroll
  for (int mi = 0; mi < 8; ++mi)
#pragma unroll
    for (int nj = 0; nj < 4; ++nj) {
      const int col = nBase + wn * 64 + nj * 16 + lcol;
      const int row0 = mBase + wm * 128 + mi * 16 + lk * 4;
#pragma unroll
      for (int jj = 0; jj < 4; ++jj) {
        float v = acc[mi][nj][jj];
        if constexpr (MODE == 1) v = gelu_exact(v + bias[col]);
        Cb[(size_t)(row0 + jj) * N + col] = (__bf16)v;
      }
    }
}

// ---------------- MFMA rel-pos attention v11: single-buffer + reg-staged (3 blocks/CU) ----
// T14 async-STAGE split: issue next-tile global loads to 24 VGPRs at top of jt
// (covered by the full compute phase), write to SINGLE K/KP/VT buffers after
// barrier-A (all reads done), publish with barrier-B. LDS 49.7 KB -> 3 blocks/CU.
__global__ __launch_bounds__(256)
void attn11(const __bf16* __restrict__ qk, const __bf16* __restrict__ vT,
            const __bf16* __restrict__ kpos, const float* __restrict__ rwbias,
            const float* __restrict__ rrbias, __bf16* __restrict__ av) {
  constexpr float ALPHA = 0.125f * 1.44269504088896f;
  constexpr int PB = 132;
  // K 8K | KP 8K | VT 8K | P 8K | sbd [64][132] 16.9K = 49664 B
  __shared__ __align__(16) char smem[49664];
  __bf16* sK  = (__bf16*)(smem);
  __bf16* sKP = (__bf16*)(smem + 8192);
  __bf16* sVT = (__bf16*)(smem + 16384);
  __bf16* sP  = (__bf16*)(smem + 24576);
  __bf16* sbd = (__bf16*)(smem + 32768);

  const int flat = blockIdx.x;
  const int xcd = flat & 7, rr_ = flat >> 3;
  const int bn = xcd * 8 + (rr_ >> 4);
  const int it = rr_ & 15;
  const int b = bn >> 4, n = bn & 15;
  const int i0 = it * 64;
  const int tid = threadIdx.x;
  const int l = tid & 63;
  const int lcol = l & 15, lk = l >> 4;
  const int strip = (tid >> 6) * 16;
  const int wbase = tid & 192;
  const int nh64 = n * 64;
  const int q = strip + lcol;

  const int rB = tid >> 3;
  const int cs8 = ((tid & 7) ^ (rB & 7)) * 8;

  bf16x8 onesf;
#pragma unroll
  for (int u = 0; u < 8; ++u) onesf[u] = (__bf16)1.0f;

  bf16x8 qac[2], qlo[2], qhi[2];
  {
    const __bf16* qrow = qk + ((size_t)(b * 1024 + i0 + q)) * 2048 + nh64;
    int gH = i0 + q + 1; gH = gH < 1024 ? gH : 1023;
    const __bf16* qrowH = qk + ((size_t)(b * 1024 + gH)) * 2048 + nh64;
#pragma unroll
    for (int kk = 0; kk < 2; ++kk) {
      bf16x8 qv = *(const bf16x8*)(qrow + kk * 32 + lk * 8);
      bf16x8 qh = *(const bf16x8*)(qrowH + kk * 32 + lk * 8);
      const int dbase = nh64 + kk * 32 + lk * 8;
#pragma unroll
      for (int u = 0; u < 8; ++u) {
        const float rb = rrbias[dbase + u];
        qac[kk][u] = (__bf16)(((float)qv[u] + rwbias[dbase + u]) * ALPHA);
        qlo[kk][u] = (__bf16)(((float)qv[u] + rb) * ALPHA);
        qhi[kk][u] = (__bf16)(((float)qh[u] + rb) * ALPHA);
      }
    }
  }

  // ---- prologue stage: low band -> sP(temp), K0 -> sK, KP0 -> sKP, VT0 -> sVT ----
#pragma unroll
  for (int kq = 0; kq < 2; ++kq) {
    const int r = kq * 32 + rB;
    const int dst = (kq * 256 + wbase) * 8;
    gload_lds16(kpos + ((size_t)((960 - i0 + r) * 4 + b)) * 1024 + nh64 + cs8, sP + dst);
    gload_lds16(qk + ((size_t)(b * 1024 + r)) * 2048 + 1024 + nh64 + cs8, sK + dst);
    const int rrel = r - i0;
    const int idx = (rrel <= 0) ? (1024 + rrel) : (rrel - 1);
    gload_lds16(kpos + ((size_t)(idx * 4 + b)) * 1024 + nh64 + cs8, sKP + dst);
    gload_lds16(vT + ((size_t)(nh64 + r)) * 4096 + b * 1024 + cs8, sVT + dst);
  }
  __syncthreads();
  // ---- prologue G on low band from sP temp (rrel in [-i0-64,-i0), lo frags) ----
  {
    const __bf16* kpl = sP;
    const int colb0 = (-i0 - 64) & 127;
#pragma unroll
    for (int fb = 0; fb < 4; ++fb) {
      const int row = fb * 16 + lcol;
      f32x4 g = {};
#pragma unroll
      for (int kk = 0; kk < 2; ++kk) {
        bf16x8 a = *(const bf16x8*)&kpl[row * 64 + (((kk * 4 + lk) ^ (lcol & 7)) * 8)];
        g = __builtin_amdgcn_mfma_f32_16x16x32_bf16(a, qlo[kk], g, 0, 0, 0);
      }
      bf16x4 gw = {(__bf16)g[0], (__bf16)g[1], (__bf16)g[2], (__bf16)g[3]};
      *(bf16x4*)&sbd[q * PB + ((colb0 + fb * 16 + lk * 4) & 127)] = gw;
    }
  }
  __syncthreads();   // sP temp reads done before jt0's P writes

  f32x4 oacc[4] = {};
  f32x4 zq = {};
  size_t kS = (size_t)(b * 1024 + 64 + rB) * 2048 + 1024 + nh64 + cs8;
  size_t vS = (size_t)(nh64 + rB) * 4096 + b * 1024 + 64 + cs8;

  auto jtStep = [&](int jt, const bf16x8 (&qg)[2], bool dofix) {
    const int d0 = jt * 64 - i0;
    // ---- phase 1: issue next-tile loads into regs (full compute phase of cover) ----
    bf16x8 rKr[2], rKPr[2], rVTr[2];
#pragma unroll
    for (int kq = 0; kq < 2; ++kq) {
      rKr[kq] = *(const bf16x8*)(qk + kS + kq * 65536);
      rVTr[kq] = *(const bf16x8*)(vT + vS + kq * 131072);
      const int rreln = d0 + 64 + kq * 32 + rB;
      const int idx = (rreln <= 0) ? (1024 + rreln) : (rreln - 1);
      rKPr[kq] = *(const bf16x8*)(kpos + ((size_t)(idx * 4 + b)) * 1024 + nh64 + cs8);
    }
    kS += 131072; vS += 64;
    // ---- phase 2: compute jt from single buffers ----
    {
      __builtin_amdgcn_s_setprio(1);
#pragma unroll
      for (int fb = 0; fb < 4; ++fb) {
        const int row = fb * 16 + lcol;
        f32x4 g = {};
        g = __builtin_amdgcn_mfma_f32_16x16x32_bf16(
            *(const bf16x8*)&sKP[row * 64 + ((lk ^ (lcol & 7)) * 8)], qg[0], g, 0, 0, 0);
        g = __builtin_amdgcn_mfma_f32_16x16x32_bf16(
            *(const bf16x8*)&sKP[row * 64 + (((4 + lk) ^ (lcol & 7)) * 8)], qg[1], g, 0, 0, 0);
        bf16x4 gw = {(__bf16)g[0], (__bf16)g[1], (__bf16)g[2], (__bf16)g[3]};
        *(bf16x4*)&sbd[q * PB + ((d0 + fb * 16 + lk * 4) & 127)] = gw;
      }
      __builtin_amdgcn_s_setprio(0);
      if (dofix) {                 // col rrel=0 (needs lo q-rows): once per block
        const int cl = tid >> 2, part = tid & 3;
        const __bf16* qs = qk + ((size_t)(b * 1024 + i0 + cl)) * 2048 + nh64 + part * 16;
        bf16x8 a0 = *(const bf16x8*)qs;
        bf16x8 a1 = *(const bf16x8*)(qs + 8);
        bf16x8 k0 = *(const bf16x8*)&sKP[(2 * part) * 8];
        bf16x8 k1 = *(const bf16x8*)&sKP[(2 * part + 1) * 8];
        float s64 = 0.f;
#pragma unroll
        for (int u = 0; u < 8; ++u)
          s64 += ((float)a0[u] + rrbias[nh64 + part * 16 + u]) * (float)k0[u]
               + ((float)a1[u] + rrbias[nh64 + part * 16 + 8 + u]) * (float)k1[u];
        s64 += __shfl_xor(s64, 1, 64);
        s64 += __shfl_xor(s64, 2, 64);
        if (part == 0) sbd[cl * PB] = (__bf16)(s64 * ALPHA);
      }
    }
    f32x4 sc[4];
    __builtin_amdgcn_s_setprio(1);
#pragma unroll
    for (int fk = 0; fk < 4; ++fk) {
      const int row = fk * 16 + lcol;
      f32x4 a = {};
#pragma unroll
      for (int kk = 0; kk < 2; ++kk) {
        bf16x8 kf = *(const bf16x8*)&sK[row * 64 + (((kk * 4 + lk) ^ (lcol & 7)) * 8)];
        a = __builtin_amdgcn_mfma_f32_16x16x32_bf16(kf, qac[kk], a, 0, 0, 0);
      }
      sc[fk] = a;
    }
    __builtin_amdgcn_s_setprio(0);
    {
      const int rowb = q * PB;
      const int sb = d0 - q;
#pragma unroll
      for (int fk = 0; fk < 4; ++fk) {
        const int cb = sb + fk * 16 + lk * 4;
        float e0 = exp2f(sc[fk][0] + (float)sbd[rowb + ((cb) & 127)]);
        float e1 = exp2f(sc[fk][1] + (float)sbd[rowb + ((cb + 1) & 127)]);
        float e2 = exp2f(sc[fk][2] + (float)sbd[rowb + ((cb + 2) & 127)]);
        float e3 = exp2f(sc[fk][3] + (float)sbd[rowb + ((cb + 3) & 127)]);
        bf16x4 pw = {(__bf16)e0, (__bf16)e1, (__bf16)e2, (__bf16)e3};
        *(bf16x4*)&sP[q * 64 + (((fk * 2 + (lk >> 1)) ^ (q & 7)) * 8) + (lk & 1) * 4] = pw;
      }
    }
    __builtin_amdgcn_s_setprio(1);
#pragma unroll
    for (int kk = 0; kk < 2; ++kk) {
      bf16x8 pa = *(const bf16x8*)&sP[q * 64 + (((kk * 4 + lk) ^ (q & 7)) * 8)];
      zq = __builtin_amdgcn_mfma_f32_16x16x32_bf16(pa, onesf, zq, 0, 0, 0);
#pragma unroll
      for (int fd = 0; fd < 4; ++fd) {
        const int vrow = fd * 16 + lcol;
        bf16x8 bv = *(const bf16x8*)&sVT[vrow * 64 + (((kk * 4 + lk) ^ (lcol & 7)) * 8)];
        oacc[fd] = __builtin_amdgcn_mfma_f32_16x16x32_bf16(pa, bv, oacc[fd], 0, 0, 0);
      }
    }
    __builtin_amdgcn_s_setprio(0);
    // ---- barrier A: all LDS reads of jt done ----
    __syncthreads();
    // ---- phase 3: write staged regs -> single buffers (linear, conflict-free) ----
#pragma unroll
    for (int kq = 0; kq < 2; ++kq) {
      const int dst = (kq * 256 + tid) * 8;
      *(bf16x8*)(sK + dst) = rKr[kq];
      *(bf16x8*)(sKP + dst) = rKPr[kq];
      *(bf16x8*)(sVT + dst) = rVTr[kq];
    }
    // ---- barrier B: staged tiles visible for jt+1 ----
    __syncthreads();
  };

#pragma unroll 1
  for (int jt = 0; jt < it; ++jt) jtStep(jt, qlo, false);      // d0 < 0
  jtStep(it, qhi, true);                                       // d0 == 0 (+col-0 fix)
#pragma unroll 1
  for (int jt = it + 1; jt < 16; ++jt) jtStep(jt, qhi, false); // d0 > 0

#pragma unroll
  for (int jj = 0; jj < 4; ++jj) {
    const float rz = 1.f / zq[jj];
    const int ig = i0 + strip + lk * 4 + jj;
    __bf16* dst = av + ((size_t)(ig * 4 + b)) * 1024 + nh64;
#pragma unroll
    for (int fd = 0; fd < 4; ++fd)
      dst[fd * 16 + lcol] = (__bf16)(oacc[fd][jj] * rz);
  }
}

// ---------------- fused residual + LayerNorm (f32 or bf16 base, 4 bf16 partials) ----------------
__global__ __launch_bounds__(256)
void ln_fuse(const float* __restrict__ A, const __bf16* __restrict__ Ab,
             const __bf16* __restrict__ P0, const __bf16* __restrict__ P1,
             const __bf16* __restrict__ P2, const __bf16* __restrict__ P3,
             const float* __restrict__ cb, const float* __restrict__ g,
             const float* __restrict__ be, float* __restrict__ oF,
             __bf16* __restrict__ oB) {
  const int row = blockIdx.x, t = threadIdx.x;
  const size_t base = (size_t)row * 1024 + t * 4;
  float x0, x1, x2, x3;
  if (A) {
    const float4 a = *(const float4*)(A + base);
    x0 = a.x; x1 = a.y; x2 = a.z; x3 = a.w;
  } else {
    const bf16x4 a = *(const bf16x4*)(Ab + base);
    x0 = (float)a[0]; x1 = (float)a[1]; x2 = (float)a[2]; x3 = (float)a[3];
  }
  const bf16x4 p0 = *(const bf16x4*)(P0 + base);
  const bf16x4 p1 = *(const bf16x4*)(P1 + base);
  const bf16x4 p2 = *(const bf16x4*)(P2 + base);
  const bf16x4 p3 = *(const bf16x4*)(P3 + base);
  x0 += (float)p0[0] + (float)p1[0] + (float)p2[0] + (float)p3[0];
  x1 += (float)p0[1] + (float)p1[1] + (float)p2[1] + (float)p3[1];
  x2 += (float)p0[2] + (float)p1[2] + (float)p2[2] + (float)p3[2];
  x3 += (float)p0[3] + (float)p1[3] + (float)p2[3] + (float)p3[3];
  if (cb) {
    const float4 c = *(const float4*)(cb + t * 4);
    x0 += c.x; x1 += c.y; x2 += c.z; x3 += c.w;
  }
  float s = x0 + x1 + x2 + x3;
  float qq = x0 * x0 + x1 * x1 + x2 * x2 + x3 * x3;
#pragma unroll
  for (int o = 1; o < 64; o <<= 1) { s += __shfl_xor(s, o, 64); qq += __shfl_xor(qq, o, 64); }
  __shared__ float ss[4], qs[4];
  if ((t & 63) == 0) { ss[t >> 6] = s; qs[t >> 6] = qq; }
  __syncthreads();
  s = ss[0] + ss[1] + ss[2] + ss[3];
  qq = qs[0] + qs[1] + qs[2] + qs[3];
  const float mean = s * (1.f / 1024.f);
  const float var = qq * (1.f / 1024.f) - mean * mean;
  const float rstd = rsqrtf(var + 1e-5f);
  const float4 gv = *(const float4*)(g + t * 4);
  const float4 bev = *(const float4*)(be + t * 4);
  const float y0 = (x0 - mean) * rstd * gv.x + bev.x;
  const float y1 = (x1 - mean) * rstd * gv.y + bev.y;
  const float y2 = (x2 - mean) * rstd * gv.z + bev.z;
  const float y3 = (x3 - mean) * rstd * gv.w + bev.w;
  if (oF) {
    float4 r = {y0, y1, y2, y3};
    *(float4*)(oF + base) = r;
  }
  if (oB) {
    bf16x4 o4 = {(__bf16)y0, (__bf16)y1, (__bf16)y2, (__bf16)y3};
    *(bf16x4*)(oB + base) = o4;
  }
}

extern "C" void kernel_launch(void* const* d_in, const int* in_sizes, int n_in,
                              void* d_out, int out_size, void* d_ws, size_t ws_size,
                              hipStream_t stream) {
  const float* src    = (const float*)d_in[0];
  const float* pos    = (const float*)d_in[1];
  const float* qw     = (const float*)d_in[3];
  const float* kw     = (const float*)d_in[4];
  const float* vw     = (const float*)d_in[5];
  const float* rw     = (const float*)d_in[6];
  const float* ow     = (const float*)d_in[7];
  const float* rwbias = (const float*)d_in[8];
  const float* rrbias = (const float*)d_in[9];
  const float* w1     = (const float*)d_in[10];
  const float* b1     = (const float*)d_in[11];
  const float* w2     = (const float*)d_in[12];
  const float* b2     = (const float*)d_in[13];
  const float* g1     = (const float*)d_in[14];
  const float* be1    = (const float*)d_in[15];
  const float* g2     = (const float*)d_in[16];
  const float* be2    = (const float*)d_in[17];
  float* out = (float*)d_out;

  char* p = (char*)d_ws;
  auto alloc = [&](size_t bytes) { char* r = p; p += (bytes + 255) & ~(size_t)255; return r; };
  __bf16* qkB   = (__bf16*)alloc(4096ull * 2048 * 2);   // dead after attn
  __bf16* vTB   = (__bf16*)alloc(1024ull * 4096 * 2);   // dead after attn
  __bf16* kposB = (__bf16*)alloc(4100ull * 1024 * 2);   // dead after attn
  __bf16* avB   = (__bf16*)alloc(4096ull * 1024 * 2);   // dead after attn-out
  __bf16* srcB2 = (__bf16*)alloc(4096ull * 1024 * 2);   // dead after projections
  __bf16* posB  = (__bf16*)alloc(4100ull * 1024 * 2);   // dead after proj2
  float*  xF    = (float*)alloc(4096ull * 1024 * 4);    // scratch: 2x 8MB partial slots
  __bf16* w2B   = (__bf16*)alloc(4096ull * 1024 * 2);
  __bf16* qkvT  = (__bf16*)alloc(3072ull * 1024 * 2);
  __bf16* rwT   = (__bf16*)alloc(1024ull * 1024 * 2);
  __bf16* owB   = (__bf16*)alloc(1024ull * 1024 * 2);
  __bf16* w1B   = (__bf16*)alloc(4096ull * 1024 * 2);   // dead after FFN1
  __bf16* xB    = (__bf16*)alloc(4096ull * 1024 * 2);   // live until LN2 (residual)
  // aliases (disjoint lifetimes):
  __bf16* gB   = qkB;                  // gelu 32MB over qkB+vTB+kposB
  __bf16* xS0  = (__bf16*)xF;          // scratch slot A (8MB)
  __bf16* xS1  = (__bf16*)xF + 4194304;// scratch slot B (8MB)

  prep_all<<<11521, 256, 0, stream>>>(src, srcB2, pos, posB, ow, owB, w1, w1B,
                                      w2, w2B, qw, kw, vw, rw, qkvT, rwT);
  gemm256<2><<<dim3(16, 16), 512, 0, stream>>>(srcB2, qkvT, qkB, nullptr, 4096, 2048, 1024);
  proj2_kernel<<<1040, 256, 0, stream>>>(qkvT + 2048 * 1024, srcB2, posB, rwT, vTB, kposB);
  attn11<<<dim3(1024), 256, 0, stream>>>(qkB, vTB, kposB, rwbias, rrbias, avB);
  gemm512<2><<<dim3(4, 16, 4), 512, 0, stream>>>(avB, owB, srcB2, posB, xS0, xS1, nullptr, 4096, 1024, 1024, 256);
  ln_fuse<<<4096, 256, 0, stream>>>(src, nullptr, srcB2, posB, xS0, xS1, nullptr, g1, be1, nullptr, xB);
  gemm512<1><<<dim3(16, 16), 512, 0, stream>>>(xB, w1B, gB, nullptr, nullptr, nullptr, b1, 4096, 4096, 1024, 1024);
  gemm512<2><<<dim3(4, 16, 4), 512, 0, stream>>>(gB, w2B, avB, w1B, xS0, xS1, nullptr, 4096, 1024, 4096, 1024);
  ln_fuse<<<4096, 256, 0, stream>>>(nullptr, xB, avB, w1B, xS0, xS1, b2, g2, be2, out, nullptr);
  (void)in_sizes; (void)n_in; (void)out_size; (void)ws_size;
}